// Round 6
// baseline (736.873 us; speedup 1.0000x reference)
//
#include <hip/hip_runtime.h>
#include <hip/hip_bf16.h>

#define N_NODES 8192
#define F_IN    512
#define DIM     256
#define NCLS    40

typedef __attribute__((ext_vector_type(8))) short bf16x8;
typedef __attribute__((ext_vector_type(4))) float f32x4;

#define MFMA16 __builtin_amdgcn_mfma_f32_16x16x32_bf16

static __device__ __forceinline__ unsigned short f2bf(float x) {
    __hip_bfloat16 h = __float2bfloat16(x);
    return *reinterpret_cast<unsigned short*>(&h);
}
static __device__ __forceinline__ float bf2f(unsigned short u) {
    union { unsigned int u32; float f; } v; v.u32 = ((unsigned int)u) << 16;
    return v.f;
}
static __device__ __forceinline__ void gll16(const void* g, void* l) {
    __builtin_amdgcn_global_load_lds(
        (const __attribute__((address_space(1))) unsigned int*)g,
        (__attribute__((address_space(3))) unsigned int*)l, 16, 0, 0);
}

// ---------------------------------------------------------------------------
// fp32 tiled GEMM for the projections. OBF=true writes bf16 output.
// ---------------------------------------------------------------------------
template<int BM, int BN, int BK, int TM, int TN, bool OBF>
__global__ __launch_bounds__(256) void gemm_kernel(
    const float* __restrict__ A, const float* __restrict__ B,
    const float* __restrict__ bias, float* __restrict__ C,
    int M, int N, int K)
{
    static_assert((BM / TM) * (BN / TN) == 256, "256 threads");

    __shared__ float As[BK][BM];
    __shared__ float Bs[BK][BN];

    const int tid = threadIdx.x;
    const int tx  = tid % (BN / TN);
    const int ty  = tid / (BN / TN);
    const int n0  = blockIdx.x * BN;
    const int m0  = blockIdx.y * BM;

    float acc[TM][TN] = {};

    for (int k0 = 0; k0 < K; k0 += BK) {
        #pragma unroll
        for (int i = tid * 4; i < BM * BK; i += 1024) {
            int r = i / BK, c = i % BK;
            float4 v = *(const float4*)(A + (size_t)(m0 + r) * K + k0 + c);
            As[c + 0][r] = v.x; As[c + 1][r] = v.y;
            As[c + 2][r] = v.z; As[c + 3][r] = v.w;
        }
        #pragma unroll
        for (int i = tid * 4; i < BK * BN; i += 1024) {
            int r = i / BN, c = i % BN;
            *(float4*)&Bs[r][c] =
                *(const float4*)(B + (size_t)(k0 + r) * N + n0 + c);
        }
        __syncthreads();

        #pragma unroll
        for (int k = 0; k < BK; ++k) {
            float a[TM], b[TN];
            #pragma unroll
            for (int i = 0; i < TM; i += 4)
                *(float4*)&a[i] = *(const float4*)&As[k][ty * TM + i];
            #pragma unroll
            for (int j = 0; j < TN; j += 4)
                *(float4*)&b[j] = *(const float4*)&Bs[k][tx * TN + j];
            #pragma unroll
            for (int i = 0; i < TM; ++i)
                #pragma unroll
                for (int j = 0; j < TN; ++j)
                    acc[i][j] += a[i] * b[j];
        }
        __syncthreads();
    }

    #pragma unroll
    for (int i = 0; i < TM; ++i) {
        const int m = m0 + ty * TM + i;
        #pragma unroll
        for (int j = 0; j < TN; ++j) {
            const int n = n0 + tx * TN + j;
            float v = acc[i][j];
            if (bias) v += bias[n];
            if (OBF) ((unsigned short*)C)[(size_t)m * N + n] = f2bf(v);
            else     C[(size_t)m * N + n] = v;
        }
    }
}

// ---------------------------------------------------------------------------
// LayerNorm + hi/lo bf16 split.
// ---------------------------------------------------------------------------
__global__ __launch_bounds__(256) void ln_split_kernel(
    const float* __restrict__ X,
    unsigned short* __restrict__ Hi, unsigned short* __restrict__ Lo)
{
    const int row = blockIdx.x;
    const int t = threadIdx.x;
    float x = X[(size_t)row * DIM + t];

    float s1 = x, s2 = x * x;
    #pragma unroll
    for (int o = 32; o; o >>= 1) {
        s1 += __shfl_xor(s1, o);
        s2 += __shfl_xor(s2, o);
    }
    __shared__ float r1[4], r2[4];
    const int wid = t >> 6;
    if ((t & 63) == 0) { r1[wid] = s1; r2[wid] = s2; }
    __syncthreads();
    const float sum = r1[0] + r1[1] + r1[2] + r1[3];
    const float ssq = r2[0] + r2[1] + r2[2] + r2[3];
    const float mean = sum * (1.0f / DIM);
    const float var  = ssq * (1.0f / DIM) - mean * mean;
    const float y = (x - mean) * rsqrtf(var + 1e-5f);

    const unsigned short h = f2bf(y);
    Hi[(size_t)row * DIM + t] = h;
    Lo[(size_t)row * DIM + t] = f2bf(y - bf2f(h));
}

// ---------------------------------------------------------------------------
// V [8192,256] fp32 -> VT [256,8192] bf16.
// ---------------------------------------------------------------------------
__global__ __launch_bounds__(256) void vtrans_kernel(
    const float* __restrict__ V, unsigned short* __restrict__ VT)
{
    __shared__ float tile[64][65];
    const int r0 = blockIdx.x * 64;
    const int c0 = blockIdx.y * 64;
    const int t = threadIdx.x;
    #pragma unroll
    for (int i = 0; i < 4; ++i) {
        int r = i * 16 + (t >> 4);
        int c = (t & 15) * 4;
        float4 v = *(const float4*)&V[(size_t)(r0 + r) * DIM + c0 + c];
        tile[r][c] = v.x; tile[r][c + 1] = v.y;
        tile[r][c + 2] = v.z; tile[r][c + 3] = v.w;
    }
    __syncthreads();
    #pragma unroll
    for (int i = 0; i < 4; ++i) {
        int c = i * 16 + (t >> 4);
        int r = (t & 15) * 4;
        ushort4 o;
        o.x = f2bf(tile[r][c]);     o.y = f2bf(tile[r + 1][c]);
        o.z = f2bf(tile[r + 2][c]); o.w = f2bf(tile[r + 3][c]);
        *(ushort4*)&VT[(size_t)(c0 + c) * N_NODES + r0 + r] = o;
    }
}

// ---------------------------------------------------------------------------
// scores = Q @ K^T (split-bf16, 3 MFMA terms), global_load_lds staging,
// fused per-block softmax partial stats -> pstat[row][colblock].
// ---------------------------------------------------------------------------
__global__ __launch_bounds__(256) void qkt_kernel(
    const unsigned short* __restrict__ Qh, const unsigned short* __restrict__ Ql,
    const unsigned short* __restrict__ Kh, const unsigned short* __restrict__ Kl,
    float* __restrict__ S, float2* __restrict__ pstat)
{
    __shared__ short Ah[128][32], Al[128][32], Bh[128][32], Bl[128][32];
    __shared__ float2 ps[2][128];

    const int bid = blockIdx.x;
    const int wg = (bid & 7) * 512 + (bid >> 3);   // XCD swizzle (4096%8==0)
    const int mb = wg >> 6, nb = wg & 63;
    const int m0 = mb * 128, n0 = nb * 128;

    const int t = threadIdx.x, lane = t & 63, w = t >> 6;
    const int wm = w >> 1, wn = w & 1;
    const int fr = lane & 15, kb = lane >> 4;

    f32x4 acc[4][4] = {};

    for (int k0 = 0; k0 < DIM; k0 += 32) {
        #pragma unroll
        for (int r = 0; r < 2; ++r) {
            int c = r * 256 + t;
            int row = c >> 2, slot = c & 3;
            size_t ga = (size_t)(m0 + row) * DIM + k0 + slot * 8;
            size_t gb = (size_t)(n0 + row) * DIM + k0 + slot * 8;
            int lo = c * 16;
            gll16(Qh + ga, (char*)&Ah[0][0] + lo);
            gll16(Ql + ga, (char*)&Al[0][0] + lo);
            gll16(Kh + gb, (char*)&Bh[0][0] + lo);
            gll16(Kl + gb, (char*)&Bl[0][0] + lo);
        }
        __syncthreads();

        bf16x8 ah[4], al[4], bh[4], bl[4];
        #pragma unroll
        for (int m = 0; m < 4; ++m) {
            int row = wm * 64 + m * 16 + fr;
            ah[m] = *(const bf16x8*)&Ah[row][kb * 8];
            al[m] = *(const bf16x8*)&Al[row][kb * 8];
        }
        #pragma unroll
        for (int n = 0; n < 4; ++n) {
            int col = wn * 64 + n * 16 + fr;
            bh[n] = *(const bf16x8*)&Bh[col][kb * 8];
            bl[n] = *(const bf16x8*)&Bl[col][kb * 8];
        }
        #pragma unroll
        for (int m = 0; m < 4; ++m)
            #pragma unroll
            for (int n = 0; n < 4; ++n) {
                acc[m][n] = MFMA16(ah[m], bh[n], acc[m][n], 0, 0, 0);
                acc[m][n] = MFMA16(ah[m], bl[n], acc[m][n], 0, 0, 0);
                acc[m][n] = MFMA16(al[m], bh[n], acc[m][n], 0, 0, 0);
            }
        __syncthreads();
    }

    // ---- write raw scores
    #pragma unroll
    for (int m = 0; m < 4; ++m)
        #pragma unroll
        for (int e = 0; e < 4; ++e) {
            int row = m0 + wm * 64 + m * 16 + kb * 4 + e;
            #pragma unroll
            for (int n = 0; n < 4; ++n)
                S[(size_t)row * N_NODES + n0 + wn * 64 + n * 16 + fr] =
                    acc[m][n][e];
        }

    // ---- per-row (max, sumexp) over this block's 128 cols
    #pragma unroll
    for (int m = 0; m < 4; ++m)
        #pragma unroll
        for (int e = 0; e < 4; ++e) {
            float mx = acc[m][0][e];
            #pragma unroll
            for (int n = 1; n < 4; ++n) mx = fmaxf(mx, acc[m][n][e]);
            #pragma unroll
            for (int o = 1; o < 16; o <<= 1) mx = fmaxf(mx, __shfl_xor(mx, o));
            float se = 0.f;
            #pragma unroll
            for (int n = 0; n < 4; ++n) se += __expf(acc[m][n][e] - mx);
            #pragma unroll
            for (int o = 1; o < 16; o <<= 1) se += __shfl_xor(se, o);
            if (fr == 0) ps[wn][wm * 64 + m * 16 + kb * 4 + e] = make_float2(mx, se);
        }
    __syncthreads();
    if (t < 128) {
        float2 a = ps[0][t], b = ps[1][t];
        float gm = fmaxf(a.x, b.x);
        float gs = a.y * __expf(a.x - gm) + b.y * __expf(b.x - gm);
        pstat[(size_t)(m0 + t) * 64 + nb] = make_float2(gm, gs);
    }
}

// ---------------------------------------------------------------------------
// rstat[row] = (gmax, 1/gsum) from 64 pstat entries. 4 rows/block.
// ---------------------------------------------------------------------------
__global__ __launch_bounds__(256) void rstat_reduce_kernel(
    const float2* __restrict__ pstat, float2* __restrict__ rstat)
{
    const int row = blockIdx.x * 4 + (threadIdx.x >> 6);
    const int lane = threadIdx.x & 63;
    float2 v = pstat[(size_t)row * 64 + lane];
    float gm = v.x;
    #pragma unroll
    for (int o = 1; o < 64; o <<= 1) gm = fmaxf(gm, __shfl_xor(gm, o));
    float s = v.y * __expf(v.x - gm);
    #pragma unroll
    for (int o = 1; o < 64; o <<= 1) s += __shfl_xor(s, o);
    if (lane == 0) rstat[row] = make_float2(gm, 1.0f / s);
}

// ---------------------------------------------------------------------------
// Fused normalize + attn write + partial ZA.
// 16 rows/block, 4-way k-split -> 2048 blocks (8/CU) for latency hiding.
// As: [2][16][128] bf16, 16B-chunk XOR swizzle.
// ---------------------------------------------------------------------------
static __device__ __forceinline__ void norm_pack8(
    float* dst, unsigned short* rowbase, int chunk,
    float4 v0, float4 v1, float m, float inv)
{
    float p[8] = {v0.x, v0.y, v0.z, v0.w, v1.x, v1.y, v1.z, v1.w};
    #pragma unroll
    for (int j = 0; j < 8; ++j) p[j] = __expf(p[j] - m) * inv;
    *(float4*)(dst + 0) = make_float4(p[0], p[1], p[2], p[3]);
    *(float4*)(dst + 4) = make_float4(p[4], p[5], p[6], p[7]);
    unsigned int u[4];
    #pragma unroll
    for (int j = 0; j < 4; ++j)
        u[j] = (unsigned)f2bf(p[2 * j]) | ((unsigned)f2bf(p[2 * j + 1]) << 16);
    *(int4*)(rowbase + chunk * 8) = make_int4(u[0], u[1], u[2], u[3]);
}

__global__ __launch_bounds__(256) void av_kernel(
    float* S, const float2* __restrict__ rs, const unsigned short* __restrict__ VT,
    float* __restrict__ P0, float* __restrict__ P1,
    float* __restrict__ P2, float* __restrict__ P3)
{
    __shared__ unsigned short As[2][16][128];   // chunk-swizzled
    __shared__ float sm[16], si[16];

    const int r0 = blockIdx.x * 16;
    const int ks = blockIdx.y;
    const int kbase = ks * 2048;
    const int t = threadIdx.x, lane = t & 63, w = t >> 6;
    const int fr = lane & 15, kb = lane >> 4;

    if (t < 16) { float2 v = rs[r0 + t]; sm[t] = v.x; si[t] = v.y; }
    __syncthreads();

    const int ar = t >> 4, sl = t & 15;        // row, 16B-chunk slot
    const int xr = ar & 7;                     // write-side swizzle key
    const int xf = fr & 7;                     // read-side swizzle key
    const float m = sm[ar], inv = si[ar];
    float* arow = S + (size_t)(r0 + ar) * N_NODES + kbase + sl * 8;

    const unsigned short* vbase[4];
    #pragma unroll
    for (int n = 0; n < 4; ++n)
        vbase[n] = VT + (size_t)(w * 64 + n * 16 + fr) * N_NODES + kbase + kb * 8;

    f32x4 acc[4] = {};

    {   // stage step 0
        float4 v0 = *(const float4*)(arow + 0);
        float4 v1 = *(const float4*)(arow + 4);
        norm_pack8(arow, &As[0][ar][0], sl ^ xr, v0, v1, m, inv);
    }
    __syncthreads();

    for (int s = 0; s < 16; ++s) {
        const int b = s & 1;
        const bool more = (s + 1 < 16);
        float4 w0, w1;
        if (more) {
            const float* nx = arow + (s + 1) * 128;
            w0 = *(const float4*)(nx + 0);
            w1 = *(const float4*)(nx + 4);
        }
        // MFMA in two halves; each half prefetches its 8 B-fragments first
        #pragma unroll
        for (int h = 0; h < 2; ++h) {
            bf16x8 bb[2][4];
            #pragma unroll
            for (int k2 = 0; k2 < 2; ++k2)
                #pragma unroll
                for (int n = 0; n < 4; ++n)
                    bb[k2][n] = *(const bf16x8*)(vbase[n] + s * 128 + (h * 2 + k2) * 32);
            #pragma unroll
            for (int k2 = 0; k2 < 2; ++k2) {
                const int ksl = h * 2 + k2;
                const int ci = (((ksl * 4 + kb) ^ xf) & 15) * 8;
                bf16x8 a0 = *(const bf16x8*)&As[b][fr][ci];
                #pragma unroll
                for (int n = 0; n < 4; ++n)
                    acc[n] = MFMA16(a0, bb[k2][n], acc[n], 0, 0, 0);
            }
        }
        if (more)
            norm_pack8(arow + (s + 1) * 128, &As[b ^ 1][ar][0], sl ^ xr,
                       w0, w1, m, inv);
        __syncthreads();
    }

    float* P = (ks == 0) ? P0 : (ks == 1) ? P1 : (ks == 2) ? P2 : P3;
    #pragma unroll
    for (int e = 0; e < 4; ++e) {
        int row = r0 + kb * 4 + e;
        #pragma unroll
        for (int n = 0; n < 4; ++n)
            P[(size_t)row * DIM + w * 64 + n * 16 + fr] = acc[n][e];
    }
}

// ---------------------------------------------------------------------------
// SpMM: one 64-lane wave per node, lane holds 4 features (ushort4 loads).
// ---------------------------------------------------------------------------
__global__ __launch_bounds__(256) void spmm_kernel(
    const unsigned short* __restrict__ Hb, const int* __restrict__ erow,
    const int* __restrict__ ecol, const float* __restrict__ ew,
    float* __restrict__ out, int E)
{
    const int node = blockIdx.x * 4 + (threadIdx.x >> 6);
    const int lane = threadIdx.x & 63;

    int lo = 0, hi = E;
    while (lo < hi) { int mid = (lo + hi) >> 1; if (erow[mid] < node) lo = mid + 1; else hi = mid; }
    const int beg = lo;
    hi = E;
    while (lo < hi) { int mid = (lo + hi) >> 1; if (erow[mid] < node + 1) lo = mid + 1; else hi = mid; }
    const int end = lo;

    float4 acc = make_float4(0.f, 0.f, 0.f, 0.f);
    for (int e = beg; e < end; ++e) {
        const int col = ecol[e];
        const float wgt = ew[e];
        ushort4 h = *(const ushort4*)&Hb[(size_t)col * DIM + lane * 4];
        acc.x += wgt * bf2f(h.x);
        acc.y += wgt * bf2f(h.y);
        acc.z += wgt * bf2f(h.z);
        acc.w += wgt * bf2f(h.w);
    }
    *(float4*)&out[(size_t)node * DIM + lane * 4] = acc;
}

// ---------------------------------------------------------------------------
// Y = (0.5*(P0+P1+P2+P3) + 0.5*GNN) @ Wc + bc   (za_reduce fused in)
// ---------------------------------------------------------------------------
__global__ __launch_bounds__(256) void blend_cls_kernel(
    const float* __restrict__ p0, const float* __restrict__ p1,
    const float* __restrict__ p2, const float* __restrict__ p3,
    const float* __restrict__ gnn,
    const float* __restrict__ Wc, const float* __restrict__ bc,
    float* __restrict__ Y)
{
    const int row = blockIdx.x;
    const int t = threadIdx.x;
    __shared__ float z[DIM];
    __shared__ float part[4][NCLS];

    const size_t i = (size_t)row * DIM + t;
    z[t] = 0.5f * (p0[i] + p1[i] + p2[i] + p3[i] + gnn[i]);
    __syncthreads();

    if (t < 160) {
        const int c = t % NCLS, q = t / NCLS;
        float acc = 0.0f;
        #pragma unroll 4
        for (int d = q * 64; d < q * 64 + 64; ++d)
            acc += z[d] * Wc[d * NCLS + c];
        part[q][c] = acc;
    }
    __syncthreads();
    if (t < NCLS)
        Y[(size_t)row * NCLS + t] =
            part[0][t] + part[1][t] + part[2][t] + part[3][t] + bc[t];
}

// ---------------------------------------------------------------------------
extern "C" void kernel_launch(void* const* d_in, const int* in_sizes, int n_in,
                              void* d_out, int out_size, void* d_ws, size_t ws_size,
                              hipStream_t stream)
{
    const float* X     = (const float*)d_in[0];
    const int*   erow  = (const int*)d_in[1];
    const int*   ecol  = (const int*)d_in[2];
    const float* ew    = (const float*)d_in[3];
    const float* W_emb = (const float*)d_in[4];
    const float* b_emb = (const float*)d_in[5];
    const float* W_q   = (const float*)d_in[6];
    const float* b_q   = (const float*)d_in[7];
    const float* W_k   = (const float*)d_in[8];
    const float* b_k   = (const float*)d_in[9];
    const float* W_v   = (const float*)d_in[10];
    const float* b_v   = (const float*)d_in[11];
    const float* W_g   = (const float*)d_in[12];
    const float* b_g   = (const float*)d_in[13];
    const float* W_c   = (const float*)d_in[14];
    const float* b_c   = (const float*)d_in[15];
    const int E = in_sizes[1];

    float* Y    = (float*)d_out;
    float* Sc   = Y + (size_t)N_NODES * NCLS;      // scores -> attn [N,N]

    const size_t ND = (size_t)N_NODES * DIM;
    float* R0 = (float*)d_ws;      // Z0, later: VT (4MB) + pstat (4MB)
    float* R1 = R0 + ND;           // Qf, later ZA partial 0
    float* R2 = R1 + ND;           // Kf, later ZA partial 1
    float* R3 = R2 + ND;           // Vf, later ZA partial 2
    float* R4 = R3 + ND;           // Hb (bf16, 4MB) + rstat (at +4MB)
    float* R5 = R4 + ND;           // Qh/Ql, later GNN
    float* R6 = R5 + ND;           // Kh/Kl, later ZA partial 3

    unsigned short* Qh = (unsigned short*)R5;
    unsigned short* Ql = Qh + ND;
    unsigned short* Kh = (unsigned short*)R6;
    unsigned short* Kl = Kh + ND;
    unsigned short* VT = (unsigned short*)R0;
    unsigned short* Hb = (unsigned short*)R4;
    float2* pstat = (float2*)(R0 + ND / 2);        // 8192 x 64 float2 = 4MB
    float2* rstat = (float2*)(R4 + ND / 2);        // 8192 float2

    // 1. Z0 = X @ W_emb + b_emb
    gemm_kernel<128, 64, 16, 8, 4, false>
        <<<dim3(DIM / 64, N_NODES / 128), 256, 0, stream>>>(
            X, W_emb, b_emb, R0, N_NODES, DIM, F_IN);

    // 2. projections from Z0
    gemm_kernel<128, 64, 16, 8, 4, false>
        <<<dim3(DIM / 64, N_NODES / 128), 256, 0, stream>>>(
            R0, W_q, b_q, R1, N_NODES, DIM, DIM);
    gemm_kernel<128, 64, 16, 8, 4, false>
        <<<dim3(DIM / 64, N_NODES / 128), 256, 0, stream>>>(
            R0, W_k, b_k, R2, N_NODES, DIM, DIM);
    gemm_kernel<128, 64, 16, 8, 4, false>
        <<<dim3(DIM / 64, N_NODES / 128), 256, 0, stream>>>(
            R0, W_v, b_v, R3, N_NODES, DIM, DIM);
    gemm_kernel<128, 64, 16, 8, 4, true>
        <<<dim3(DIM / 64, N_NODES / 128), 256, 0, stream>>>(
            R0, W_g, b_g, (float*)Hb, N_NODES, DIM, DIM);

    // 3. LN + hi/lo split
    ln_split_kernel<<<N_NODES, 256, 0, stream>>>(R1, Qh, Ql);
    ln_split_kernel<<<N_NODES, 256, 0, stream>>>(R2, Kh, Kl);

    // 4. V -> VT bf16 (Z0/R0 dead now)
    vtrans_kernel<<<dim3(N_NODES / 64, DIM / 64), 256, 0, stream>>>(R3, VT);

    // 5. scores + fused softmax partial stats
    qkt_kernel<<<4096, 256, 0, stream>>>(Qh, Ql, Kh, Kl, Sc, pstat);

    // 6. reduce partial stats -> per-row (max, 1/sum)
    rstat_reduce_kernel<<<N_NODES / 4, 256, 0, stream>>>(pstat, rstat);

    // 7. fused normalize + attn write + partial ZA (16 rows x k-split 4)
    av_kernel<<<dim3(N_NODES / 16, 4), 256, 0, stream>>>(
        Sc, rstat, VT, R1, R2, R3, R6);

    // 8. GNN branch (bf16 H) -> R5
    spmm_kernel<<<N_NODES / 4, 256, 0, stream>>>(Hb, erow, ecol, ew, R5, E);

    // 9. blend (partials summed inline) + classifier
    blend_cls_kernel<<<N_NODES, 256, 0, stream>>>(
        R1, R2, R3, R6, R5, W_c, b_c, Y);
}

// Round 7
// 689.526 us; speedup vs baseline: 1.0687x; 1.0687x over previous
//
#include <hip/hip_runtime.h>
#include <hip/hip_bf16.h>

#define N_NODES 8192
#define F_IN    512
#define DIM     256
#define NCLS    40

typedef __attribute__((ext_vector_type(8))) short bf16x8;
typedef __attribute__((ext_vector_type(4))) float f32x4;

#define MFMA16 __builtin_amdgcn_mfma_f32_16x16x32_bf16

static __device__ __forceinline__ unsigned short f2bf(float x) {
    __hip_bfloat16 h = __float2bfloat16(x);
    return *reinterpret_cast<unsigned short*>(&h);
}
static __device__ __forceinline__ float bf2f(unsigned short u) {
    union { unsigned int u32; float f; } v; v.u32 = ((unsigned int)u) << 16;
    return v.f;
}
static __device__ __forceinline__ void gll16(const void* g, void* l) {
    __builtin_amdgcn_global_load_lds(
        (const __attribute__((address_space(1))) unsigned int*)g,
        (__attribute__((address_space(3))) unsigned int*)l, 16, 0, 0);
}

// ---------------------------------------------------------------------------
// fp32 tiled GEMM for the projections. OBF=true writes bf16 output.
// ---------------------------------------------------------------------------
template<int BM, int BN, int BK, int TM, int TN, bool OBF>
__global__ __launch_bounds__(256) void gemm_kernel(
    const float* __restrict__ A, const float* __restrict__ B,
    const float* __restrict__ bias, float* __restrict__ C,
    int M, int N, int K)
{
    static_assert((BM / TM) * (BN / TN) == 256, "256 threads");

    __shared__ float As[BK][BM];
    __shared__ float Bs[BK][BN];

    const int tid = threadIdx.x;
    const int tx  = tid % (BN / TN);
    const int ty  = tid / (BN / TN);
    const int n0  = blockIdx.x * BN;
    const int m0  = blockIdx.y * BM;

    float acc[TM][TN] = {};

    for (int k0 = 0; k0 < K; k0 += BK) {
        #pragma unroll
        for (int i = tid * 4; i < BM * BK; i += 1024) {
            int r = i / BK, c = i % BK;
            float4 v = *(const float4*)(A + (size_t)(m0 + r) * K + k0 + c);
            As[c + 0][r] = v.x; As[c + 1][r] = v.y;
            As[c + 2][r] = v.z; As[c + 3][r] = v.w;
        }
        #pragma unroll
        for (int i = tid * 4; i < BK * BN; i += 1024) {
            int r = i / BN, c = i % BN;
            *(float4*)&Bs[r][c] =
                *(const float4*)(B + (size_t)(k0 + r) * N + n0 + c);
        }
        __syncthreads();

        #pragma unroll
        for (int k = 0; k < BK; ++k) {
            float a[TM], b[TN];
            #pragma unroll
            for (int i = 0; i < TM; i += 4)
                *(float4*)&a[i] = *(const float4*)&As[k][ty * TM + i];
            #pragma unroll
            for (int j = 0; j < TN; j += 4)
                *(float4*)&b[j] = *(const float4*)&Bs[k][tx * TN + j];
            #pragma unroll
            for (int i = 0; i < TM; ++i)
                #pragma unroll
                for (int j = 0; j < TN; ++j)
                    acc[i][j] += a[i] * b[j];
        }
        __syncthreads();
    }

    #pragma unroll
    for (int i = 0; i < TM; ++i) {
        const int m = m0 + ty * TM + i;
        #pragma unroll
        for (int j = 0; j < TN; ++j) {
            const int n = n0 + tx * TN + j;
            float v = acc[i][j];
            if (bias) v += bias[n];
            if (OBF) ((unsigned short*)C)[(size_t)m * N + n] = f2bf(v);
            else     C[(size_t)m * N + n] = v;
        }
    }
}

// ---------------------------------------------------------------------------
// LayerNorm + hi/lo bf16 split.
// ---------------------------------------------------------------------------
__global__ __launch_bounds__(256) void ln_split_kernel(
    const float* __restrict__ X,
    unsigned short* __restrict__ Hi, unsigned short* __restrict__ Lo)
{
    const int row = blockIdx.x;
    const int t = threadIdx.x;
    float x = X[(size_t)row * DIM + t];

    float s1 = x, s2 = x * x;
    #pragma unroll
    for (int o = 32; o; o >>= 1) {
        s1 += __shfl_xor(s1, o);
        s2 += __shfl_xor(s2, o);
    }
    __shared__ float r1[4], r2[4];
    const int wid = t >> 6;
    if ((t & 63) == 0) { r1[wid] = s1; r2[wid] = s2; }
    __syncthreads();
    const float sum = r1[0] + r1[1] + r1[2] + r1[3];
    const float ssq = r2[0] + r2[1] + r2[2] + r2[3];
    const float mean = sum * (1.0f / DIM);
    const float var  = ssq * (1.0f / DIM) - mean * mean;
    const float y = (x - mean) * rsqrtf(var + 1e-5f);

    const unsigned short h = f2bf(y);
    Hi[(size_t)row * DIM + t] = h;
    Lo[(size_t)row * DIM + t] = f2bf(y - bf2f(h));
}

// ---------------------------------------------------------------------------
// V [8192,256] fp32 -> VT [256,8192] bf16.
// ---------------------------------------------------------------------------
__global__ __launch_bounds__(256) void vtrans_kernel(
    const float* __restrict__ V, unsigned short* __restrict__ VT)
{
    __shared__ float tile[64][65];
    const int r0 = blockIdx.x * 64;
    const int c0 = blockIdx.y * 64;
    const int t = threadIdx.x;
    #pragma unroll
    for (int i = 0; i < 4; ++i) {
        int r = i * 16 + (t >> 4);
        int c = (t & 15) * 4;
        float4 v = *(const float4*)&V[(size_t)(r0 + r) * DIM + c0 + c];
        tile[r][c] = v.x; tile[r][c + 1] = v.y;
        tile[r][c + 2] = v.z; tile[r][c + 3] = v.w;
    }
    __syncthreads();
    #pragma unroll
    for (int i = 0; i < 4; ++i) {
        int c = i * 16 + (t >> 4);
        int r = (t & 15) * 4;
        ushort4 o;
        o.x = f2bf(tile[r][c]);     o.y = f2bf(tile[r + 1][c]);
        o.z = f2bf(tile[r + 2][c]); o.w = f2bf(tile[r + 3][c]);
        *(ushort4*)&VT[(size_t)(c0 + c) * N_NODES + r0 + r] = o;
    }
}

// ---------------------------------------------------------------------------
// scores = Q @ K^T (split-bf16, 3 MFMA terms). Writes S = exp(s - m_block)
// fp32 plus per-(row,colblock) stats pstat = (m_block, sumexp_block).
// ---------------------------------------------------------------------------
__global__ __launch_bounds__(256) void qkt_kernel(
    const unsigned short* __restrict__ Qh, const unsigned short* __restrict__ Ql,
    const unsigned short* __restrict__ Kh, const unsigned short* __restrict__ Kl,
    float* __restrict__ S, float2* __restrict__ pstat)
{
    __shared__ short Ah[128][32], Al[128][32], Bh[128][32], Bl[128][32];
    __shared__ float2 ps[2][128];
    __shared__ float gmr[128];

    const int bid = blockIdx.x;
    const int wg = (bid & 7) * 512 + (bid >> 3);   // XCD swizzle (4096%8==0)
    const int mb = wg >> 6, nb = wg & 63;
    const int m0 = mb * 128, n0 = nb * 128;

    const int t = threadIdx.x, lane = t & 63, w = t >> 6;
    const int wm = w >> 1, wn = w & 1;
    const int fr = lane & 15, kb = lane >> 4;

    f32x4 acc[4][4] = {};

    for (int k0 = 0; k0 < DIM; k0 += 32) {
        #pragma unroll
        for (int r = 0; r < 2; ++r) {
            int c = r * 256 + t;
            int row = c >> 2, slot = c & 3;
            size_t ga = (size_t)(m0 + row) * DIM + k0 + slot * 8;
            size_t gb = (size_t)(n0 + row) * DIM + k0 + slot * 8;
            int lo = c * 16;
            gll16(Qh + ga, (char*)&Ah[0][0] + lo);
            gll16(Ql + ga, (char*)&Al[0][0] + lo);
            gll16(Kh + gb, (char*)&Bh[0][0] + lo);
            gll16(Kl + gb, (char*)&Bl[0][0] + lo);
        }
        __syncthreads();

        bf16x8 ah[4], al[4], bh[4], bl[4];
        #pragma unroll
        for (int m = 0; m < 4; ++m) {
            int row = wm * 64 + m * 16 + fr;
            ah[m] = *(const bf16x8*)&Ah[row][kb * 8];
            al[m] = *(const bf16x8*)&Al[row][kb * 8];
        }
        #pragma unroll
        for (int n = 0; n < 4; ++n) {
            int col = wn * 64 + n * 16 + fr;
            bh[n] = *(const bf16x8*)&Bh[col][kb * 8];
            bl[n] = *(const bf16x8*)&Bl[col][kb * 8];
        }
        #pragma unroll
        for (int m = 0; m < 4; ++m)
            #pragma unroll
            for (int n = 0; n < 4; ++n) {
                acc[m][n] = MFMA16(ah[m], bh[n], acc[m][n], 0, 0, 0);
                acc[m][n] = MFMA16(ah[m], bl[n], acc[m][n], 0, 0, 0);
                acc[m][n] = MFMA16(al[m], bh[n], acc[m][n], 0, 0, 0);
            }
        __syncthreads();
    }

    // ---- per-row (max, sumexp) over this block's 128 cols
    #pragma unroll
    for (int m = 0; m < 4; ++m)
        #pragma unroll
        for (int e = 0; e < 4; ++e) {
            float mx = acc[m][0][e];
            #pragma unroll
            for (int n = 1; n < 4; ++n) mx = fmaxf(mx, acc[m][n][e]);
            #pragma unroll
            for (int o = 1; o < 16; o <<= 1) mx = fmaxf(mx, __shfl_xor(mx, o));
            float se = 0.f;
            #pragma unroll
            for (int n = 0; n < 4; ++n) se += __expf(acc[m][n][e] - mx);
            #pragma unroll
            for (int o = 1; o < 16; o <<= 1) se += __shfl_xor(se, o);
            if (fr == 0) ps[wn][wm * 64 + m * 16 + kb * 4 + e] = make_float2(mx, se);
        }
    __syncthreads();
    if (t < 128) {
        float2 a = ps[0][t], b = ps[1][t];
        float gm = fmaxf(a.x, b.x);
        float gs = a.y * __expf(a.x - gm) + b.y * __expf(b.x - gm);
        pstat[(size_t)(m0 + t) * 64 + nb] = make_float2(gm, gs);
        gmr[t] = gm;
    }
    __syncthreads();

    // ---- write S = exp(s - m_block) (fp32)
    #pragma unroll
    for (int m = 0; m < 4; ++m)
        #pragma unroll
        for (int e = 0; e < 4; ++e) {
            const int rl = wm * 64 + m * 16 + kb * 4 + e;
            const float g = gmr[rl];
            #pragma unroll
            for (int n = 0; n < 4; ++n)
                S[(size_t)(m0 + rl) * N_NODES + n0 + wn * 64 + n * 16 + fr] =
                    __expf(acc[m][n][e] - g);
        }
}

// ---------------------------------------------------------------------------
// factab[row][cb] = exp(m_cb - m_row) / Z_row. 4 rows/block, 64 lanes/row.
// ---------------------------------------------------------------------------
__global__ __launch_bounds__(256) void factor_kernel(
    const float2* __restrict__ pstat, float* __restrict__ factab)
{
    const int row = blockIdx.x * 4 + (threadIdx.x >> 6);
    const int lane = threadIdx.x & 63;
    float2 v = pstat[(size_t)row * 64 + lane];
    float gm = v.x;
    #pragma unroll
    for (int o = 1; o < 64; o <<= 1) gm = fmaxf(gm, __shfl_xor(gm, o));
    float s = v.y * __expf(v.x - gm);
    #pragma unroll
    for (int o = 1; o < 64; o <<= 1) s += __shfl_xor(s, o);
    factab[(size_t)row * 64 + lane] = __expf(v.x - gm) / s;
}

// ---------------------------------------------------------------------------
// av: attn = S * factor (written fp32 in place) and partial ZA via MFMA.
// 64 rows/block, k-split 4 -> grid 512 = 2 blocks/CU, all resident.
// ---------------------------------------------------------------------------
__global__ __launch_bounds__(256, 2) void av_kernel(
    float* S, const float* __restrict__ factab,
    const unsigned short* __restrict__ VT,
    float* __restrict__ P0, float* __restrict__ P1,
    float* __restrict__ P2, float* __restrict__ P3)
{
    __shared__ unsigned short As[2][64][128];   // 16B-chunk XOR swizzled
    __shared__ float facs[64][16];

    const int bid = blockIdx.x;
    const int rb = bid >> 2, ks = bid & 3;
    const int r0 = rb * 64, kbase = ks * 2048, cb0 = ks * 16;
    const int t = threadIdx.x, lane = t & 63, w = t >> 6;
    const int fr = lane & 15, kb = lane >> 4;

    for (int i = t; i < 1024; i += 256)
        facs[i >> 4][i & 15] = factab[(size_t)(r0 + (i >> 4)) * 64 + cb0 + (i & 15)];

    const int ar = t >> 2, sl = t & 3;         // row 0..63, 32-col chunk 0..3
    const int key = ar & 7;
    float* arow = S + (size_t)(r0 + ar) * N_NODES + kbase + sl * 32;
    unsigned short* lrow = &As[0][ar][0];

    const unsigned short* vb[4];
    #pragma unroll
    for (int n = 0; n < 4; ++n)
        vb[n] = VT + (size_t)(w * 64 + n * 16 + fr) * N_NODES + kbase + kb * 8;

    f32x4 acc[4][4] = {};
    __syncthreads();   // facs ready

    float4 pv[8];
    #pragma unroll
    for (int j = 0; j < 8; ++j) pv[j] = *(const float4*)(arow + j * 4);
    {   // stage chunk 0: attn write + LDS pack
        const float fac = facs[ar][0];
        #pragma unroll
        for (int jj = 0; jj < 4; ++jj) {
            float a0 = pv[2*jj].x * fac,   a1 = pv[2*jj].y * fac;
            float a2 = pv[2*jj].z * fac,   a3 = pv[2*jj].w * fac;
            float a4 = pv[2*jj+1].x * fac, a5 = pv[2*jj+1].y * fac;
            float a6 = pv[2*jj+1].z * fac, a7 = pv[2*jj+1].w * fac;
            *(float4*)(arow + jj * 8)     = make_float4(a0, a1, a2, a3);
            *(float4*)(arow + jj * 8 + 4) = make_float4(a4, a5, a6, a7);
            unsigned int u0 = (unsigned)f2bf(a0) | ((unsigned)f2bf(a1) << 16);
            unsigned int u1 = (unsigned)f2bf(a2) | ((unsigned)f2bf(a3) << 16);
            unsigned int u2 = (unsigned)f2bf(a4) | ((unsigned)f2bf(a5) << 16);
            unsigned int u3 = (unsigned)f2bf(a6) | ((unsigned)f2bf(a7) << 16);
            *(int4*)(&As[0][ar][0] + (((sl * 4 + jj) ^ key) * 8)) =
                make_int4(u0, u1, u2, u3);
        }
    }
    __syncthreads();

    for (int s = 0; s < 16; ++s) {
        const int b = s & 1;
        const bool more = (s + 1 < 16);
        if (more) {
            #pragma unroll
            for (int j = 0; j < 8; ++j)
                pv[j] = *(const float4*)(arow + (s + 1) * 128 + j * 4);
        }
        // ---- MFMA over buffer b; B prefetched in batches of 8
        #pragma unroll
        for (int h = 0; h < 2; ++h) {
            bf16x8 bb[2][4];
            #pragma unroll
            for (int k2 = 0; k2 < 2; ++k2)
                #pragma unroll
                for (int n = 0; n < 4; ++n)
                    bb[k2][n] = *(const bf16x8*)(vb[n] + s * 128 + (h * 2 + k2) * 32);
            #pragma unroll
            for (int k2 = 0; k2 < 2; ++k2) {
                const int ksl = h * 2 + k2;
                bf16x8 a[4];
                #pragma unroll
                for (int m = 0; m < 4; ++m)
                    a[m] = *(const bf16x8*)&As[b][m * 16 + fr]
                              [((ksl * 4 + kb) ^ (fr & 7)) * 8];
                #pragma unroll
                for (int m = 0; m < 4; ++m)
                    #pragma unroll
                    for (int n = 0; n < 4; ++n)
                        acc[m][n] = MFMA16(a[m], bb[k2][n], acc[m][n], 0, 0, 0);
            }
        }
        // ---- stage chunk s+1 (attn write + LDS pack into buffer b^1)
        if (more) {
            const float fac = facs[ar][s + 1];
            float* aro = arow + (s + 1) * 128;
            #pragma unroll
            for (int jj = 0; jj < 4; ++jj) {
                float a0 = pv[2*jj].x * fac,   a1 = pv[2*jj].y * fac;
                float a2 = pv[2*jj].z * fac,   a3 = pv[2*jj].w * fac;
                float a4 = pv[2*jj+1].x * fac, a5 = pv[2*jj+1].y * fac;
                float a6 = pv[2*jj+1].z * fac, a7 = pv[2*jj+1].w * fac;
                *(float4*)(aro + jj * 8)     = make_float4(a0, a1, a2, a3);
                *(float4*)(aro + jj * 8 + 4) = make_float4(a4, a5, a6, a7);
                unsigned int u0 = (unsigned)f2bf(a0) | ((unsigned)f2bf(a1) << 16);
                unsigned int u1 = (unsigned)f2bf(a2) | ((unsigned)f2bf(a3) << 16);
                unsigned int u2 = (unsigned)f2bf(a4) | ((unsigned)f2bf(a5) << 16);
                unsigned int u3 = (unsigned)f2bf(a6) | ((unsigned)f2bf(a7) << 16);
                *(int4*)(&As[b ^ 1][ar][0] + (((sl * 4 + jj) ^ key) * 8)) =
                    make_int4(u0, u1, u2, u3);
            }
        }
        __syncthreads();
    }

    float* P = (ks == 0) ? P0 : (ks == 1) ? P1 : (ks == 2) ? P2 : P3;
    #pragma unroll
    for (int m = 0; m < 4; ++m)
        #pragma unroll
        for (int e = 0; e < 4; ++e) {
            int row = r0 + m * 16 + kb * 4 + e;
            #pragma unroll
            for (int n = 0; n < 4; ++n)
                P[(size_t)row * DIM + w * 64 + n * 16 + fr] = acc[m][n][e];
        }
}

// ---------------------------------------------------------------------------
// SpMM: one 64-lane wave per node, lane holds 4 features (ushort4 loads).
// ---------------------------------------------------------------------------
__global__ __launch_bounds__(256) void spmm_kernel(
    const unsigned short* __restrict__ Hb, const int* __restrict__ erow,
    const int* __restrict__ ecol, const float* __restrict__ ew,
    float* __restrict__ out, int E)
{
    const int node = blockIdx.x * 4 + (threadIdx.x >> 6);
    const int lane = threadIdx.x & 63;

    int lo = 0, hi = E;
    while (lo < hi) { int mid = (lo + hi) >> 1; if (erow[mid] < node) lo = mid + 1; else hi = mid; }
    const int beg = lo;
    hi = E;
    while (lo < hi) { int mid = (lo + hi) >> 1; if (erow[mid] < node + 1) lo = mid + 1; else hi = mid; }
    const int end = lo;

    float4 acc = make_float4(0.f, 0.f, 0.f, 0.f);
    for (int e = beg; e < end; ++e) {
        const int col = ecol[e];
        const float wgt = ew[e];
        ushort4 h = *(const ushort4*)&Hb[(size_t)col * DIM + lane * 4];
        acc.x += wgt * bf2f(h.x);
        acc.y += wgt * bf2f(h.y);
        acc.z += wgt * bf2f(h.z);
        acc.w += wgt * bf2f(h.w);
    }
    *(float4*)&out[(size_t)node * DIM + lane * 4] = acc;
}

// ---------------------------------------------------------------------------
// Y = (0.5*(P0+P1+P2+P3) + 0.5*GNN) @ Wc + bc
// ---------------------------------------------------------------------------
__global__ __launch_bounds__(256) void blend_cls_kernel(
    const float* __restrict__ p0, const float* __restrict__ p1,
    const float* __restrict__ p2, const float* __restrict__ p3,
    const float* __restrict__ gnn,
    const float* __restrict__ Wc, const float* __restrict__ bc,
    float* __restrict__ Y)
{
    const int row = blockIdx.x;
    const int t = threadIdx.x;
    __shared__ float z[DIM];
    __shared__ float part[4][NCLS];

    const size_t i = (size_t)row * DIM + t;
    z[t] = 0.5f * (p0[i] + p1[i] + p2[i] + p3[i] + gnn[i]);
    __syncthreads();

    if (t < 160) {
        const int c = t % NCLS, q = t / NCLS;
        float acc = 0.0f;
        #pragma unroll 4
        for (int d = q * 64; d < q * 64 + 64; ++d)
            acc += z[d] * Wc[d * NCLS + c];
        part[q][c] = acc;
    }
    __syncthreads();
    if (t < NCLS)
        Y[(size_t)row * NCLS + t] =
            part[0][t] + part[1][t] + part[2][t] + part[3][t] + bc[t];
}

// ---------------------------------------------------------------------------
extern "C" void kernel_launch(void* const* d_in, const int* in_sizes, int n_in,
                              void* d_out, int out_size, void* d_ws, size_t ws_size,
                              hipStream_t stream)
{
    const float* X     = (const float*)d_in[0];
    const int*   erow  = (const int*)d_in[1];
    const int*   ecol  = (const int*)d_in[2];
    const float* ew    = (const float*)d_in[3];
    const float* W_emb = (const float*)d_in[4];
    const float* b_emb = (const float*)d_in[5];
    const float* W_q   = (const float*)d_in[6];
    const float* b_q   = (const float*)d_in[7];
    const float* W_k   = (const float*)d_in[8];
    const float* b_k   = (const float*)d_in[9];
    const float* W_v   = (const float*)d_in[10];
    const float* b_v   = (const float*)d_in[11];
    const float* W_g   = (const float*)d_in[12];
    const float* b_g   = (const float*)d_in[13];
    const float* W_c   = (const float*)d_in[14];
    const float* b_c   = (const float*)d_in[15];
    const int E = in_sizes[1];

    float* Y    = (float*)d_out;
    float* Sc   = Y + (size_t)N_NODES * NCLS;      // exp-scores -> attn [N,N]

    const size_t ND = (size_t)N_NODES * DIM;
    float* R0 = (float*)d_ws;      // Z0, later: VT (4MB) + pstat (4MB)
    float* R1 = R0 + ND;           // Qf, later ZA partial 0
    float* R2 = R1 + ND;           // Kf, later ZA partial 1
    float* R3 = R2 + ND;           // Vf, later ZA partial 2
    float* R4 = R3 + ND;           // Hb (bf16, 4MB) + factab (2MB at +4MB)
    float* R5 = R4 + ND;           // Qh/Ql, later GNN
    float* R6 = R5 + ND;           // Kh/Kl, later ZA partial 3

    unsigned short* Qh = (unsigned short*)R5;
    unsigned short* Ql = Qh + ND;
    unsigned short* Kh = (unsigned short*)R6;
    unsigned short* Kl = Kh + ND;
    unsigned short* VT = (unsigned short*)R0;
    unsigned short* Hb = (unsigned short*)R4;
    float2* pstat = (float2*)(R0 + ND / 2);        // [8192][64] float2 = 4MB
    float*  factab = R4 + ND / 2;                  // [8192][64] float = 2MB

    // 1. Z0 = X @ W_emb + b_emb
    gemm_kernel<128, 64, 16, 8, 4, false>
        <<<dim3(DIM / 64, N_NODES / 128), 256, 0, stream>>>(
            X, W_emb, b_emb, R0, N_NODES, DIM, F_IN);

    // 2. projections from Z0
    gemm_kernel<128, 64, 16, 8, 4, false>
        <<<dim3(DIM / 64, N_NODES / 128), 256, 0, stream>>>(
            R0, W_q, b_q, R1, N_NODES, DIM, DIM);
    gemm_kernel<128, 64, 16, 8, 4, false>
        <<<dim3(DIM / 64, N_NODES / 128), 256, 0, stream>>>(
            R0, W_k, b_k, R2, N_NODES, DIM, DIM);
    gemm_kernel<128, 64, 16, 8, 4, false>
        <<<dim3(DIM / 64, N_NODES / 128), 256, 0, stream>>>(
            R0, W_v, b_v, R3, N_NODES, DIM, DIM);
    gemm_kernel<128, 64, 16, 8, 4, true>
        <<<dim3(DIM / 64, N_NODES / 128), 256, 0, stream>>>(
            R0, W_g, b_g, (float*)Hb, N_NODES, DIM, DIM);

    // 3. LN + hi/lo split
    ln_split_kernel<<<N_NODES, 256, 0, stream>>>(R1, Qh, Ql);
    ln_split_kernel<<<N_NODES, 256, 0, stream>>>(R2, Kh, Kl);

    // 4. V -> VT bf16 (Z0/R0 dead now)
    vtrans_kernel<<<dim3(N_NODES / 64, DIM / 64), 256, 0, stream>>>(R3, VT);

    // 5. S = exp(QK^T - m_block) + pstat
    qkt_kernel<<<4096, 256, 0, stream>>>(Qh, Ql, Kh, Kl, Sc, pstat);

    // 6. factor table
    factor_kernel<<<N_NODES / 4, 256, 0, stream>>>(pstat, factab);

    // 7. attn = S*factor (in place) + partial ZA  (64 rows x k-split 4)
    av_kernel<<<512, 256, 0, stream>>>(Sc, factab, VT, R1, R2, R3, R6);

    // 8. GNN branch (bf16 H) -> R5
    spmm_kernel<<<N_NODES / 4, 256, 0, stream>>>(Hb, erow, ecol, ew, R5, E);

    // 9. blend (partials summed inline) + classifier
    blend_cls_kernel<<<N_NODES, 256, 0, stream>>>(
        R1, R2, R3, R6, R5, W_c, b_c, Y);
}

// Round 8
// 597.774 us; speedup vs baseline: 1.2327x; 1.1535x over previous
//
#include <hip/hip_runtime.h>
#include <hip/hip_bf16.h>

#define N_NODES 8192
#define F_IN    512
#define DIM     256
#define NCLS    40

typedef __attribute__((ext_vector_type(8))) short bf16x8;
typedef __attribute__((ext_vector_type(4))) float f32x4;

#define MFMA16 __builtin_amdgcn_mfma_f32_16x16x32_bf16

static __device__ __forceinline__ unsigned short f2bf(float x) {
    __hip_bfloat16 h = __float2bfloat16(x);
    return *reinterpret_cast<unsigned short*>(&h);
}
static __device__ __forceinline__ float bf2f(unsigned short u) {
    union { unsigned int u32; float f; } v; v.u32 = ((unsigned int)u) << 16;
    return v.f;
}
static __device__ __forceinline__ void gll16(const void* g, void* l) {
    __builtin_amdgcn_global_load_lds(
        (const __attribute__((address_space(1))) unsigned int*)g,
        (__attribute__((address_space(3))) unsigned int*)l, 16, 0, 0);
}

// ---------------------------------------------------------------------------
// fp32 tiled GEMM for the projections. OBF=true writes bf16 output.
// ---------------------------------------------------------------------------
template<int BM, int BN, int BK, int TM, int TN, bool OBF>
__global__ __launch_bounds__(256) void gemm_kernel(
    const float* __restrict__ A, const float* __restrict__ B,
    const float* __restrict__ bias, float* __restrict__ C,
    int M, int N, int K)
{
    static_assert((BM / TM) * (BN / TN) == 256, "256 threads");

    __shared__ float As[BK][BM];
    __shared__ float Bs[BK][BN];

    const int tid = threadIdx.x;
    const int tx  = tid % (BN / TN);
    const int ty  = tid / (BN / TN);
    const int n0  = blockIdx.x * BN;
    const int m0  = blockIdx.y * BM;

    float acc[TM][TN] = {};

    for (int k0 = 0; k0 < K; k0 += BK) {
        #pragma unroll
        for (int i = tid * 4; i < BM * BK; i += 1024) {
            int r = i / BK, c = i % BK;
            float4 v = *(const float4*)(A + (size_t)(m0 + r) * K + k0 + c);
            As[c + 0][r] = v.x; As[c + 1][r] = v.y;
            As[c + 2][r] = v.z; As[c + 3][r] = v.w;
        }
        #pragma unroll
        for (int i = tid * 4; i < BK * BN; i += 1024) {
            int r = i / BN, c = i % BN;
            *(float4*)&Bs[r][c] =
                *(const float4*)(B + (size_t)(k0 + r) * N + n0 + c);
        }
        __syncthreads();

        #pragma unroll
        for (int k = 0; k < BK; ++k) {
            float a[TM], b[TN];
            #pragma unroll
            for (int i = 0; i < TM; i += 4)
                *(float4*)&a[i] = *(const float4*)&As[k][ty * TM + i];
            #pragma unroll
            for (int j = 0; j < TN; j += 4)
                *(float4*)&b[j] = *(const float4*)&Bs[k][tx * TN + j];
            #pragma unroll
            for (int i = 0; i < TM; ++i)
                #pragma unroll
                for (int j = 0; j < TN; ++j)
                    acc[i][j] += a[i] * b[j];
        }
        __syncthreads();
    }

    #pragma unroll
    for (int i = 0; i < TM; ++i) {
        const int m = m0 + ty * TM + i;
        #pragma unroll
        for (int j = 0; j < TN; ++j) {
            const int n = n0 + tx * TN + j;
            float v = acc[i][j];
            if (bias) v += bias[n];
            if (OBF) ((unsigned short*)C)[(size_t)m * N + n] = f2bf(v);
            else     C[(size_t)m * N + n] = v;
        }
    }
}

// ---------------------------------------------------------------------------
// LayerNorm + hi/lo bf16 split.
// ---------------------------------------------------------------------------
__global__ __launch_bounds__(256) void ln_split_kernel(
    const float* __restrict__ X,
    unsigned short* __restrict__ Hi, unsigned short* __restrict__ Lo)
{
    const int row = blockIdx.x;
    const int t = threadIdx.x;
    float x = X[(size_t)row * DIM + t];

    float s1 = x, s2 = x * x;
    #pragma unroll
    for (int o = 32; o; o >>= 1) {
        s1 += __shfl_xor(s1, o);
        s2 += __shfl_xor(s2, o);
    }
    __shared__ float r1[4], r2[4];
    const int wid = t >> 6;
    if ((t & 63) == 0) { r1[wid] = s1; r2[wid] = s2; }
    __syncthreads();
    const float sum = r1[0] + r1[1] + r1[2] + r1[3];
    const float ssq = r2[0] + r2[1] + r2[2] + r2[3];
    const float mean = sum * (1.0f / DIM);
    const float var  = ssq * (1.0f / DIM) - mean * mean;
    const float y = (x - mean) * rsqrtf(var + 1e-5f);

    const unsigned short h = f2bf(y);
    Hi[(size_t)row * DIM + t] = h;
    Lo[(size_t)row * DIM + t] = f2bf(y - bf2f(h));
}

// ---------------------------------------------------------------------------
// V [8192,256] fp32 -> VT [256,8192] bf16.
// ---------------------------------------------------------------------------
__global__ __launch_bounds__(256) void vtrans_kernel(
    const float* __restrict__ V, unsigned short* __restrict__ VT)
{
    __shared__ float tile[64][65];
    const int r0 = blockIdx.x * 64;
    const int c0 = blockIdx.y * 64;
    const int t = threadIdx.x;
    #pragma unroll
    for (int i = 0; i < 4; ++i) {
        int r = i * 16 + (t >> 4);
        int c = (t & 15) * 4;
        float4 v = *(const float4*)&V[(size_t)(r0 + r) * DIM + c0 + c];
        tile[r][c] = v.x; tile[r][c + 1] = v.y;
        tile[r][c + 2] = v.z; tile[r][c + 3] = v.w;
    }
    __syncthreads();
    #pragma unroll
    for (int i = 0; i < 4; ++i) {
        int c = i * 16 + (t >> 4);
        int r = (t & 15) * 4;
        ushort4 o;
        o.x = f2bf(tile[r][c]);     o.y = f2bf(tile[r + 1][c]);
        o.z = f2bf(tile[r + 2][c]); o.w = f2bf(tile[r + 3][c]);
        *(ushort4*)&VT[(size_t)(c0 + c) * N_NODES + r0 + r] = o;
    }
}

// ---------------------------------------------------------------------------
// scores = Q @ K^T (split-bf16, 3 MFMA terms). Writes Sb = bf16 exp(s-m_blk)
// into the first half of each attn row slot (row stride 16384 ushorts),
// plus per-(row,colblock) stats pstat = (m_block, sumexp_block).
// ---------------------------------------------------------------------------
__global__ __launch_bounds__(256) void qkt_kernel(
    const unsigned short* __restrict__ Qh, const unsigned short* __restrict__ Ql,
    const unsigned short* __restrict__ Kh, const unsigned short* __restrict__ Kl,
    unsigned short* __restrict__ Sb, float2* __restrict__ pstat)
{
    __shared__ short stage[4][128][32];   // Ah/Al/Bh/Bl; reused as bf16 out-tile
    __shared__ float2 ps[2][128];
    __shared__ float gmr[128];

    const int bid = blockIdx.x;
    const int wg = (bid & 7) * 512 + (bid >> 3);   // XCD swizzle (4096%8==0)
    const int mb = wg >> 6, nb = wg & 63;
    const int m0 = mb * 128, n0 = nb * 128;

    const int t = threadIdx.x, lane = t & 63, w = t >> 6;
    const int wm = w >> 1, wn = w & 1;
    const int fr = lane & 15, kb = lane >> 4;

    f32x4 acc[4][4] = {};

    for (int k0 = 0; k0 < DIM; k0 += 32) {
        #pragma unroll
        for (int r = 0; r < 2; ++r) {
            int c = r * 256 + t;
            int row = c >> 2, slot = c & 3;
            size_t ga = (size_t)(m0 + row) * DIM + k0 + slot * 8;
            size_t gb = (size_t)(n0 + row) * DIM + k0 + slot * 8;
            int lo = c * 16;
            gll16(Qh + ga, (char*)&stage[0][0][0] + lo);
            gll16(Ql + ga, (char*)&stage[1][0][0] + lo);
            gll16(Kh + gb, (char*)&stage[2][0][0] + lo);
            gll16(Kl + gb, (char*)&stage[3][0][0] + lo);
        }
        __syncthreads();

        bf16x8 ah[4], al[4], bh[4], bl[4];
        #pragma unroll
        for (int m = 0; m < 4; ++m) {
            int row = wm * 64 + m * 16 + fr;
            ah[m] = *(const bf16x8*)&stage[0][row][kb * 8];
            al[m] = *(const bf16x8*)&stage[1][row][kb * 8];
        }
        #pragma unroll
        for (int n = 0; n < 4; ++n) {
            int col = wn * 64 + n * 16 + fr;
            bh[n] = *(const bf16x8*)&stage[2][col][kb * 8];
            bl[n] = *(const bf16x8*)&stage[3][col][kb * 8];
        }
        #pragma unroll
        for (int m = 0; m < 4; ++m)
            #pragma unroll
            for (int n = 0; n < 4; ++n) {
                acc[m][n] = MFMA16(ah[m], bh[n], acc[m][n], 0, 0, 0);
                acc[m][n] = MFMA16(ah[m], bl[n], acc[m][n], 0, 0, 0);
                acc[m][n] = MFMA16(al[m], bh[n], acc[m][n], 0, 0, 0);
            }
        __syncthreads();
    }

    // ---- per-row (max, sumexp) over this block's 128 cols
    #pragma unroll
    for (int m = 0; m < 4; ++m)
        #pragma unroll
        for (int e = 0; e < 4; ++e) {
            float mx = acc[m][0][e];
            #pragma unroll
            for (int n = 1; n < 4; ++n) mx = fmaxf(mx, acc[m][n][e]);
            #pragma unroll
            for (int o = 1; o < 16; o <<= 1) mx = fmaxf(mx, __shfl_xor(mx, o));
            float se = 0.f;
            #pragma unroll
            for (int n = 0; n < 4; ++n) se += __expf(acc[m][n][e] - mx);
            #pragma unroll
            for (int o = 1; o < 16; o <<= 1) se += __shfl_xor(se, o);
            if (fr == 0) ps[wn][wm * 64 + m * 16 + kb * 4 + e] = make_float2(mx, se);
        }
    __syncthreads();
    if (t < 128) {
        float2 a = ps[0][t], b = ps[1][t];
        float gm = fmaxf(a.x, b.x);
        float gs = a.y * __expf(a.x - gm) + b.y * __expf(b.x - gm);
        pstat[(size_t)(m0 + t) * 64 + nb] = make_float2(gm, gs);
        gmr[t] = gm;
    }
    __syncthreads();

    // ---- exp -> bf16 tile in LDS (staging memory is dead now)
    unsigned short* tile = (unsigned short*)&stage[0][0][0];   // [128][128]
    #pragma unroll
    for (int m = 0; m < 4; ++m)
        #pragma unroll
        for (int e = 0; e < 4; ++e) {
            const int rl = wm * 64 + m * 16 + kb * 4 + e;
            const float g = gmr[rl];
            #pragma unroll
            for (int n = 0; n < 4; ++n)
                tile[rl * 128 + wn * 64 + n * 16 + fr] =
                    f2bf(__expf(acc[m][n][e] - g));
        }
    __syncthreads();

    // ---- coalesced bf16 store: row stride 16384 ushorts (32KB attn slot)
    #pragma unroll
    for (int p = 0; p < 8; ++p) {
        int c = p * 256 + t;            // 16B chunk id (2048 total)
        int r = c >> 4, sl = c & 15;
        *(int4*)&Sb[(size_t)(m0 + r) * 16384 + n0 + sl * 8] =
            *(const int4*)((const char*)tile + c * 16);
    }
}

// ---------------------------------------------------------------------------
// factab[row][cb] = exp(m_cb - m_row) / Z_row. 4 rows/block, 64 lanes/row.
// ---------------------------------------------------------------------------
__global__ __launch_bounds__(256) void factor_kernel(
    const float2* __restrict__ pstat, float* __restrict__ factab)
{
    const int row = blockIdx.x * 4 + (threadIdx.x >> 6);
    const int lane = threadIdx.x & 63;
    float2 v = pstat[(size_t)row * 64 + lane];
    float gm = v.x;
    #pragma unroll
    for (int o = 1; o < 64; o <<= 1) gm = fmaxf(gm, __shfl_xor(gm, o));
    float s = v.y * __expf(v.x - gm);
    #pragma unroll
    for (int o = 1; o < 64; o <<= 1) s += __shfl_xor(s, o);
    factab[(size_t)row * 64 + lane] = __expf(v.x - gm) / s;
}

// ---------------------------------------------------------------------------
// av_mfma: ZA partials = (factor * Sb) @ VT^T via per-step scaled MFMA.
// 64 rows/block, k-split 4 -> 512 blocks. A staged by gll16 (linear LDS,
// XOR-pre-swizzled global source); factor applied post-MFMA per step.
// ---------------------------------------------------------------------------
__global__ __launch_bounds__(256, 2) void av_mfma_kernel(
    const unsigned short* __restrict__ Sb, const float* __restrict__ factab,
    const unsigned short* __restrict__ VT,
    float* __restrict__ P0, float* __restrict__ P1,
    float* __restrict__ P2, float* __restrict__ P3)
{
    __shared__ unsigned short As[2][64][128];   // linear dest, swizzled source
    __shared__ float facsT[16][64];             // [local cb][row]

    const int bid = blockIdx.x;
    const int rb = bid >> 2, ks = bid & 3;
    const int r0 = rb * 64, kbase = ks * 2048, cb0 = ks * 16;
    const int t = threadIdx.x, lane = t & 63, w = t >> 6;
    const int fr = lane & 15, kb = lane >> 4;

    for (int i = t; i < 1024; i += 256)
        facsT[i >> 6][i & 63] =
            factab[(size_t)(r0 + (i & 63)) * 64 + cb0 + (i >> 6)];

    const unsigned short* vb[4];
    #pragma unroll
    for (int n = 0; n < 4; ++n)
        vb[n] = VT + (size_t)(w * 64 + n * 16 + fr) * N_NODES + kbase + kb * 8;

    #define STAGE(S_, BUF_) do {                                              \
        _Pragma("unroll")                                                     \
        for (int p = 0; p < 4; ++p) {                                         \
            int c = p * 256 + t;                                              \
            int rr = c >> 4, sl = c & 15;                                     \
            int slp = sl ^ (rr & 7);                                          \
            gll16(Sb + (size_t)(r0 + rr) * 16384 + kbase + (S_) * 128 + slp * 8, \
                  (char*)&As[BUF_][0][0] + c * 16);                           \
        } } while (0)

    f32x4 acc[4][4] = {};
    const f32x4 z4 = {0.f, 0.f, 0.f, 0.f};

    STAGE(0, 0);
    __syncthreads();

    for (int s = 0; s < 16; ++s) {
        const int b = s & 1;
        if (s + 1 < 16) STAGE(s + 1, b ^ 1);

        bf16x8 bb[4][4];
        #pragma unroll
        for (int ksl = 0; ksl < 4; ++ksl)
            #pragma unroll
            for (int n = 0; n < 4; ++n)
                bb[ksl][n] = *(const bf16x8*)(vb[n] + s * 128 + ksl * 32);

        const char* abase = (const char*)&As[b][0][0];
        #pragma unroll
        for (int m = 0; m < 4; ++m) {
            f32x4 sacc[4];
            {
                bf16x8 a = *(const bf16x8*)(abase + (m * 16 + fr) * 256 +
                                            ((kb ^ (fr & 7)) * 16));
                #pragma unroll
                for (int n = 0; n < 4; ++n)
                    sacc[n] = MFMA16(a, bb[0][n], z4, 0, 0, 0);
            }
            #pragma unroll
            for (int ksl = 1; ksl < 4; ++ksl) {
                bf16x8 a = *(const bf16x8*)(abase + (m * 16 + fr) * 256 +
                                            (((ksl * 4 + kb) ^ (fr & 7)) * 16));
                #pragma unroll
                for (int n = 0; n < 4; ++n)
                    sacc[n] = MFMA16(a, bb[ksl][n], sacc[n], 0, 0, 0);
            }
            f32x4 fac = *(const f32x4*)&facsT[s][m * 16 + kb * 4];
            #pragma unroll
            for (int n = 0; n < 4; ++n)
                acc[m][n] += fac * sacc[n];
        }
        __syncthreads();
    }
    #undef STAGE

    float* P = (ks == 0) ? P0 : (ks == 1) ? P1 : (ks == 2) ? P2 : P3;
    #pragma unroll
    for (int m = 0; m < 4; ++m)
        #pragma unroll
        for (int e = 0; e < 4; ++e) {
            int row = r0 + m * 16 + kb * 4 + e;
            #pragma unroll
            for (int n = 0; n < 4; ++n)
                P[(size_t)row * DIM + w * 64 + n * 16 + fr] = acc[m][n][e];
        }
}

// ---------------------------------------------------------------------------
// scale: attn[row] = bf2f(Sb[row]) * factor, written fp32 IN PLACE over the
// same row slot (Sb occupies the first 16KB of each 32KB attn row).
// Whole row staged in LDS before any write -> safe expansion.
// ---------------------------------------------------------------------------
__global__ __launch_bounds__(256) void scale_kernel(
    const unsigned short* __restrict__ Sb, const float* __restrict__ factab,
    float* __restrict__ attn)
{
    __shared__ unsigned short srow[N_NODES];
    __shared__ float fr_[64];
    const int row = blockIdx.x;
    const int t = threadIdx.x;

    if (t < 64) fr_[t] = factab[(size_t)row * 64 + t];
    const unsigned short* src = Sb + (size_t)row * 16384;
    #pragma unroll
    for (int p = 0; p < 4; ++p) {
        int c = (p * 256 + t) * 8;
        *(int4*)&srow[c] = *(const int4*)&src[c];
    }
    __syncthreads();

    float* dst = attn + (size_t)row * N_NODES;
    #pragma unroll
    for (int p = 0; p < 4; ++p) {
        int c = (p * 256 + t) * 8;
        const float f = fr_[c >> 7];
        int4 v = *(const int4*)&srow[c];
        float4 o0, o1;
        o0.x = bf2f((unsigned short)(v.x & 0xffff)) * f;
        o0.y = bf2f((unsigned short)((unsigned)v.x >> 16)) * f;
        o0.z = bf2f((unsigned short)(v.y & 0xffff)) * f;
        o0.w = bf2f((unsigned short)((unsigned)v.y >> 16)) * f;
        o1.x = bf2f((unsigned short)(v.z & 0xffff)) * f;
        o1.y = bf2f((unsigned short)((unsigned)v.z >> 16)) * f;
        o1.z = bf2f((unsigned short)(v.w & 0xffff)) * f;
        o1.w = bf2f((unsigned short)((unsigned)v.w >> 16)) * f;
        *(float4*)(dst + c)     = o0;
        *(float4*)(dst + c + 4) = o1;
    }
}

// ---------------------------------------------------------------------------
// SpMM: one 64-lane wave per node, lane holds 4 features (ushort4 loads).
// ---------------------------------------------------------------------------
__global__ __launch_bounds__(256) void spmm_kernel(
    const unsigned short* __restrict__ Hb, const int* __restrict__ erow,
    const int* __restrict__ ecol, const float* __restrict__ ew,
    float* __restrict__ out, int E)
{
    const int node = blockIdx.x * 4 + (threadIdx.x >> 6);
    const int lane = threadIdx.x & 63;

    int lo = 0, hi = E;
    while (lo < hi) { int mid = (lo + hi) >> 1; if (erow[mid] < node) lo = mid + 1; else hi = mid; }
    const int beg = lo;
    hi = E;
    while (lo < hi) { int mid = (lo + hi) >> 1; if (erow[mid] < node + 1) lo = mid + 1; else hi = mid; }
    const int end = lo;

    float4 acc = make_float4(0.f, 0.f, 0.f, 0.f);
    for (int e = beg; e < end; ++e) {
        const int col = ecol[e];
        const float wgt = ew[e];
        ushort4 h = *(const ushort4*)&Hb[(size_t)col * DIM + lane * 4];
        acc.x += wgt * bf2f(h.x);
        acc.y += wgt * bf2f(h.y);
        acc.z += wgt * bf2f(h.z);
        acc.w += wgt * bf2f(h.w);
    }
    *(float4*)&out[(size_t)node * DIM + lane * 4] = acc;
}

// ---------------------------------------------------------------------------
// Y = (0.5*(P0+P1+P2+P3) + 0.5*GNN) @ Wc + bc
// ---------------------------------------------------------------------------
__global__ __launch_bounds__(256) void blend_cls_kernel(
    const float* __restrict__ p0, const float* __restrict__ p1,
    const float* __restrict__ p2, const float* __restrict__ p3,
    const float* __restrict__ gnn,
    const float* __restrict__ Wc, const float* __restrict__ bc,
    float* __restrict__ Y)
{
    const int row = blockIdx.x;
    const int t = threadIdx.x;
    __shared__ float z[DIM];
    __shared__ float part[4][NCLS];

    const size_t i = (size_t)row * DIM + t;
    z[t] = 0.5f * (p0[i] + p1[i] + p2[i] + p3[i] + gnn[i]);
    __syncthreads();

    if (t < 160) {
        const int c = t % NCLS, q = t / NCLS;
        float acc = 0.0f;
        #pragma unroll 4
        for (int d = q * 64; d < q * 64 + 64; ++d)
            acc += z[d] * Wc[d * NCLS + c];
        part[q][c] = acc;
    }
    __syncthreads();
    if (t < NCLS)
        Y[(size_t)row * NCLS + t] =
            part[0][t] + part[1][t] + part[2][t] + part[3][t] + bc[t];
}

// ---------------------------------------------------------------------------
extern "C" void kernel_launch(void* const* d_in, const int* in_sizes, int n_in,
                              void* d_out, int out_size, void* d_ws, size_t ws_size,
                              hipStream_t stream)
{
    const float* X     = (const float*)d_in[0];
    const int*   erow  = (const int*)d_in[1];
    const int*   ecol  = (const int*)d_in[2];
    const float* ew    = (const float*)d_in[3];
    const float* W_emb = (const float*)d_in[4];
    const float* b_emb = (const float*)d_in[5];
    const float* W_q   = (const float*)d_in[6];
    const float* b_q   = (const float*)d_in[7];
    const float* W_k   = (const float*)d_in[8];
    const float* b_k   = (const float*)d_in[9];
    const float* W_v   = (const float*)d_in[10];
    const float* b_v   = (const float*)d_in[11];
    const float* W_g   = (const float*)d_in[12];
    const float* b_g   = (const float*)d_in[13];
    const float* W_c   = (const float*)d_in[14];
    const float* b_c   = (const float*)d_in[15];
    const int E = in_sizes[1];

    float* Y    = (float*)d_out;
    float* Sc   = Y + (size_t)N_NODES * NCLS;      // attn [N,N]; Sb packed in row slots
    unsigned short* Sb = (unsigned short*)Sc;      // row r at ushort offset r*16384

    const size_t ND = (size_t)N_NODES * DIM;
    float* R0 = (float*)d_ws;      // Z0, later: VT (4MB) + pstat (4MB)
    float* R1 = R0 + ND;           // Qf, later ZA partial 0
    float* R2 = R1 + ND;           // Kf, later ZA partial 1
    float* R3 = R2 + ND;           // Vf, later ZA partial 2
    float* R4 = R3 + ND;           // Hb (bf16, 4MB) + factab (2MB at +4MB)
    float* R5 = R4 + ND;           // Qh/Ql, later GNN
    float* R6 = R5 + ND;           // Kh/Kl, later ZA partial 3

    unsigned short* Qh = (unsigned short*)R5;
    unsigned short* Ql = Qh + ND;
    unsigned short* Kh = (unsigned short*)R6;
    unsigned short* Kl = Kh + ND;
    unsigned short* VT = (unsigned short*)R0;
    unsigned short* Hb = (unsigned short*)R4;
    float2* pstat = (float2*)(R0 + ND / 2);        // [8192][64] float2 = 4MB
    float*  factab = R4 + ND / 2;                  // [8192][64] float = 2MB

    // 1. Z0 = X @ W_emb + b_emb
    gemm_kernel<128, 64, 16, 8, 4, false>
        <<<dim3(DIM / 64, N_NODES / 128), 256, 0, stream>>>(
            X, W_emb, b_emb, R0, N_NODES, DIM, F_IN);

    // 2. projections from Z0
    gemm_kernel<128, 64, 16, 8, 4, false>
        <<<dim3(DIM / 64, N_NODES / 128), 256, 0, stream>>>(
            R0, W_q, b_q, R1, N_NODES, DIM, DIM);
    gemm_kernel<128, 64, 16, 8, 4, false>
        <<<dim3(DIM / 64, N_NODES / 128), 256, 0, stream>>>(
            R0, W_k, b_k, R2, N_NODES, DIM, DIM);
    gemm_kernel<128, 64, 16, 8, 4, false>
        <<<dim3(DIM / 64, N_NODES / 128), 256, 0, stream>>>(
            R0, W_v, b_v, R3, N_NODES, DIM, DIM);
    gemm_kernel<128, 64, 16, 8, 4, true>
        <<<dim3(DIM / 64, N_NODES / 128), 256, 0, stream>>>(
            R0, W_g, b_g, (float*)Hb, N_NODES, DIM, DIM);

    // 3. LN + hi/lo split
    ln_split_kernel<<<N_NODES, 256, 0, stream>>>(R1, Qh, Ql);
    ln_split_kernel<<<N_NODES, 256, 0, stream>>>(R2, Kh, Kl);

    // 4. V -> VT bf16 (Z0/R0 dead now)
    vtrans_kernel<<<dim3(N_NODES / 64, DIM / 64), 256, 0, stream>>>(R3, VT);

    // 5. Sb = bf16 exp(QK^T - m_block) + pstat
    qkt_kernel<<<4096, 256, 0, stream>>>(Qh, Ql, Kh, Kl, Sb, pstat);

    // 6. factor table
    factor_kernel<<<N_NODES / 4, 256, 0, stream>>>(pstat, factab);

    // 7. ZA partials = (factor * Sb) @ V   (reads Sb, must precede scale)
    av_mfma_kernel<<<512, 256, 0, stream>>>(
        Sb, factab, VT, R1, R2, R3, R6);

    // 8. attn = bf2f(Sb) * factor, fp32 in place
    scale_kernel<<<N_NODES, 256, 0, stream>>>(Sb, factab, Sc);

    // 9. GNN branch (bf16 H) -> R5
    spmm_kernel<<<N_NODES / 4, 256, 0, stream>>>(Hb, erow, ecol, ew, R5, E);

    // 10. blend (partials summed inline) + classifier
    blend_cls_kernel<<<N_NODES, 256, 0, stream>>>(
        R1, R2, R3, R6, R5, W_c, b_c, Y);
}

// Round 9
// 476.355 us; speedup vs baseline: 1.5469x; 1.2549x over previous
//
#include <hip/hip_runtime.h>
#include <hip/hip_bf16.h>

#define N_NODES 8192
#define F_IN    512
#define DIM     256
#define NCLS    40

typedef __attribute__((ext_vector_type(8))) short bf16x8;
typedef __attribute__((ext_vector_type(4))) float f32x4;

#define MFMA16 __builtin_amdgcn_mfma_f32_16x16x32_bf16

static __device__ __forceinline__ unsigned short f2bf(float x) {
    __hip_bfloat16 h = __float2bfloat16(x);
    return *reinterpret_cast<unsigned short*>(&h);
}
static __device__ __forceinline__ float bf2f(unsigned short u) {
    union { unsigned int u32; float f; } v; v.u32 = ((unsigned int)u) << 16;
    return v.f;
}
static __device__ __forceinline__ void gll16(const void* g, void* l) {
    __builtin_amdgcn_global_load_lds(
        (const __attribute__((address_space(1))) unsigned int*)g,
        (__attribute__((address_space(3))) unsigned int*)l, 16, 0, 0);
}

// ---------------------------------------------------------------------------
// split: fp32 -> (hi, lo) bf16 pair, elementwise. 4 elems/thread.
// ---------------------------------------------------------------------------
__global__ __launch_bounds__(256) void split_kernel(
    const float* __restrict__ X,
    unsigned short* __restrict__ Xh, unsigned short* __restrict__ Xl)
{
    const size_t i = ((size_t)blockIdx.x * 256 + threadIdx.x) * 4;
    float4 v = *(const float4*)&X[i];
    ushort4 h, l;
    h.x = f2bf(v.x); l.x = f2bf(v.x - bf2f(h.x));
    h.y = f2bf(v.y); l.y = f2bf(v.y - bf2f(h.y));
    h.z = f2bf(v.z); l.z = f2bf(v.z - bf2f(h.z));
    h.w = f2bf(v.w); l.w = f2bf(v.w - bf2f(h.w));
    *(ushort4*)&Xh[i] = h;
    *(ushort4*)&Xl[i] = l;
}

// ---------------------------------------------------------------------------
// wtrans: W fp32 [K,N] -> WT hi/lo bf16 [N,K]. 64x64 LDS transpose tiles.
// ---------------------------------------------------------------------------
__global__ __launch_bounds__(256) void wtrans_kernel(
    const float* __restrict__ W,
    unsigned short* __restrict__ WTh, unsigned short* __restrict__ WTl,
    int K, int N)
{
    __shared__ float tile[64][65];
    const int r0 = blockIdx.x * 64;   // K dim
    const int c0 = blockIdx.y * 64;   // N dim
    const int t = threadIdx.x;
    #pragma unroll
    for (int i = 0; i < 4; ++i) {
        int r = i * 16 + (t >> 4);
        int c = (t & 15) * 4;
        float4 v = *(const float4*)&W[(size_t)(r0 + r) * N + c0 + c];
        tile[r][c] = v.x; tile[r][c + 1] = v.y;
        tile[r][c + 2] = v.z; tile[r][c + 3] = v.w;
    }
    __syncthreads();
    #pragma unroll
    for (int i = 0; i < 4; ++i) {
        int c = i * 16 + (t >> 4);    // N-local
        int r = (t & 15) * 4;         // K-local
        ushort4 h, l;
        float x0 = tile[r][c],     x1 = tile[r + 1][c];
        float x2 = tile[r + 2][c], x3 = tile[r + 3][c];
        h.x = f2bf(x0); l.x = f2bf(x0 - bf2f(h.x));
        h.y = f2bf(x1); l.y = f2bf(x1 - bf2f(h.y));
        h.z = f2bf(x2); l.z = f2bf(x2 - bf2f(h.z));
        h.w = f2bf(x3); l.w = f2bf(x3 - bf2f(h.w));
        *(ushort4*)&WTh[(size_t)(c0 + c) * K + r0 + r] = h;
        *(ushort4*)&WTl[(size_t)(c0 + c) * K + r0 + r] = l;
    }
}

// ---------------------------------------------------------------------------
// mfma_gemm3: C[M,256] = (Ah+Al)[M,K] x (Bh+Bl)[256,K]^T + bias, 3-term
// split-bf16 MFMA. BM=64, BN=128, BK=32, 4 waves. grid (2, M/64).
// OUTMODE: 0 = fp32 C0; 1 = bf16 C0; 2 = hi/lo split into C0,C1.
// ---------------------------------------------------------------------------
template<int KDIM, int OUTMODE>
__global__ __launch_bounds__(256) void mfma_gemm3_kernel(
    const unsigned short* __restrict__ Ah_, const unsigned short* __restrict__ Al_,
    const unsigned short* __restrict__ Bh_, const unsigned short* __restrict__ Bl_,
    const float* __restrict__ bias,
    void* __restrict__ C0, void* __restrict__ C1)
{
    __shared__ short Ah[64][32], Al[64][32], Bh[128][32], Bl[128][32];

    const int m0 = blockIdx.y * 64;
    const int n0 = blockIdx.x * 128;
    const int t = threadIdx.x, lane = t & 63, w = t >> 6;
    const int wm = w >> 1, wn = w & 1;
    const int fr = lane & 15, kb = lane >> 4;

    f32x4 acc[2][4] = {};

    for (int k0 = 0; k0 < KDIM; k0 += 32) {
        // stage A (hi+lo): 512 x 16B chunks, 2/thread
        #pragma unroll
        for (int r = 0; r < 2; ++r) {
            int c = r * 256 + t;
            int tens = c >> 8, idx = c & 255;
            int row = idx >> 2, slot = idx & 3;
            const unsigned short* src =
                (tens ? Al_ : Ah_) + (size_t)(m0 + row) * KDIM + k0 + slot * 8;
            gll16(src, (char*)(tens ? &Al[0][0] : &Ah[0][0]) + idx * 16);
        }
        // stage B (hi+lo): 1024 chunks, 4/thread
        #pragma unroll
        for (int r = 0; r < 4; ++r) {
            int c = r * 256 + t;
            int tens = c >> 9, idx = c & 511;
            int row = idx >> 2, slot = idx & 3;
            const unsigned short* src =
                (tens ? Bl_ : Bh_) + (size_t)(n0 + row) * KDIM + k0 + slot * 8;
            gll16(src, (char*)(tens ? &Bl[0][0] : &Bh[0][0]) + idx * 16);
        }
        __syncthreads();

        bf16x8 ah[2], al[2], bh[4], bl[4];
        #pragma unroll
        for (int m = 0; m < 2; ++m) {
            int row = wm * 32 + m * 16 + fr;
            ah[m] = *(const bf16x8*)&Ah[row][kb * 8];
            al[m] = *(const bf16x8*)&Al[row][kb * 8];
        }
        #pragma unroll
        for (int n = 0; n < 4; ++n) {
            int col = wn * 64 + n * 16 + fr;
            bh[n] = *(const bf16x8*)&Bh[col][kb * 8];
            bl[n] = *(const bf16x8*)&Bl[col][kb * 8];
        }
        #pragma unroll
        for (int m = 0; m < 2; ++m)
            #pragma unroll
            for (int n = 0; n < 4; ++n) {
                acc[m][n] = MFMA16(ah[m], bh[n], acc[m][n], 0, 0, 0);
                acc[m][n] = MFMA16(ah[m], bl[n], acc[m][n], 0, 0, 0);
                acc[m][n] = MFMA16(al[m], bh[n], acc[m][n], 0, 0, 0);
            }
        __syncthreads();
    }

    #pragma unroll
    for (int m = 0; m < 2; ++m)
        #pragma unroll
        for (int e = 0; e < 4; ++e) {
            const int row = m0 + wm * 32 + m * 16 + kb * 4 + e;
            #pragma unroll
            for (int n = 0; n < 4; ++n) {
                const int col = n0 + wn * 64 + n * 16 + fr;
                float v = acc[m][n][e] + bias[col];
                if (OUTMODE == 0) {
                    ((float*)C0)[(size_t)row * 256 + col] = v;
                } else if (OUTMODE == 1) {
                    ((unsigned short*)C0)[(size_t)row * 256 + col] = f2bf(v);
                } else {
                    unsigned short h = f2bf(v);
                    ((unsigned short*)C0)[(size_t)row * 256 + col] = h;
                    ((unsigned short*)C1)[(size_t)row * 256 + col] =
                        f2bf(v - bf2f(h));
                }
            }
        }
}

// ---------------------------------------------------------------------------
// LayerNorm + hi/lo bf16 split.
// ---------------------------------------------------------------------------
__global__ __launch_bounds__(256) void ln_split_kernel(
    const float* __restrict__ X,
    unsigned short* __restrict__ Hi, unsigned short* __restrict__ Lo)
{
    const int row = blockIdx.x;
    const int t = threadIdx.x;
    float x = X[(size_t)row * DIM + t];

    float s1 = x, s2 = x * x;
    #pragma unroll
    for (int o = 32; o; o >>= 1) {
        s1 += __shfl_xor(s1, o);
        s2 += __shfl_xor(s2, o);
    }
    __shared__ float r1[4], r2[4];
    const int wid = t >> 6;
    if ((t & 63) == 0) { r1[wid] = s1; r2[wid] = s2; }
    __syncthreads();
    const float sum = r1[0] + r1[1] + r1[2] + r1[3];
    const float ssq = r2[0] + r2[1] + r2[2] + r2[3];
    const float mean = sum * (1.0f / DIM);
    const float var  = ssq * (1.0f / DIM) - mean * mean;
    const float y = (x - mean) * rsqrtf(var + 1e-5f);

    const unsigned short h = f2bf(y);
    Hi[(size_t)row * DIM + t] = h;
    Lo[(size_t)row * DIM + t] = f2bf(y - bf2f(h));
}

// ---------------------------------------------------------------------------
// V [8192,256] fp32 -> VT [256,8192] bf16.
// ---------------------------------------------------------------------------
__global__ __launch_bounds__(256) void vtrans_kernel(
    const float* __restrict__ V, unsigned short* __restrict__ VT)
{
    __shared__ float tile[64][65];
    const int r0 = blockIdx.x * 64;
    const int c0 = blockIdx.y * 64;
    const int t = threadIdx.x;
    #pragma unroll
    for (int i = 0; i < 4; ++i) {
        int r = i * 16 + (t >> 4);
        int c = (t & 15) * 4;
        float4 v = *(const float4*)&V[(size_t)(r0 + r) * DIM + c0 + c];
        tile[r][c] = v.x; tile[r][c + 1] = v.y;
        tile[r][c + 2] = v.z; tile[r][c + 3] = v.w;
    }
    __syncthreads();
    #pragma unroll
    for (int i = 0; i < 4; ++i) {
        int c = i * 16 + (t >> 4);
        int r = (t & 15) * 4;
        ushort4 o;
        o.x = f2bf(tile[r][c]);     o.y = f2bf(tile[r + 1][c]);
        o.z = f2bf(tile[r + 2][c]); o.w = f2bf(tile[r + 3][c]);
        *(ushort4*)&VT[(size_t)(c0 + c) * N_NODES + r0 + r] = o;
    }
}

// ---------------------------------------------------------------------------
// scores = Q @ K^T (split-bf16, 3 MFMA terms). Single-exp epilogue:
// block max first, then one exp pass -> bf16 tile + sumexp.
// Sb row stride 16384 ushorts (32KB attn slot); pstat=(m_blk, sumexp_blk).
// ---------------------------------------------------------------------------
__global__ __launch_bounds__(256) void qkt_kernel(
    const unsigned short* __restrict__ Qh, const unsigned short* __restrict__ Ql,
    const unsigned short* __restrict__ Kh, const unsigned short* __restrict__ Kl,
    unsigned short* __restrict__ Sb, float2* __restrict__ pstat)
{
    __shared__ short stage[4][128][32];   // Ah/Al/Bh/Bl; reused as bf16 out-tile
    __shared__ float2 ps[2][128];
    __shared__ float gmr[128];

    const int bid = blockIdx.x;
    const int wg = (bid & 7) * 512 + (bid >> 3);   // XCD swizzle (4096%8==0)
    const int mb = wg >> 6, nb = wg & 63;
    const int m0 = mb * 128, n0 = nb * 128;

    const int t = threadIdx.x, lane = t & 63, w = t >> 6;
    const int wm = w >> 1, wn = w & 1;
    const int fr = lane & 15, kb = lane >> 4;

    f32x4 acc[4][4] = {};

    for (int k0 = 0; k0 < DIM; k0 += 32) {
        #pragma unroll
        for (int r = 0; r < 2; ++r) {
            int c = r * 256 + t;
            int row = c >> 2, slot = c & 3;
            size_t ga = (size_t)(m0 + row) * DIM + k0 + slot * 8;
            size_t gb = (size_t)(n0 + row) * DIM + k0 + slot * 8;
            int lo = c * 16;
            gll16(Qh + ga, (char*)&stage[0][0][0] + lo);
            gll16(Ql + ga, (char*)&stage[1][0][0] + lo);
            gll16(Kh + gb, (char*)&stage[2][0][0] + lo);
            gll16(Kl + gb, (char*)&stage[3][0][0] + lo);
        }
        __syncthreads();

        bf16x8 ah[4], al[4], bh[4], bl[4];
        #pragma unroll
        for (int m = 0; m < 4; ++m) {
            int row = wm * 64 + m * 16 + fr;
            ah[m] = *(const bf16x8*)&stage[0][row][kb * 8];
            al[m] = *(const bf16x8*)&stage[1][row][kb * 8];
        }
        #pragma unroll
        for (int n = 0; n < 4; ++n) {
            int col = wn * 64 + n * 16 + fr;
            bh[n] = *(const bf16x8*)&stage[2][col][kb * 8];
            bl[n] = *(const bf16x8*)&stage[3][col][kb * 8];
        }
        #pragma unroll
        for (int m = 0; m < 4; ++m)
            #pragma unroll
            for (int n = 0; n < 4; ++n) {
                acc[m][n] = MFMA16(ah[m], bh[n], acc[m][n], 0, 0, 0);
                acc[m][n] = MFMA16(ah[m], bl[n], acc[m][n], 0, 0, 0);
                acc[m][n] = MFMA16(al[m], bh[n], acc[m][n], 0, 0, 0);
            }
        __syncthreads();
    }

    // ---- phase A: per-row max over this block's 128 cols
    #pragma unroll
    for (int m = 0; m < 4; ++m)
        #pragma unroll
        for (int e = 0; e < 4; ++e) {
            float mx = acc[m][0][e];
            #pragma unroll
            for (int n = 1; n < 4; ++n) mx = fmaxf(mx, acc[m][n][e]);
            #pragma unroll
            for (int o = 1; o < 16; o <<= 1) mx = fmaxf(mx, __shfl_xor(mx, o));
            if (fr == 0) ps[wn][wm * 64 + m * 16 + kb * 4 + e].x = mx;
        }
    __syncthreads();
    if (t < 128) gmr[t] = fmaxf(ps[0][t].x, ps[1][t].x);
    __syncthreads();

    // ---- phase B: single exp pass -> bf16 tile + sumexp
    unsigned short* tile = (unsigned short*)&stage[0][0][0];   // [128][128]
    #pragma unroll
    for (int m = 0; m < 4; ++m)
        #pragma unroll
        for (int e = 0; e < 4; ++e) {
            const int rl = wm * 64 + m * 16 + kb * 4 + e;
            const float g = gmr[rl];
            float se = 0.f;
            #pragma unroll
            for (int n = 0; n < 4; ++n) {
                float ev = __expf(acc[m][n][e] - g);
                se += ev;
                tile[rl * 128 + wn * 64 + n * 16 + fr] = f2bf(ev);
            }
            #pragma unroll
            for (int o = 1; o < 16; o <<= 1) se += __shfl_xor(se, o);
            if (fr == 0) ps[wn][rl].y = se;
        }
    __syncthreads();
    if (t < 128)
        pstat[(size_t)(m0 + t) * 64 + nb] =
            make_float2(gmr[t], ps[0][t].y + ps[1][t].y);

    // ---- coalesced bf16 store: row stride 16384 ushorts (32KB attn slot)
    #pragma unroll
    for (int p = 0; p < 8; ++p) {
        int c = p * 256 + t;            // 16B chunk id (2048 total)
        int r = c >> 4, sl = c & 15;
        *(int4*)&Sb[(size_t)(m0 + r) * 16384 + n0 + sl * 8] =
            *(const int4*)((const char*)tile + c * 16);
    }
}

// ---------------------------------------------------------------------------
// factab[row][cb] = exp(m_cb - m_row) / Z_row. 4 rows/block, 64 lanes/row.
// ---------------------------------------------------------------------------
__global__ __launch_bounds__(256) void factor_kernel(
    const float2* __restrict__ pstat, float* __restrict__ factab)
{
    const int row = blockIdx.x * 4 + (threadIdx.x >> 6);
    const int lane = threadIdx.x & 63;
    float2 v = pstat[(size_t)row * 64 + lane];
    float gm = v.x;
    #pragma unroll
    for (int o = 1; o < 64; o <<= 1) gm = fmaxf(gm, __shfl_xor(gm, o));
    float s = v.y * __expf(v.x - gm);
    #pragma unroll
    for (int o = 1; o < 64; o <<= 1) s += __shfl_xor(s, o);
    factab[(size_t)row * 64 + lane] = __expf(v.x - gm) / s;
}

// ---------------------------------------------------------------------------
// av_mfma: ZA partials = (factor * Sb) @ VT^T via per-step scaled MFMA.
// 64 rows/block, k-split 4 -> 512 blocks.
// ---------------------------------------------------------------------------
__global__ __launch_bounds__(256, 2) void av_mfma_kernel(
    const unsigned short* __restrict__ Sb, const float* __restrict__ factab,
    const unsigned short* __restrict__ VT,
    float* __restrict__ P0, float* __restrict__ P1,
    float* __restrict__ P2, float* __restrict__ P3)
{
    __shared__ unsigned short As[2][64][128];   // linear dest, swizzled source
    __shared__ float facsT[16][64];             // [local cb][row]

    const int bid = blockIdx.x;
    const int rb = bid >> 2, ks = bid & 3;
    const int r0 = rb * 64, kbase = ks * 2048, cb0 = ks * 16;
    const int t = threadIdx.x, lane = t & 63, w = t >> 6;
    const int fr = lane & 15, kb = lane >> 4;

    for (int i = t; i < 1024; i += 256)
        facsT[i >> 6][i & 63] =
            factab[(size_t)(r0 + (i & 63)) * 64 + cb0 + (i >> 6)];

    const unsigned short* vb[4];
    #pragma unroll
    for (int n = 0; n < 4; ++n)
        vb[n] = VT + (size_t)(w * 64 + n * 16 + fr) * N_NODES + kbase + kb * 8;

    #define STAGE(S_, BUF_) do {                                              \
        _Pragma("unroll")                                                     \
        for (int p = 0; p < 4; ++p) {                                         \
            int c = p * 256 + t;                                              \
            int rr = c >> 4, sl = c & 15;                                     \
            int slp = sl ^ (rr & 7);                                          \
            gll16(Sb + (size_t)(r0 + rr) * 16384 + kbase + (S_) * 128 + slp * 8, \
                  (char*)&As[BUF_][0][0] + c * 16);                           \
        } } while (0)

    f32x4 acc[4][4] = {};
    const f32x4 z4 = {0.f, 0.f, 0.f, 0.f};

    STAGE(0, 0);
    __syncthreads();

    for (int s = 0; s < 16; ++s) {
        const int b = s & 1;
        if (s + 1 < 16) STAGE(s + 1, b ^ 1);

        bf16x8 bb[4][4];
        #pragma unroll
        for (int ksl = 0; ksl < 4; ++ksl)
            #pragma unroll
            for (int n = 0; n < 4; ++n)
                bb[ksl][n] = *(const bf16x8*)(vb[n] + s * 128 + ksl * 32);

        const char* abase = (const char*)&As[b][0][0];
        #pragma unroll
        for (int m = 0; m < 4; ++m) {
            f32x4 sacc[4];
            {
                bf16x8 a = *(const bf16x8*)(abase + (m * 16 + fr) * 256 +
                                            ((kb ^ (fr & 7)) * 16));
                #pragma unroll
                for (int n = 0; n < 4; ++n)
                    sacc[n] = MFMA16(a, bb[0][n], z4, 0, 0, 0);
            }
            #pragma unroll
            for (int ksl = 1; ksl < 4; ++ksl) {
                bf16x8 a = *(const bf16x8*)(abase + (m * 16 + fr) * 256 +
                                            (((ksl * 4 + kb) ^ (fr & 7)) * 16));
                #pragma unroll
                for (int n = 0; n < 4; ++n)
                    sacc[n] = MFMA16(a, bb[ksl][n], sacc[n], 0, 0, 0);
            }
            f32x4 fac = *(const f32x4*)&facsT[s][m * 16 + kb * 4];
            #pragma unroll
            for (int n = 0; n < 4; ++n)
                acc[m][n] += fac * sacc[n];
        }
        __syncthreads();
    }
    #undef STAGE

    float* P = (ks == 0) ? P0 : (ks == 1) ? P1 : (ks == 2) ? P2 : P3;
    #pragma unroll
    for (int m = 0; m < 4; ++m)
        #pragma unroll
        for (int e = 0; e < 4; ++e) {
            int row = r0 + m * 16 + kb * 4 + e;
            #pragma unroll
            for (int n = 0; n < 4; ++n)
                P[(size_t)row * DIM + w * 64 + n * 16 + fr] = acc[m][n][e];
        }
}

// ---------------------------------------------------------------------------
// scale: attn[row] = bf2f(Sb[row]) * factor, fp32 in place over the same
// row slot. Register-staged (no LDS): all reads, barrier, all writes.
// ---------------------------------------------------------------------------
__global__ __launch_bounds__(256) void scale_kernel(
    const unsigned short* __restrict__ Sb, const float* __restrict__ factab,
    float* __restrict__ attn)
{
    const int row = blockIdx.x;
    const int t = threadIdx.x;
    const unsigned short* src = Sb + (size_t)row * 16384;

    int4 v[4];
    float f[4];
    #pragma unroll
    for (int p = 0; p < 4; ++p) {
        int c = p * 256 + t;
        v[p] = *(const int4*)&src[c * 8];
        f[p] = factab[(size_t)row * 64 + (c >> 4)];
    }
    __syncthreads();

    float* dst = attn + (size_t)row * N_NODES;
    #pragma unroll
    for (int p = 0; p < 4; ++p) {
        int c = p * 256 + t;
        float4 o0, o1;
        o0.x = bf2f((unsigned short)(v[p].x & 0xffff)) * f[p];
        o0.y = bf2f((unsigned short)((unsigned)v[p].x >> 16)) * f[p];
        o0.z = bf2f((unsigned short)(v[p].y & 0xffff)) * f[p];
        o0.w = bf2f((unsigned short)((unsigned)v[p].y >> 16)) * f[p];
        o1.x = bf2f((unsigned short)(v[p].z & 0xffff)) * f[p];
        o1.y = bf2f((unsigned short)((unsigned)v[p].z >> 16)) * f[p];
        o1.z = bf2f((unsigned short)(v[p].w & 0xffff)) * f[p];
        o1.w = bf2f((unsigned short)((unsigned)v[p].w >> 16)) * f[p];
        *(float4*)(dst + c * 8)     = o0;
        *(float4*)(dst + c * 8 + 4) = o1;
    }
}

// ---------------------------------------------------------------------------
// SpMM: one 64-lane wave per node, lane holds 4 features (ushort4 loads).
// ---------------------------------------------------------------------------
__global__ __launch_bounds__(256) void spmm_kernel(
    const unsigned short* __restrict__ Hb, const int* __restrict__ erow,
    const int* __restrict__ ecol, const float* __restrict__ ew,
    float* __restrict__ out, int E)
{
    const int node = blockIdx.x * 4 + (threadIdx.x >> 6);
    const int lane = threadIdx.x & 63;

    int lo = 0, hi = E;
    while (lo < hi) { int mid = (lo + hi) >> 1; if (erow[mid] < node) lo = mid + 1; else hi = mid; }
    const int beg = lo;
    hi = E;
    while (lo < hi) { int mid = (lo + hi) >> 1; if (erow[mid] < node + 1) lo = mid + 1; else hi = mid; }
    const int end = lo;

    float4 acc = make_float4(0.f, 0.f, 0.f, 0.f);
    for (int e = beg; e < end; ++e) {
        const int col = ecol[e];
        const float wgt = ew[e];
        ushort4 h = *(const ushort4*)&Hb[(size_t)col * DIM + lane * 4];
        acc.x += wgt * bf2f(h.x);
        acc.y += wgt * bf2f(h.y);
        acc.z += wgt * bf2f(h.z);
        acc.w += wgt * bf2f(h.w);
    }
    *(float4*)&out[(size_t)node * DIM + lane * 4] = acc;
}

// ---------------------------------------------------------------------------
// Y = (0.5*(P0+P1+P2+P3) + 0.5*GNN) @ Wc + bc
// ---------------------------------------------------------------------------
__global__ __launch_bounds__(256) void blend_cls_kernel(
    const float* __restrict__ p0, const float* __restrict__ p1,
    const float* __restrict__ p2, const float* __restrict__ p3,
    const float* __restrict__ gnn,
    const float* __restrict__ Wc, const float* __restrict__ bc,
    float* __restrict__ Y)
{
    const int row = blockIdx.x;
    const int t = threadIdx.x;
    __shared__ float z[DIM];
    __shared__ float part[4][NCLS];

    const size_t i = (size_t)row * DIM + t;
    z[t] = 0.5f * (p0[i] + p1[i] + p2[i] + p3[i] + gnn[i]);
    __syncthreads();

    if (t < 160) {
        const int c = t % NCLS, q = t / NCLS;
        float acc = 0.0f;
        #pragma unroll 4
        for (int d = q * 64; d < q * 64 + 64; ++d)
            acc += z[d] * Wc[d * NCLS + c];
        part[q][c] = acc;
    }
    __syncthreads();
    if (t < NCLS)
        Y[(size_t)row * NCLS + t] =
            part[0][t] + part[1][t] + part[2][t] + part[3][t] + bc[t];
}

// ---------------------------------------------------------------------------
extern "C" void kernel_launch(void* const* d_in, const int* in_sizes, int n_in,
                              void* d_out, int out_size, void* d_ws, size_t ws_size,
                              hipStream_t stream)
{
    const float* X     = (const float*)d_in[0];
    const int*   erow  = (const int*)d_in[1];
    const int*   ecol  = (const int*)d_in[2];
    const float* ew    = (const float*)d_in[3];
    const float* W_emb = (const float*)d_in[4];
    const float* b_emb = (const float*)d_in[5];
    const float* W_q   = (const float*)d_in[6];
    const float* b_q   = (const float*)d_in[7];
    const float* W_k   = (const float*)d_in[8];
    const float* b_k   = (const float*)d_in[9];
    const float* W_v   = (const float*)d_in[10];
    const float* b_v   = (const float*)d_in[11];
    const float* W_g   = (const float*)d_in[12];
    const float* b_g   = (const float*)d_in[13];
    const float* W_c   = (const float*)d_in[14];
    const float* b_c   = (const float*)d_in[15];
    const int E = in_sizes[1];

    float* Y    = (float*)d_out;
    float* Sc   = Y + (size_t)N_NODES * NCLS;      // attn [N,N]; Sb packed in rows
    unsigned short* Sb = (unsigned short*)Sc;      // row r at ushort offset r*16384

    const size_t ND = (size_t)N_NODES * DIM;       // 2M elements (8 MB fp32)
    float* R0 = (float*)d_ws;   // Xh/Xl? no: see plan below
    float* R1 = R0 + ND;
    float* R2 = R1 + ND;
    float* R3 = R2 + ND;
    float* R4 = R3 + ND;
    float* R5 = R4 + ND;
    float* R6 = R5 + ND;

    // phase-1 aliases
    unsigned short* Xh = (unsigned short*)R0;      // 8 MB
    unsigned short* Xl = (unsigned short*)R1;      // 8 MB
    unsigned short* Wt = (unsigned short*)R2;      // packed weight transposes
    unsigned short* WembTh = Wt;                   // 256x512
    unsigned short* WembTl = Wt + 256 * 512;
    unsigned short* WqTh = WembTl + 256 * 512;     // 256x256 each
    unsigned short* WqTl = WqTh + 256 * 256;
    unsigned short* WkTh = WqTl + 256 * 256;
    unsigned short* WkTl = WkTh + 256 * 256;
    unsigned short* WvTh = WkTl + 256 * 256;
    unsigned short* WvTl = WvTh + 256 * 256;
    unsigned short* WgTh = WvTl + 256 * 256;
    unsigned short* WgTl = WgTh + 256 * 256;
    unsigned short* Z0h = (unsigned short*)R3;     // 4 MB
    unsigned short* Z0l = Z0h + ND;                // 4 MB
    float* Qf = R4;
    float* Kf = R5;
    float* Vf = R6;
    unsigned short* Hb = (unsigned short*)R0;      // first 4 MB (X dead)
    // phase-2 aliases
    unsigned short* Qh = (unsigned short*)R1;      // Xl dead
    unsigned short* Ql = Qh + ND;
    unsigned short* Kh = (unsigned short*)R2;      // weights dead
    unsigned short* Kl = Kh + ND;
    unsigned short* VT = (unsigned short*)(R0 + ND / 2);  // second 4 MB of R0
    float2* pstat = (float2*)R4;                   // Qf dead after ln_split
    float*  factab = R5;                           // Kf dead after ln_split+qkt
    // ZA partials (each 8 MB)
    float* P0 = R6;   // Vf dead after vtrans
    float* P1 = R3;   // Z0 dead after projections
    float* P2 = R4;   // pstat dead after factor
    float* P3 = R1;   // Qh/Ql dead after qkt
    float* GNN = R2;  // Kh/Kl dead after qkt

    // 1. X -> hi/lo bf16
    split_kernel<<<(N_NODES * F_IN) / 1024, 256, 0, stream>>>(X, Xh, Xl);

    // 2. weight transposes (fp32 [K,N] -> bf16 hi/lo [N,K])
    wtrans_kernel<<<dim3(F_IN / 64, DIM / 64), 256, 0, stream>>>(W_emb, WembTh, WembTl, F_IN, DIM);
    wtrans_kernel<<<dim3(DIM / 64, DIM / 64), 256, 0, stream>>>(W_q, WqTh, WqTl, DIM, DIM);
    wtrans_kernel<<<dim3(DIM / 64, DIM / 64), 256, 0, stream>>>(W_k, WkTh, WkTl, DIM, DIM);
    wtrans_kernel<<<dim3(DIM / 64, DIM / 64), 256, 0, stream>>>(W_v, WvTh, WvTl, DIM, DIM);
    wtrans_kernel<<<dim3(DIM / 64, DIM / 64), 256, 0, stream>>>(W_g, WgTh, WgTl, DIM, DIM);

    // 3. Z0 = X @ W_emb + b (split-bf16 MFMA, output hi/lo)
    mfma_gemm3_kernel<F_IN, 2><<<dim3(2, N_NODES / 64), 256, 0, stream>>>(
        Xh, Xl, WembTh, WembTl, b_emb, Z0h, Z0l);

    // 4. projections from Z0
    mfma_gemm3_kernel<DIM, 0><<<dim3(2, N_NODES / 64), 256, 0, stream>>>(
        Z0h, Z0l, WqTh, WqTl, b_q, Qf, nullptr);
    mfma_gemm3_kernel<DIM, 0><<<dim3(2, N_NODES / 64), 256, 0, stream>>>(
        Z0h, Z0l, WkTh, WkTl, b_k, Kf, nullptr);
    mfma_gemm3_kernel<DIM, 0><<<dim3(2, N_NODES / 64), 256, 0, stream>>>(
        Z0h, Z0l, WvTh, WvTl, b_v, Vf, nullptr);
    mfma_gemm3_kernel<DIM, 1><<<dim3(2, N_NODES / 64), 256, 0, stream>>>(
        Z0h, Z0l, WgTh, WgTl, b_g, Hb, nullptr);

    // 5. LN + hi/lo split
    ln_split_kernel<<<N_NODES, 256, 0, stream>>>(Qf, Qh, Ql);
    ln_split_kernel<<<N_NODES, 256, 0, stream>>>(Kf, Kh, Kl);

    // 6. V -> VT bf16
    vtrans_kernel<<<dim3(N_NODES / 64, DIM / 64), 256, 0, stream>>>(Vf, VT);

    // 7. Sb = bf16 exp(QK^T - m_block) + pstat
    qkt_kernel<<<4096, 256, 0, stream>>>(Qh, Ql, Kh, Kl, Sb, pstat);

    // 8. factor table
    factor_kernel<<<N_NODES / 4, 256, 0, stream>>>(pstat, factab);

    // 9. ZA partials = (factor * Sb) @ V   (reads Sb, must precede scale)
    av_mfma_kernel<<<512, 256, 0, stream>>>(Sb, factab, VT, P0, P1, P2, P3);

    // 10. attn = bf2f(Sb) * factor, fp32 in place
    scale_kernel<<<N_NODES, 256, 0, stream>>>(Sb, factab, Sc);

    // 11. GNN branch (bf16 H)
    spmm_kernel<<<N_NODES / 4, 256, 0, stream>>>(Hb, erow, ecol, ew, GNN, E);

    // 12. blend (partials summed inline) + classifier
    blend_cls_kernel<<<N_NODES, 256, 0, stream>>>(
        P0, P1, P2, P3, GNN, W_c, b_c, Y);
}

// Round 10
// 455.456 us; speedup vs baseline: 1.6179x; 1.0459x over previous
//
#include <hip/hip_runtime.h>
#include <hip/hip_bf16.h>

#define N_NODES 8192
#define F_IN    512
#define DIM     256
#define NCLS    40

typedef __attribute__((ext_vector_type(8))) short bf16x8;
typedef __attribute__((ext_vector_type(4))) float f32x4;

#define MFMA16 __builtin_amdgcn_mfma_f32_16x16x32_bf16

static __device__ __forceinline__ unsigned short f2bf(float x) {
    __hip_bfloat16 h = __float2bfloat16(x);
    return *reinterpret_cast<unsigned short*>(&h);
}
static __device__ __forceinline__ float bf2f(unsigned short u) {
    union { unsigned int u32; float f; } v; v.u32 = ((unsigned int)u) << 16;
    return v.f;
}
static __device__ __forceinline__ void gll16(const void* g, void* l) {
    __builtin_amdgcn_global_load_lds(
        (const __attribute__((address_space(1))) unsigned int*)g,
        (__attribute__((address_space(3))) unsigned int*)l, 16, 0, 0);
}

// ---------------------------------------------------------------------------
// split: fp32 -> (hi, lo) bf16 pair, elementwise. 4 elems/thread.
// ---------------------------------------------------------------------------
__global__ __launch_bounds__(256) void split_kernel(
    const float* __restrict__ X,
    unsigned short* __restrict__ Xh, unsigned short* __restrict__ Xl)
{
    const size_t i = ((size_t)blockIdx.x * 256 + threadIdx.x) * 4;
    float4 v = *(const float4*)&X[i];
    ushort4 h, l;
    h.x = f2bf(v.x); l.x = f2bf(v.x - bf2f(h.x));
    h.y = f2bf(v.y); l.y = f2bf(v.y - bf2f(h.y));
    h.z = f2bf(v.z); l.z = f2bf(v.z - bf2f(h.z));
    h.w = f2bf(v.w); l.w = f2bf(v.w - bf2f(h.w));
    *(ushort4*)&Xh[i] = h;
    *(ushort4*)&Xl[i] = l;
}

// ---------------------------------------------------------------------------
// wtrans: W fp32 [K,N] -> WT hi/lo bf16 [N,K]. 64x64 LDS transpose tiles.
// ---------------------------------------------------------------------------
__global__ __launch_bounds__(256) void wtrans_kernel(
    const float* __restrict__ W,
    unsigned short* __restrict__ WTh, unsigned short* __restrict__ WTl,
    int K, int N)
{
    __shared__ float tile[64][65];
    const int r0 = blockIdx.x * 64;   // K dim
    const int c0 = blockIdx.y * 64;   // N dim
    const int t = threadIdx.x;
    #pragma unroll
    for (int i = 0; i < 4; ++i) {
        int r = i * 16 + (t >> 4);
        int c = (t & 15) * 4;
        float4 v = *(const float4*)&W[(size_t)(r0 + r) * N + c0 + c];
        tile[r][c] = v.x; tile[r][c + 1] = v.y;
        tile[r][c + 2] = v.z; tile[r][c + 3] = v.w;
    }
    __syncthreads();
    #pragma unroll
    for (int i = 0; i < 4; ++i) {
        int c = i * 16 + (t >> 4);    // N-local
        int r = (t & 15) * 4;         // K-local
        ushort4 h, l;
        float x0 = tile[r][c],     x1 = tile[r + 1][c];
        float x2 = tile[r + 2][c], x3 = tile[r + 3][c];
        h.x = f2bf(x0); l.x = f2bf(x0 - bf2f(h.x));
        h.y = f2bf(x1); l.y = f2bf(x1 - bf2f(h.y));
        h.z = f2bf(x2); l.z = f2bf(x2 - bf2f(h.z));
        h.w = f2bf(x3); l.w = f2bf(x3 - bf2f(h.w));
        *(ushort4*)&WTh[(size_t)(c0 + c) * K + r0 + r] = h;
        *(ushort4*)&WTl[(size_t)(c0 + c) * K + r0 + r] = l;
    }
}

// ---------------------------------------------------------------------------
// mfma_gemm3: C[M,256] = (Ah+Al)[M,K] x (Bh+Bl)[256,K]^T + bias, 3-term
// split-bf16 MFMA. BM=64, BN=128, BK=32, 4 waves. (used for embedding)
// OUTMODE: 0 = fp32 C0; 1 = bf16 C0; 2 = hi/lo split into C0,C1.
// ---------------------------------------------------------------------------
template<int KDIM, int OUTMODE>
__global__ __launch_bounds__(256) void mfma_gemm3_kernel(
    const unsigned short* __restrict__ Ah_, const unsigned short* __restrict__ Al_,
    const unsigned short* __restrict__ Bh_, const unsigned short* __restrict__ Bl_,
    const float* __restrict__ bias,
    void* __restrict__ C0, void* __restrict__ C1)
{
    __shared__ short Ah[64][32], Al[64][32], Bh[128][32], Bl[128][32];

    const int m0 = blockIdx.y * 64;
    const int n0 = blockIdx.x * 128;
    const int t = threadIdx.x, lane = t & 63, w = t >> 6;
    const int wm = w >> 1, wn = w & 1;
    const int fr = lane & 15, kb = lane >> 4;

    f32x4 acc[2][4] = {};

    for (int k0 = 0; k0 < KDIM; k0 += 32) {
        #pragma unroll
        for (int r = 0; r < 2; ++r) {
            int c = r * 256 + t;
            int tens = c >> 8, idx = c & 255;
            int row = idx >> 2, slot = idx & 3;
            const unsigned short* src =
                (tens ? Al_ : Ah_) + (size_t)(m0 + row) * KDIM + k0 + slot * 8;
            gll16(src, (char*)(tens ? &Al[0][0] : &Ah[0][0]) + idx * 16);
        }
        #pragma unroll
        for (int r = 0; r < 4; ++r) {
            int c = r * 256 + t;
            int tens = c >> 9, idx = c & 511;
            int row = idx >> 2, slot = idx & 3;
            const unsigned short* src =
                (tens ? Bl_ : Bh_) + (size_t)(n0 + row) * KDIM + k0 + slot * 8;
            gll16(src, (char*)(tens ? &Bl[0][0] : &Bh[0][0]) + idx * 16);
        }
        __syncthreads();

        bf16x8 ah[2], al[2], bh[4], bl[4];
        #pragma unroll
        for (int m = 0; m < 2; ++m) {
            int row = wm * 32 + m * 16 + fr;
            ah[m] = *(const bf16x8*)&Ah[row][kb * 8];
            al[m] = *(const bf16x8*)&Al[row][kb * 8];
        }
        #pragma unroll
        for (int n = 0; n < 4; ++n) {
            int col = wn * 64 + n * 16 + fr;
            bh[n] = *(const bf16x8*)&Bh[col][kb * 8];
            bl[n] = *(const bf16x8*)&Bl[col][kb * 8];
        }
        #pragma unroll
        for (int m = 0; m < 2; ++m)
            #pragma unroll
            for (int n = 0; n < 4; ++n) {
                acc[m][n] = MFMA16(ah[m], bh[n], acc[m][n], 0, 0, 0);
                acc[m][n] = MFMA16(ah[m], bl[n], acc[m][n], 0, 0, 0);
                acc[m][n] = MFMA16(al[m], bh[n], acc[m][n], 0, 0, 0);
            }
        __syncthreads();
    }

    #pragma unroll
    for (int m = 0; m < 2; ++m)
        #pragma unroll
        for (int e = 0; e < 4; ++e) {
            const int row = m0 + wm * 32 + m * 16 + kb * 4 + e;
            #pragma unroll
            for (int n = 0; n < 4; ++n) {
                const int col = n0 + wn * 64 + n * 16 + fr;
                float v = acc[m][n][e] + bias[col];
                if (OUTMODE == 0) {
                    ((float*)C0)[(size_t)row * 256 + col] = v;
                } else if (OUTMODE == 1) {
                    ((unsigned short*)C0)[(size_t)row * 256 + col] = f2bf(v);
                } else {
                    unsigned short h = f2bf(v);
                    ((unsigned short*)C0)[(size_t)row * 256 + col] = h;
                    ((unsigned short*)C1)[(size_t)row * 256 + col] =
                        f2bf(v - bf2f(h));
                }
            }
        }
}

// ---------------------------------------------------------------------------
// proj4: all four DIM x DIM projections in one launch (z selects weights).
// z=0..2 -> fp32 out (Q,K,V); z=3 -> bf16 out (H). Shared Z0 A-panels.
// ---------------------------------------------------------------------------
struct Proj4Args {
    const unsigned short* Bh[4];
    const unsigned short* Bl[4];
    const float* bias[4];
    void* C[4];
};

__global__ __launch_bounds__(256) void proj4_kernel(
    const unsigned short* __restrict__ Ah_, const unsigned short* __restrict__ Al_,
    Proj4Args p)
{
    __shared__ short Ah[64][32], Al[64][32], Bh[128][32], Bl[128][32];

    const int z  = blockIdx.z;
    const int m0 = blockIdx.y * 64;
    const int n0 = blockIdx.x * 128;
    const unsigned short* Bh_ = p.Bh[z];
    const unsigned short* Bl_ = p.Bl[z];
    const float* bias = p.bias[z];

    const int t = threadIdx.x, lane = t & 63, w = t >> 6;
    const int wm = w >> 1, wn = w & 1;
    const int fr = lane & 15, kb = lane >> 4;

    f32x4 acc[2][4] = {};

    for (int k0 = 0; k0 < DIM; k0 += 32) {
        #pragma unroll
        for (int r = 0; r < 2; ++r) {
            int c = r * 256 + t;
            int tens = c >> 8, idx = c & 255;
            int row = idx >> 2, slot = idx & 3;
            const unsigned short* src =
                (tens ? Al_ : Ah_) + (size_t)(m0 + row) * DIM + k0 + slot * 8;
            gll16(src, (char*)(tens ? &Al[0][0] : &Ah[0][0]) + idx * 16);
        }
        #pragma unroll
        for (int r = 0; r < 4; ++r) {
            int c = r * 256 + t;
            int tens = c >> 9, idx = c & 511;
            int row = idx >> 2, slot = idx & 3;
            const unsigned short* src =
                (tens ? Bl_ : Bh_) + (size_t)(n0 + row) * DIM + k0 + slot * 8;
            gll16(src, (char*)(tens ? &Bl[0][0] : &Bh[0][0]) + idx * 16);
        }
        __syncthreads();

        bf16x8 ah[2], al[2], bh[4], bl[4];
        #pragma unroll
        for (int m = 0; m < 2; ++m) {
            int row = wm * 32 + m * 16 + fr;
            ah[m] = *(const bf16x8*)&Ah[row][kb * 8];
            al[m] = *(const bf16x8*)&Al[row][kb * 8];
        }
        #pragma unroll
        for (int n = 0; n < 4; ++n) {
            int col = wn * 64 + n * 16 + fr;
            bh[n] = *(const bf16x8*)&Bh[col][kb * 8];
            bl[n] = *(const bf16x8*)&Bl[col][kb * 8];
        }
        #pragma unroll
        for (int m = 0; m < 2; ++m)
            #pragma unroll
            for (int n = 0; n < 4; ++n) {
                acc[m][n] = MFMA16(ah[m], bh[n], acc[m][n], 0, 0, 0);
                acc[m][n] = MFMA16(ah[m], bl[n], acc[m][n], 0, 0, 0);
                acc[m][n] = MFMA16(al[m], bh[n], acc[m][n], 0, 0, 0);
            }
        __syncthreads();
    }

    #pragma unroll
    for (int m = 0; m < 2; ++m)
        #pragma unroll
        for (int e = 0; e < 4; ++e) {
            const int row = m0 + wm * 32 + m * 16 + kb * 4 + e;
            #pragma unroll
            for (int n = 0; n < 4; ++n) {
                const int col = n0 + wn * 64 + n * 16 + fr;
                float v = acc[m][n][e] + bias[col];
                if (z < 3)
                    ((float*)p.C[z])[(size_t)row * 256 + col] = v;
                else
                    ((unsigned short*)p.C[z])[(size_t)row * 256 + col] = f2bf(v);
            }
        }
}

// ---------------------------------------------------------------------------
// LayerNorm + hi/lo bf16 split.
// ---------------------------------------------------------------------------
__global__ __launch_bounds__(256) void ln_split_kernel(
    const float* __restrict__ X,
    unsigned short* __restrict__ Hi, unsigned short* __restrict__ Lo)
{
    const int row = blockIdx.x;
    const int t = threadIdx.x;
    float x = X[(size_t)row * DIM + t];

    float s1 = x, s2 = x * x;
    #pragma unroll
    for (int o = 32; o; o >>= 1) {
        s1 += __shfl_xor(s1, o);
        s2 += __shfl_xor(s2, o);
    }
    __shared__ float r1[4], r2[4];
    const int wid = t >> 6;
    if ((t & 63) == 0) { r1[wid] = s1; r2[wid] = s2; }
    __syncthreads();
    const float sum = r1[0] + r1[1] + r1[2] + r1[3];
    const float ssq = r2[0] + r2[1] + r2[2] + r2[3];
    const float mean = sum * (1.0f / DIM);
    const float var  = ssq * (1.0f / DIM) - mean * mean;
    const float y = (x - mean) * rsqrtf(var + 1e-5f);

    const unsigned short h = f2bf(y);
    Hi[(size_t)row * DIM + t] = h;
    Lo[(size_t)row * DIM + t] = f2bf(y - bf2f(h));
}

// ---------------------------------------------------------------------------
// V [8192,256] fp32 -> VT [256,8192] bf16.
// ---------------------------------------------------------------------------
__global__ __launch_bounds__(256) void vtrans_kernel(
    const float* __restrict__ V, unsigned short* __restrict__ VT)
{
    __shared__ float tile[64][65];
    const int r0 = blockIdx.x * 64;
    const int c0 = blockIdx.y * 64;
    const int t = threadIdx.x;
    #pragma unroll
    for (int i = 0; i < 4; ++i) {
        int r = i * 16 + (t >> 4);
        int c = (t & 15) * 4;
        float4 v = *(const float4*)&V[(size_t)(r0 + r) * DIM + c0 + c];
        tile[r][c] = v.x; tile[r][c + 1] = v.y;
        tile[r][c + 2] = v.z; tile[r][c + 3] = v.w;
    }
    __syncthreads();
    #pragma unroll
    for (int i = 0; i < 4; ++i) {
        int c = i * 16 + (t >> 4);
        int r = (t & 15) * 4;
        ushort4 o;
        o.x = f2bf(tile[r][c]);     o.y = f2bf(tile[r + 1][c]);
        o.z = f2bf(tile[r + 2][c]); o.w = f2bf(tile[r + 3][c]);
        *(ushort4*)&VT[(size_t)(c0 + c) * N_NODES + r0 + r] = o;
    }
}

// ---------------------------------------------------------------------------
// scores = Q @ K^T (split-bf16, 3 MFMA terms). 2D-chunked XCD ordering:
// each XCD iterates (mb,nb) in 8x8 supertiles -> Q+K working set 2MB < L2.
// Sb row stride 16384 ushorts (32KB attn slot); pstat=(m_blk, sumexp_blk).
// ---------------------------------------------------------------------------
__global__ __launch_bounds__(256) void qkt_kernel(
    const unsigned short* __restrict__ Qh, const unsigned short* __restrict__ Ql,
    const unsigned short* __restrict__ Kh, const unsigned short* __restrict__ Kl,
    unsigned short* __restrict__ Sb, float2* __restrict__ pstat)
{
    __shared__ short stage[4][128][32];   // Ah/Al/Bh/Bl; reused as bf16 out-tile
    __shared__ float2 ps[2][128];
    __shared__ float gmr[128];

    // 2D-chunked XCD swizzle: xcd owns mb in [x*8,x*8+8); nb grouped by 8.
    const int bid = blockIdx.x;
    const int x   = bid & 7;
    const int i   = bid >> 3;          // 0..511
    const int nbs = i >> 6;            // 0..7
    const int j   = i & 63;
    const int mb  = x * 8 + (j & 7);
    const int nb  = nbs * 8 + (j >> 3);
    const int m0 = mb * 128, n0 = nb * 128;

    const int t = threadIdx.x, lane = t & 63, w = t >> 6;
    const int wm = w >> 1, wn = w & 1;
    const int fr = lane & 15, kb = lane >> 4;

    f32x4 acc[4][4] = {};

    for (int k0 = 0; k0 < DIM; k0 += 32) {
        #pragma unroll
        for (int r = 0; r < 2; ++r) {
            int c = r * 256 + t;
            int row = c >> 2, slot = c & 3;
            size_t ga = (size_t)(m0 + row) * DIM + k0 + slot * 8;
            size_t gb = (size_t)(n0 + row) * DIM + k0 + slot * 8;
            int lo = c * 16;
            gll16(Qh + ga, (char*)&stage[0][0][0] + lo);
            gll16(Ql + ga, (char*)&stage[1][0][0] + lo);
            gll16(Kh + gb, (char*)&stage[2][0][0] + lo);
            gll16(Kl + gb, (char*)&stage[3][0][0] + lo);
        }
        __syncthreads();

        bf16x8 ah[4], al[4], bh[4], bl[4];
        #pragma unroll
        for (int m = 0; m < 4; ++m) {
            int row = wm * 64 + m * 16 + fr;
            ah[m] = *(const bf16x8*)&stage[0][row][kb * 8];
            al[m] = *(const bf16x8*)&stage[1][row][kb * 8];
        }
        #pragma unroll
        for (int n = 0; n < 4; ++n) {
            int col = wn * 64 + n * 16 + fr;
            bh[n] = *(const bf16x8*)&stage[2][col][kb * 8];
            bl[n] = *(const bf16x8*)&stage[3][col][kb * 8];
        }
        #pragma unroll
        for (int m = 0; m < 4; ++m)
            #pragma unroll
            for (int n = 0; n < 4; ++n) {
                acc[m][n] = MFMA16(ah[m], bh[n], acc[m][n], 0, 0, 0);
                acc[m][n] = MFMA16(ah[m], bl[n], acc[m][n], 0, 0, 0);
                acc[m][n] = MFMA16(al[m], bh[n], acc[m][n], 0, 0, 0);
            }
        __syncthreads();
    }

    // ---- phase A: per-row max over this block's 128 cols
    #pragma unroll
    for (int m = 0; m < 4; ++m)
        #pragma unroll
        for (int e = 0; e < 4; ++e) {
            float mx = acc[m][0][e];
            #pragma unroll
            for (int n = 1; n < 4; ++n) mx = fmaxf(mx, acc[m][n][e]);
            #pragma unroll
            for (int o = 1; o < 16; o <<= 1) mx = fmaxf(mx, __shfl_xor(mx, o));
            if (fr == 0) ps[wn][wm * 64 + m * 16 + kb * 4 + e].x = mx;
        }
    __syncthreads();
    if (t < 128) gmr[t] = fmaxf(ps[0][t].x, ps[1][t].x);
    __syncthreads();

    // ---- phase B: single exp pass -> bf16 tile + sumexp
    unsigned short* tile = (unsigned short*)&stage[0][0][0];   // [128][128]
    #pragma unroll
    for (int m = 0; m < 4; ++m)
        #pragma unroll
        for (int e = 0; e < 4; ++e) {
            const int rl = wm * 64 + m * 16 + kb * 4 + e;
            const float g = gmr[rl];
            float se = 0.f;
            #pragma unroll
            for (int n = 0; n < 4; ++n) {
                float ev = __expf(acc[m][n][e] - g);
                se += ev;
                tile[rl * 128 + wn * 64 + n * 16 + fr] = f2bf(ev);
            }
            #pragma unroll
            for (int o = 1; o < 16; o <<= 1) se += __shfl_xor(se, o);
            if (fr == 0) ps[wn][rl].y = se;
        }
    __syncthreads();
    if (t < 128)
        pstat[(size_t)(m0 + t) * 64 + nb] =
            make_float2(gmr[t], ps[0][t].y + ps[1][t].y);

    // ---- coalesced bf16 store: row stride 16384 ushorts (32KB attn slot)
    #pragma unroll
    for (int p = 0; p < 8; ++p) {
        int c = p * 256 + t;            // 16B chunk id (2048 total)
        int r = c >> 4, sl = c & 15;
        *(int4*)&Sb[(size_t)(m0 + r) * 16384 + n0 + sl * 8] =
            *(const int4*)((const char*)tile + c * 16);
    }
}

// ---------------------------------------------------------------------------
// factab[row][cb] = exp(m_cb - m_row) / Z_row. 4 rows/block, 64 lanes/row.
// ---------------------------------------------------------------------------
__global__ __launch_bounds__(256) void factor_kernel(
    const float2* __restrict__ pstat, float* __restrict__ factab)
{
    const int row = blockIdx.x * 4 + (threadIdx.x >> 6);
    const int lane = threadIdx.x & 63;
    float2 v = pstat[(size_t)row * 64 + lane];
    float gm = v.x;
    #pragma unroll
    for (int o = 1; o < 64; o <<= 1) gm = fmaxf(gm, __shfl_xor(gm, o));
    float s = v.y * __expf(v.x - gm);
    #pragma unroll
    for (int o = 1; o < 64; o <<= 1) s += __shfl_xor(s, o);
    factab[(size_t)row * 64 + lane] = __expf(v.x - gm) / s;
}

// ---------------------------------------------------------------------------
// av_mfma: ZA partials = (factor * Sb) @ VT^T via per-step scaled MFMA.
// Block order: ks slow per XCD so each XCD keeps one 1MB VT k-slice in L2.
// ---------------------------------------------------------------------------
__global__ __launch_bounds__(256, 2) void av_mfma_kernel(
    const unsigned short* __restrict__ Sb, const float* __restrict__ factab,
    const unsigned short* __restrict__ VT,
    float* __restrict__ P0, float* __restrict__ P1,
    float* __restrict__ P2, float* __restrict__ P3)
{
    __shared__ unsigned short As[2][64][128];   // linear dest, swizzled source
    __shared__ float facsT[16][64];             // [local cb][row]

    const int bid = blockIdx.x;
    const int x = bid & 7, i = bid >> 3;        // i in [0,64)
    const int ks = i >> 4;                      // slow per XCD
    const int rb = (i & 15) * 8 + x;            // 0..127
    const int r0 = rb * 64, kbase = ks * 2048, cb0 = ks * 16;
    const int t = threadIdx.x, lane = t & 63, w = t >> 6;
    const int fr = lane & 15, kb = lane >> 4;

    for (int ii = t; ii < 1024; ii += 256)
        facsT[ii >> 6][ii & 63] =
            factab[(size_t)(r0 + (ii & 63)) * 64 + cb0 + (ii >> 6)];

    const unsigned short* vb[4];
    #pragma unroll
    for (int n = 0; n < 4; ++n)
        vb[n] = VT + (size_t)(w * 64 + n * 16 + fr) * N_NODES + kbase + kb * 8;

    #define STAGE(S_, BUF_) do {                                              \
        _Pragma("unroll")                                                     \
        for (int p = 0; p < 4; ++p) {                                         \
            int c = p * 256 + t;                                              \
            int rr = c >> 4, sl = c & 15;                                     \
            int slp = sl ^ (rr & 7);                                          \
            gll16(Sb + (size_t)(r0 + rr) * 16384 + kbase + (S_) * 128 + slp * 8, \
                  (char*)&As[BUF_][0][0] + c * 16);                           \
        } } while (0)

    f32x4 acc[4][4] = {};
    const f32x4 z4 = {0.f, 0.f, 0.f, 0.f};

    STAGE(0, 0);
    __syncthreads();

    for (int s = 0; s < 16; ++s) {
        const int b = s & 1;
        if (s + 1 < 16) STAGE(s + 1, b ^ 1);

        bf16x8 bb[4][4];
        #pragma unroll
        for (int ksl = 0; ksl < 4; ++ksl)
            #pragma unroll
            for (int n = 0; n < 4; ++n)
                bb[ksl][n] = *(const bf16x8*)(vb[n] + s * 128 + ksl * 32);

        const char* abase = (const char*)&As[b][0][0];
        #pragma unroll
        for (int m = 0; m < 4; ++m) {
            f32x4 sacc[4];
            {
                bf16x8 a = *(const bf16x8*)(abase + (m * 16 + fr) * 256 +
                                            ((kb ^ (fr & 7)) * 16));
                #pragma unroll
                for (int n = 0; n < 4; ++n)
                    sacc[n] = MFMA16(a, bb[0][n], z4, 0, 0, 0);
            }
            #pragma unroll
            for (int ksl = 1; ksl < 4; ++ksl) {
                bf16x8 a = *(const bf16x8*)(abase + (m * 16 + fr) * 256 +
                                            (((ksl * 4 + kb) ^ (fr & 7)) * 16));
                #pragma unroll
                for (int n = 0; n < 4; ++n)
                    sacc[n] = MFMA16(a, bb[ksl][n], sacc[n], 0, 0, 0);
            }
            f32x4 fac = *(const f32x4*)&facsT[s][m * 16 + kb * 4];
            #pragma unroll
            for (int n = 0; n < 4; ++n)
                acc[m][n] += fac * sacc[n];
        }
        __syncthreads();
    }
    #undef STAGE

    float* P = (ks == 0) ? P0 : (ks == 1) ? P1 : (ks == 2) ? P2 : P3;
    #pragma unroll
    for (int m = 0; m < 4; ++m)
        #pragma unroll
        for (int e = 0; e < 4; ++e) {
            int row = r0 + m * 16 + kb * 4 + e;
            #pragma unroll
            for (int n = 0; n < 4; ++n)
                P[(size_t)row * DIM + w * 64 + n * 16 + fr] = acc[m][n][e];
        }
}

// ---------------------------------------------------------------------------
// scale: attn[row] = bf2f(Sb[row]) * factor, fp32 in place over the same
// row slot. Register-staged: all reads, barrier, all writes.
// ---------------------------------------------------------------------------
__global__ __launch_bounds__(256) void scale_kernel(
    const unsigned short* __restrict__ Sb, const float* __restrict__ factab,
    float* __restrict__ attn)
{
    const int row = blockIdx.x;
    const int t = threadIdx.x;
    const unsigned short* src = Sb + (size_t)row * 16384;

    int4 v[4];
    float f[4];
    #pragma unroll
    for (int p = 0; p < 4; ++p) {
        int c = p * 256 + t;
        v[p] = *(const int4*)&src[c * 8];
        f[p] = factab[(size_t)row * 64 + (c >> 4)];
    }
    __syncthreads();

    float* dst = attn + (size_t)row * N_NODES;
    #pragma unroll
    for (int p = 0; p < 4; ++p) {
        int c = p * 256 + t;
        float4 o0, o1;
        o0.x = bf2f((unsigned short)(v[p].x & 0xffff)) * f[p];
        o0.y = bf2f((unsigned short)((unsigned)v[p].x >> 16)) * f[p];
        o0.z = bf2f((unsigned short)(v[p].y & 0xffff)) * f[p];
        o0.w = bf2f((unsigned short)((unsigned)v[p].y >> 16)) * f[p];
        o1.x = bf2f((unsigned short)(v[p].z & 0xffff)) * f[p];
        o1.y = bf2f((unsigned short)((unsigned)v[p].z >> 16)) * f[p];
        o1.z = bf2f((unsigned short)(v[p].w & 0xffff)) * f[p];
        o1.w = bf2f((unsigned short)((unsigned)v[p].w >> 16)) * f[p];
        *(float4*)(dst + c * 8)     = o0;
        *(float4*)(dst + c * 8 + 4) = o1;
    }
}

// ---------------------------------------------------------------------------
// SpMM: one 64-lane wave per node, lane holds 4 features (ushort4 loads).
// ---------------------------------------------------------------------------
__global__ __launch_bounds__(256) void spmm_kernel(
    const unsigned short* __restrict__ Hb, const int* __restrict__ erow,
    const int* __restrict__ ecol, const float* __restrict__ ew,
    float* __restrict__ out, int E)
{
    const int node = blockIdx.x * 4 + (threadIdx.x >> 6);
    const int lane = threadIdx.x & 63;

    int lo = 0, hi = E;
    while (lo < hi) { int mid = (lo + hi) >> 1; if (erow[mid] < node) lo = mid + 1; else hi = mid; }
    const int beg = lo;
    hi = E;
    while (lo < hi) { int mid = (lo + hi) >> 1; if (erow[mid] < node + 1) lo = mid + 1; else hi = mid; }
    const int end = lo;

    float4 acc = make_float4(0.f, 0.f, 0.f, 0.f);
    for (int e = beg; e < end; ++e) {
        const int col = ecol[e];
        const float wgt = ew[e];
        ushort4 h = *(const ushort4*)&Hb[(size_t)col * DIM + lane * 4];
        acc.x += wgt * bf2f(h.x);
        acc.y += wgt * bf2f(h.y);
        acc.z += wgt * bf2f(h.z);
        acc.w += wgt * bf2f(h.w);
    }
    *(float4*)&out[(size_t)node * DIM + lane * 4] = acc;
}

// ---------------------------------------------------------------------------
// Y = (0.5*(P0+P1+P2+P3) + 0.5*GNN) @ Wc + bc
// ---------------------------------------------------------------------------
__global__ __launch_bounds__(256) void blend_cls_kernel(
    const float* __restrict__ p0, const float* __restrict__ p1,
    const float* __restrict__ p2, const float* __restrict__ p3,
    const float* __restrict__ gnn,
    const float* __restrict__ Wc, const float* __restrict__ bc,
    float* __restrict__ Y)
{
    const int row = blockIdx.x;
    const int t = threadIdx.x;
    __shared__ float z[DIM];
    __shared__ float part[4][NCLS];

    const size_t i = (size_t)row * DIM + t;
    z[t] = 0.5f * (p0[i] + p1[i] + p2[i] + p3[i] + gnn[i]);
    __syncthreads();

    if (t < 160) {
        const int c = t % NCLS, q = t / NCLS;
        float acc = 0.0f;
        #pragma unroll 4
        for (int d = q * 64; d < q * 64 + 64; ++d)
            acc += z[d] * Wc[d * NCLS + c];
        part[q][c] = acc;
    }
    __syncthreads();
    if (t < NCLS)
        Y[(size_t)row * NCLS + t] =
            part[0][t] + part[1][t] + part[2][t] + part[3][t] + bc[t];
}

// ---------------------------------------------------------------------------
extern "C" void kernel_launch(void* const* d_in, const int* in_sizes, int n_in,
                              void* d_out, int out_size, void* d_ws, size_t ws_size,
                              hipStream_t stream)
{
    const float* X     = (const float*)d_in[0];
    const int*   erow  = (const int*)d_in[1];
    const int*   ecol  = (const int*)d_in[2];
    const float* ew    = (const float*)d_in[3];
    const float* W_emb = (const float*)d_in[4];
    const float* b_emb = (const float*)d_in[5];
    const float* W_q   = (const float*)d_in[6];
    const float* b_q   = (const float*)d_in[7];
    const float* W_k   = (const float*)d_in[8];
    const float* b_k   = (const float*)d_in[9];
    const float* W_v   = (const float*)d_in[10];
    const float* b_v   = (const float*)d_in[11];
    const float* W_g   = (const float*)d_in[12];
    const float* b_g   = (const float*)d_in[13];
    const float* W_c   = (const float*)d_in[14];
    const float* b_c   = (const float*)d_in[15];
    const int E = in_sizes[1];

    float* Y    = (float*)d_out;
    float* Sc   = Y + (size_t)N_NODES * NCLS;      // attn [N,N]; Sb packed in rows
    unsigned short* Sb = (unsigned short*)Sc;      // row r at ushort offset r*16384

    const size_t ND = (size_t)N_NODES * DIM;       // 2M elements (8 MB fp32)
    float* R0 = (float*)d_ws;
    float* R1 = R0 + ND;
    float* R2 = R1 + ND;
    float* R3 = R2 + ND;
    float* R4 = R3 + ND;
    float* R5 = R4 + ND;
    float* R6 = R5 + ND;

    // phase-1 aliases
    unsigned short* Xh = (unsigned short*)R0;      // 8 MB
    unsigned short* Xl = (unsigned short*)R1;      // 8 MB
    unsigned short* Wt = (unsigned short*)R2;      // packed weight transposes
    unsigned short* WembTh = Wt;                   // 256x512
    unsigned short* WembTl = Wt + 256 * 512;
    unsigned short* WqTh = WembTl + 256 * 512;     // 256x256 each
    unsigned short* WqTl = WqTh + 256 * 256;
    unsigned short* WkTh = WqTl + 256 * 256;
    unsigned short* WkTl = WkTh + 256 * 256;
    unsigned short* WvTh = WkTl + 256 * 256;
    unsigned short* WvTl = WvTh + 256 * 256;
    unsigned short* WgTh = WvTl + 256 * 256;
    unsigned short* WgTl = WgTh + 256 * 256;
    unsigned short* Z0h = (unsigned short*)R3;     // 4 MB
    unsigned short* Z0l = Z0h + ND;                // 4 MB
    float* Qf = R4;
    float* Kf = R5;
    float* Vf = R6;
    unsigned short* Hb = (unsigned short*)R0;      // first 4 MB (X dead)
    // phase-2 aliases
    unsigned short* Qh = (unsigned short*)R1;      // Xl dead
    unsigned short* Ql = Qh + ND;
    unsigned short* Kh = (unsigned short*)R2;      // weights dead
    unsigned short* Kl = Kh + ND;
    unsigned short* VT = (unsigned short*)(R0 + ND / 2);  // second 4 MB of R0
    float2* pstat = (float2*)R4;                   // Qf dead after ln_split
    float*  factab = R5;                           // Kf dead after ln_split+qkt
    // ZA partials (each 8 MB)
    float* P0 = R6;   // Vf dead after vtrans
    float* P1 = R3;   // Z0 dead after projections
    float* P2 = R4;   // pstat dead after factor
    float* P3 = R1;   // Qh/Ql dead after qkt
    float* GNN = R2;  // Kh/Kl dead after qkt

    // 1. X -> hi/lo bf16
    split_kernel<<<(N_NODES * F_IN) / 1024, 256, 0, stream>>>(X, Xh, Xl);

    // 2. weight transposes (fp32 [K,N] -> bf16 hi/lo [N,K])
    wtrans_kernel<<<dim3(F_IN / 64, DIM / 64), 256, 0, stream>>>(W_emb, WembTh, WembTl, F_IN, DIM);
    wtrans_kernel<<<dim3(DIM / 64, DIM / 64), 256, 0, stream>>>(W_q, WqTh, WqTl, DIM, DIM);
    wtrans_kernel<<<dim3(DIM / 64, DIM / 64), 256, 0, stream>>>(W_k, WkTh, WkTl, DIM, DIM);
    wtrans_kernel<<<dim3(DIM / 64, DIM / 64), 256, 0, stream>>>(W_v, WvTh, WvTl, DIM, DIM);
    wtrans_kernel<<<dim3(DIM / 64, DIM / 64), 256, 0, stream>>>(W_g, WgTh, WgTl, DIM, DIM);

    // 3. Z0 = X @ W_emb + b (split-bf16 MFMA, output hi/lo)
    mfma_gemm3_kernel<F_IN, 2><<<dim3(2, N_NODES / 64), 256, 0, stream>>>(
        Xh, Xl, WembTh, WembTl, b_emb, Z0h, Z0l);

    // 4. all four projections in one launch
    Proj4Args pa;
    pa.Bh[0] = WqTh; pa.Bl[0] = WqTl; pa.bias[0] = b_q; pa.C[0] = Qf;
    pa.Bh[1] = WkTh; pa.Bl[1] = WkTl; pa.bias[1] = b_k; pa.C[1] = Kf;
    pa.Bh[2] = WvTh; pa.Bl[2] = WvTl; pa.bias[2] = b_v; pa.C[2] = Vf;
    pa.Bh[3] = WgTh; pa.Bl[3] = WgTl; pa.bias[3] = b_g; pa.C[3] = Hb;
    proj4_kernel<<<dim3(2, N_NODES / 64, 4), 256, 0, stream>>>(Z0h, Z0l, pa);

    // 5. LN + hi/lo split
    ln_split_kernel<<<N_NODES, 256, 0, stream>>>(Qf, Qh, Ql);
    ln_split_kernel<<<N_NODES, 256, 0, stream>>>(Kf, Kh, Kl);

    // 6. V -> VT bf16
    vtrans_kernel<<<dim3(N_NODES / 64, DIM / 64), 256, 0, stream>>>(Vf, VT);

    // 7. Sb = bf16 exp(QK^T - m_block) + pstat
    qkt_kernel<<<4096, 256, 0, stream>>>(Qh, Ql, Kh, Kl, Sb, pstat);

    // 8. factor table
    factor_kernel<<<N_NODES / 4, 256, 0, stream>>>(pstat, factab);

    // 9. ZA partials = (factor * Sb) @ V   (reads Sb, must precede scale)
    av_mfma_kernel<<<512, 256, 0, stream>>>(Sb, factab, VT, P0, P1, P2, P3);

    // 10. attn = bf2f(Sb) * factor, fp32 in place
    scale_kernel<<<N_NODES, 256, 0, stream>>>(Sb, factab, Sc);

    // 11. GNN branch (bf16 H)
    spmm_kernel<<<N_NODES / 4, 256, 0, stream>>>(Hb, erow, ecol, ew, GNN, E);

    // 12. blend (partials summed inline) + classifier
    blend_cls_kernel<<<N_NODES, 256, 0, stream>>>(
        P0, P1, P2, P3, GNN, W_c, b_c, Y);
}

// Round 11
// 441.318 us; speedup vs baseline: 1.6697x; 1.0320x over previous
//
#include <hip/hip_runtime.h>
#include <hip/hip_bf16.h>

#define N_NODES 8192
#define F_IN    512
#define DIM     256
#define NCLS    40

typedef __attribute__((ext_vector_type(8))) short bf16x8;
typedef __attribute__((ext_vector_type(4))) float f32x4;

#define MFMA16 __builtin_amdgcn_mfma_f32_16x16x32_bf16

static __device__ __forceinline__ unsigned short f2bf(float x) {
    __hip_bfloat16 h = __float2bfloat16(x);
    return *reinterpret_cast<unsigned short*>(&h);
}
static __device__ __forceinline__ float bf2f(unsigned short u) {
    union { unsigned int u32; float f; } v; v.u32 = ((unsigned int)u) << 16;
    return v.f;
}
static __device__ __forceinline__ void gll16(const void* g, void* l) {
    __builtin_amdgcn_global_load_lds(
        (const __attribute__((address_space(1))) unsigned int*)g,
        (__attribute__((address_space(3))) unsigned int*)l, 16, 0, 0);
}

// ---------------------------------------------------------------------------
// split: fp32 -> (hi, lo) bf16 pair, elementwise. 4 elems/thread.
// ---------------------------------------------------------------------------
__global__ __launch_bounds__(256) void split_kernel(
    const float* __restrict__ X,
    unsigned short* __restrict__ Xh, unsigned short* __restrict__ Xl)
{
    const size_t i = ((size_t)blockIdx.x * 256 + threadIdx.x) * 4;
    float4 v = *(const float4*)&X[i];
    ushort4 h, l;
    h.x = f2bf(v.x); l.x = f2bf(v.x - bf2f(h.x));
    h.y = f2bf(v.y); l.y = f2bf(v.y - bf2f(h.y));
    h.z = f2bf(v.z); l.z = f2bf(v.z - bf2f(h.z));
    h.w = f2bf(v.w); l.w = f2bf(v.w - bf2f(h.w));
    *(ushort4*)&Xh[i] = h;
    *(ushort4*)&Xl[i] = l;
}

// ---------------------------------------------------------------------------
// wtrans: W fp32 [K,N] -> WT hi/lo bf16 [N,K]. 64x64 LDS transpose tiles.
// ---------------------------------------------------------------------------
__global__ __launch_bounds__(256) void wtrans_kernel(
    const float* __restrict__ W,
    unsigned short* __restrict__ WTh, unsigned short* __restrict__ WTl,
    int K, int N)
{
    __shared__ float tile[64][65];
    const int r0 = blockIdx.x * 64;   // K dim
    const int c0 = blockIdx.y * 64;   // N dim
    const int t = threadIdx.x;
    #pragma unroll
    for (int i = 0; i < 4; ++i) {
        int r = i * 16 + (t >> 4);
        int c = (t & 15) * 4;
        float4 v = *(const float4*)&W[(size_t)(r0 + r) * N + c0 + c];
        tile[r][c] = v.x; tile[r][c + 1] = v.y;
        tile[r][c + 2] = v.z; tile[r][c + 3] = v.w;
    }
    __syncthreads();
    #pragma unroll
    for (int i = 0; i < 4; ++i) {
        int c = i * 16 + (t >> 4);    // N-local
        int r = (t & 15) * 4;         // K-local
        ushort4 h, l;
        float x0 = tile[r][c],     x1 = tile[r + 1][c];
        float x2 = tile[r + 2][c], x3 = tile[r + 3][c];
        h.x = f2bf(x0); l.x = f2bf(x0 - bf2f(h.x));
        h.y = f2bf(x1); l.y = f2bf(x1 - bf2f(h.y));
        h.z = f2bf(x2); l.z = f2bf(x2 - bf2f(h.z));
        h.w = f2bf(x3); l.w = f2bf(x3 - bf2f(h.w));
        *(ushort4*)&WTh[(size_t)(c0 + c) * K + r0 + r] = h;
        *(ushort4*)&WTl[(size_t)(c0 + c) * K + r0 + r] = l;
    }
}

// ---------------------------------------------------------------------------
// mfma_gemm3: C[M,256] = (Ah+Al)[M,K] x (Bh+Bl)[256,K]^T + bias, 3-term
// split-bf16 MFMA. BM=64, BN=128, BK=32, 4 waves. (used for embedding)
// OUTMODE: 0 = fp32 C0; 1 = bf16 C0; 2 = hi/lo split into C0,C1.
// ---------------------------------------------------------------------------
template<int KDIM, int OUTMODE>
__global__ __launch_bounds__(256, 4) void mfma_gemm3_kernel(
    const unsigned short* __restrict__ Ah_, const unsigned short* __restrict__ Al_,
    const unsigned short* __restrict__ Bh_, const unsigned short* __restrict__ Bl_,
    const float* __restrict__ bias,
    void* __restrict__ C0, void* __restrict__ C1)
{
    __shared__ short Ah[64][32], Al[64][32], Bh[128][32], Bl[128][32];

    const int m0 = blockIdx.y * 64;
    const int n0 = blockIdx.x * 128;
    const int t = threadIdx.x, lane = t & 63, w = t >> 6;
    const int wm = w >> 1, wn = w & 1;
    const int fr = lane & 15, kb = lane >> 4;

    f32x4 acc[2][4] = {};

    for (int k0 = 0; k0 < KDIM; k0 += 32) {
        #pragma unroll
        for (int r = 0; r < 2; ++r) {
            int c = r * 256 + t;
            int tens = c >> 8, idx = c & 255;
            int row = idx >> 2, slot = idx & 3;
            const unsigned short* src =
                (tens ? Al_ : Ah_) + (size_t)(m0 + row) * KDIM + k0 + slot * 8;
            gll16(src, (char*)(tens ? &Al[0][0] : &Ah[0][0]) + idx * 16);
        }
        #pragma unroll
        for (int r = 0; r < 4; ++r) {
            int c = r * 256 + t;
            int tens = c >> 9, idx = c & 511;
            int row = idx >> 2, slot = idx & 3;
            const unsigned short* src =
                (tens ? Bl_ : Bh_) + (size_t)(n0 + row) * KDIM + k0 + slot * 8;
            gll16(src, (char*)(tens ? &Bl[0][0] : &Bh[0][0]) + idx * 16);
        }
        __syncthreads();

        bf16x8 ah[2], al[2], bh[4], bl[4];
        #pragma unroll
        for (int m = 0; m < 2; ++m) {
            int row = wm * 32 + m * 16 + fr;
            ah[m] = *(const bf16x8*)&Ah[row][kb * 8];
            al[m] = *(const bf16x8*)&Al[row][kb * 8];
        }
        #pragma unroll
        for (int n = 0; n < 4; ++n) {
            int col = wn * 64 + n * 16 + fr;
            bh[n] = *(const bf16x8*)&Bh[col][kb * 8];
            bl[n] = *(const bf16x8*)&Bl[col][kb * 8];
        }
        #pragma unroll
        for (int m = 0; m < 2; ++m)
            #pragma unroll
            for (int n = 0; n < 4; ++n) {
                acc[m][n] = MFMA16(ah[m], bh[n], acc[m][n], 0, 0, 0);
                acc[m][n] = MFMA16(ah[m], bl[n], acc[m][n], 0, 0, 0);
                acc[m][n] = MFMA16(al[m], bh[n], acc[m][n], 0, 0, 0);
            }
        __syncthreads();
    }

    #pragma unroll
    for (int m = 0; m < 2; ++m)
        #pragma unroll
        for (int e = 0; e < 4; ++e) {
            const int row = m0 + wm * 32 + m * 16 + kb * 4 + e;
            #pragma unroll
            for (int n = 0; n < 4; ++n) {
                const int col = n0 + wn * 64 + n * 16 + fr;
                float v = acc[m][n][e] + bias[col];
                if (OUTMODE == 0) {
                    ((float*)C0)[(size_t)row * 256 + col] = v;
                } else if (OUTMODE == 1) {
                    ((unsigned short*)C0)[(size_t)row * 256 + col] = f2bf(v);
                } else {
                    unsigned short h = f2bf(v);
                    ((unsigned short*)C0)[(size_t)row * 256 + col] = h;
                    ((unsigned short*)C1)[(size_t)row * 256 + col] =
                        f2bf(v - bf2f(h));
                }
            }
        }
}

// ---------------------------------------------------------------------------
// proj4: all four DIM x DIM projections in one launch (z selects weights).
// z=0..2 -> fp32 out (Q,K,V); z=3 -> bf16 out (H). Shared Z0 A-panels.
// ---------------------------------------------------------------------------
struct Proj4Args {
    const unsigned short* Bh[4];
    const unsigned short* Bl[4];
    const float* bias[4];
    void* C[4];
};

__global__ __launch_bounds__(256, 4) void proj4_kernel(
    const unsigned short* __restrict__ Ah_, const unsigned short* __restrict__ Al_,
    Proj4Args p)
{
    __shared__ short Ah[64][32], Al[64][32], Bh[128][32], Bl[128][32];

    const int z  = blockIdx.z;
    const int m0 = blockIdx.y * 64;
    const int n0 = blockIdx.x * 128;
    const unsigned short* Bh_ = p.Bh[z];
    const unsigned short* Bl_ = p.Bl[z];
    const float* bias = p.bias[z];

    const int t = threadIdx.x, lane = t & 63, w = t >> 6;
    const int wm = w >> 1, wn = w & 1;
    const int fr = lane & 15, kb = lane >> 4;

    f32x4 acc[2][4] = {};

    for (int k0 = 0; k0 < DIM; k0 += 32) {
        #pragma unroll
        for (int r = 0; r < 2; ++r) {
            int c = r * 256 + t;
            int tens = c >> 8, idx = c & 255;
            int row = idx >> 2, slot = idx & 3;
            const unsigned short* src =
                (tens ? Al_ : Ah_) + (size_t)(m0 + row) * DIM + k0 + slot * 8;
            gll16(src, (char*)(tens ? &Al[0][0] : &Ah[0][0]) + idx * 16);
        }
        #pragma unroll
        for (int r = 0; r < 4; ++r) {
            int c = r * 256 + t;
            int tens = c >> 9, idx = c & 511;
            int row = idx >> 2, slot = idx & 3;
            const unsigned short* src =
                (tens ? Bl_ : Bh_) + (size_t)(n0 + row) * DIM + k0 + slot * 8;
            gll16(src, (char*)(tens ? &Bl[0][0] : &Bh[0][0]) + idx * 16);
        }
        __syncthreads();

        bf16x8 ah[2], al[2], bh[4], bl[4];
        #pragma unroll
        for (int m = 0; m < 2; ++m) {
            int row = wm * 32 + m * 16 + fr;
            ah[m] = *(const bf16x8*)&Ah[row][kb * 8];
            al[m] = *(const bf16x8*)&Al[row][kb * 8];
        }
        #pragma unroll
        for (int n = 0; n < 4; ++n) {
            int col = wn * 64 + n * 16 + fr;
            bh[n] = *(const bf16x8*)&Bh[col][kb * 8];
            bl[n] = *(const bf16x8*)&Bl[col][kb * 8];
        }
        #pragma unroll
        for (int m = 0; m < 2; ++m)
            #pragma unroll
            for (int n = 0; n < 4; ++n) {
                acc[m][n] = MFMA16(ah[m], bh[n], acc[m][n], 0, 0, 0);
                acc[m][n] = MFMA16(ah[m], bl[n], acc[m][n], 0, 0, 0);
                acc[m][n] = MFMA16(al[m], bh[n], acc[m][n], 0, 0, 0);
            }
        __syncthreads();
    }

    #pragma unroll
    for (int m = 0; m < 2; ++m)
        #pragma unroll
        for (int e = 0; e < 4; ++e) {
            const int row = m0 + wm * 32 + m * 16 + kb * 4 + e;
            #pragma unroll
            for (int n = 0; n < 4; ++n) {
                const int col = n0 + wn * 64 + n * 16 + fr;
                float v = acc[m][n][e] + bias[col];
                if (z < 3)
                    ((float*)p.C[z])[(size_t)row * 256 + col] = v;
                else
                    ((unsigned short*)p.C[z])[(size_t)row * 256 + col] = f2bf(v);
            }
        }
}

// ---------------------------------------------------------------------------
// LayerNorm + hi/lo bf16 split.
// ---------------------------------------------------------------------------
__global__ __launch_bounds__(256) void ln_split_kernel(
    const float* __restrict__ X,
    unsigned short* __restrict__ Hi, unsigned short* __restrict__ Lo)
{
    const int row = blockIdx.x;
    const int t = threadIdx.x;
    float x = X[(size_t)row * DIM + t];

    float s1 = x, s2 = x * x;
    #pragma unroll
    for (int o = 32; o; o >>= 1) {
        s1 += __shfl_xor(s1, o);
        s2 += __shfl_xor(s2, o);
    }
    __shared__ float r1[4], r2[4];
    const int wid = t >> 6;
    if ((t & 63) == 0) { r1[wid] = s1; r2[wid] = s2; }
    __syncthreads();
    const float sum = r1[0] + r1[1] + r1[2] + r1[3];
    const float ssq = r2[0] + r2[1] + r2[2] + r2[3];
    const float mean = sum * (1.0f / DIM);
    const float var  = ssq * (1.0f / DIM) - mean * mean;
    const float y = (x - mean) * rsqrtf(var + 1e-5f);

    const unsigned short h = f2bf(y);
    Hi[(size_t)row * DIM + t] = h;
    Lo[(size_t)row * DIM + t] = f2bf(y - bf2f(h));
}

// ---------------------------------------------------------------------------
// V [8192,256] fp32 -> VT [256,8192] bf16.
// ---------------------------------------------------------------------------
__global__ __launch_bounds__(256) void vtrans_kernel(
    const float* __restrict__ V, unsigned short* __restrict__ VT)
{
    __shared__ float tile[64][65];
    const int r0 = blockIdx.x * 64;
    const int c0 = blockIdx.y * 64;
    const int t = threadIdx.x;
    #pragma unroll
    for (int i = 0; i < 4; ++i) {
        int r = i * 16 + (t >> 4);
        int c = (t & 15) * 4;
        float4 v = *(const float4*)&V[(size_t)(r0 + r) * DIM + c0 + c];
        tile[r][c] = v.x; tile[r][c + 1] = v.y;
        tile[r][c + 2] = v.z; tile[r][c + 3] = v.w;
    }
    __syncthreads();
    #pragma unroll
    for (int i = 0; i < 4; ++i) {
        int c = i * 16 + (t >> 4);
        int r = (t & 15) * 4;
        ushort4 o;
        o.x = f2bf(tile[r][c]);     o.y = f2bf(tile[r + 1][c]);
        o.z = f2bf(tile[r + 2][c]); o.w = f2bf(tile[r + 3][c]);
        *(ushort4*)&VT[(size_t)(c0 + c) * N_NODES + r0 + r] = o;
    }
}

// ---------------------------------------------------------------------------
// scores = Q @ K^T (split-bf16, 3 MFMA terms). 2D-chunked XCD ordering.
// Epilogue tile writes use chunk^=2*kb XOR swizzle (bank-conflict-free).
// Sb row stride 16384 ushorts (32KB attn slot); pstat=(m_blk, sumexp_blk).
// ---------------------------------------------------------------------------
__global__ __launch_bounds__(256, 4) void qkt_kernel(
    const unsigned short* __restrict__ Qh, const unsigned short* __restrict__ Ql,
    const unsigned short* __restrict__ Kh, const unsigned short* __restrict__ Kl,
    unsigned short* __restrict__ Sb, float2* __restrict__ pstat)
{
    __shared__ short stage[4][128][32];   // Ah/Al/Bh/Bl; reused as bf16 out-tile
    __shared__ float2 ps[2][128];
    __shared__ float gmr[128];

    // 2D-chunked XCD swizzle: xcd owns mb in [x*8,x*8+8); nb grouped by 8.
    const int bid = blockIdx.x;
    const int x   = bid & 7;
    const int i   = bid >> 3;          // 0..511
    const int nbs = i >> 6;            // 0..7
    const int j   = i & 63;
    const int mb  = x * 8 + (j & 7);
    const int nb  = nbs * 8 + (j >> 3);
    const int m0 = mb * 128, n0 = nb * 128;

    const int t = threadIdx.x, lane = t & 63, w = t >> 6;
    const int wm = w >> 1, wn = w & 1;
    const int fr = lane & 15, kb = lane >> 4;

    f32x4 acc[4][4] = {};

    for (int k0 = 0; k0 < DIM; k0 += 32) {
        #pragma unroll
        for (int r = 0; r < 2; ++r) {
            int c = r * 256 + t;
            int row = c >> 2, slot = c & 3;
            size_t ga = (size_t)(m0 + row) * DIM + k0 + slot * 8;
            size_t gb = (size_t)(n0 + row) * DIM + k0 + slot * 8;
            int lo = c * 16;
            gll16(Qh + ga, (char*)&stage[0][0][0] + lo);
            gll16(Ql + ga, (char*)&stage[1][0][0] + lo);
            gll16(Kh + gb, (char*)&stage[2][0][0] + lo);
            gll16(Kl + gb, (char*)&stage[3][0][0] + lo);
        }
        __syncthreads();

        bf16x8 ah[4], al[4], bh[4], bl[4];
        #pragma unroll
        for (int m = 0; m < 4; ++m) {
            int row = wm * 64 + m * 16 + fr;
            ah[m] = *(const bf16x8*)&stage[0][row][kb * 8];
            al[m] = *(const bf16x8*)&stage[1][row][kb * 8];
        }
        #pragma unroll
        for (int n = 0; n < 4; ++n) {
            int col = wn * 64 + n * 16 + fr;
            bh[n] = *(const bf16x8*)&stage[2][col][kb * 8];
            bl[n] = *(const bf16x8*)&stage[3][col][kb * 8];
        }
        #pragma unroll
        for (int m = 0; m < 4; ++m)
            #pragma unroll
            for (int n = 0; n < 4; ++n) {
                acc[m][n] = MFMA16(ah[m], bh[n], acc[m][n], 0, 0, 0);
                acc[m][n] = MFMA16(ah[m], bl[n], acc[m][n], 0, 0, 0);
                acc[m][n] = MFMA16(al[m], bh[n], acc[m][n], 0, 0, 0);
            }
        __syncthreads();
    }

    // ---- phase A: per-row max over this block's 128 cols
    #pragma unroll
    for (int m = 0; m < 4; ++m)
        #pragma unroll
        for (int e = 0; e < 4; ++e) {
            float mx = acc[m][0][e];
            #pragma unroll
            for (int n = 1; n < 4; ++n) mx = fmaxf(mx, acc[m][n][e]);
            #pragma unroll
            for (int o = 1; o < 16; o <<= 1) mx = fmaxf(mx, __shfl_xor(mx, o));
            if (fr == 0) ps[wn][wm * 64 + m * 16 + kb * 4 + e].x = mx;
        }
    __syncthreads();
    if (t < 128) gmr[t] = fmaxf(ps[0][t].x, ps[1][t].x);
    __syncthreads();

    // ---- phase B: single exp pass -> bf16 tile (XOR-swizzled) + sumexp
    unsigned short* tile = (unsigned short*)&stage[0][0][0];   // [128][128]
    #pragma unroll
    for (int m = 0; m < 4; ++m)
        #pragma unroll
        for (int e = 0; e < 4; ++e) {
            const int rl = wm * 64 + m * 16 + kb * 4 + e;
            const float g = gmr[rl];
            const int key = kb << 1;           // (rl>>2)&3 == kb
            float se = 0.f;
            #pragma unroll
            for (int n = 0; n < 4; ++n) {
                float ev = __expf(acc[m][n][e] - g);
                se += ev;
                const int col = wn * 64 + n * 16 + fr;
                tile[rl * 128 + (((col >> 3) ^ key) << 3) + (col & 7)] =
                    f2bf(ev);
            }
            #pragma unroll
            for (int o = 1; o < 16; o <<= 1) se += __shfl_xor(se, o);
            if (fr == 0) ps[wn][rl].y = se;
        }
    __syncthreads();
    if (t < 128)
        pstat[(size_t)(m0 + t) * 64 + nb] =
            make_float2(gmr[t], ps[0][t].y + ps[1][t].y);

    // ---- coalesced bf16 store (undo the chunk XOR on the LDS read side)
    #pragma unroll
    for (int p = 0; p < 8; ++p) {
        int c = p * 256 + t;            // 16B chunk id (2048 total)
        int r = c >> 4, sl = c & 15;
        int slx = sl ^ (((r >> 2) & 3) << 1);
        *(int4*)&Sb[(size_t)(m0 + r) * 16384 + n0 + sl * 8] =
            *(const int4*)((const char*)tile + (r * 16 + slx) * 16);
    }
}

// ---------------------------------------------------------------------------
// factab[row][cb] = exp(m_cb - m_row) / Z_row. 4 rows/block, 64 lanes/row.
// ---------------------------------------------------------------------------
__global__ __launch_bounds__(256) void factor_kernel(
    const float2* __restrict__ pstat, float* __restrict__ factab)
{
    const int row = blockIdx.x * 4 + (threadIdx.x >> 6);
    const int lane = threadIdx.x & 63;
    float2 v = pstat[(size_t)row * 64 + lane];
    float gm = v.x;
    #pragma unroll
    for (int o = 1; o < 64; o <<= 1) gm = fmaxf(gm, __shfl_xor(gm, o));
    float s = v.y * __expf(v.x - gm);
    #pragma unroll
    for (int o = 1; o < 64; o <<= 1) s += __shfl_xor(s, o);
    factab[(size_t)row * 64 + lane] = __expf(v.x - gm) / s;
}

// ---------------------------------------------------------------------------
// av_mfma: ZA partials = (factor * Sb) @ VT^T via per-step scaled MFMA.
// Block order: ks slow per XCD so each XCD keeps one 1MB VT k-slice in L2.
// ---------------------------------------------------------------------------
__global__ __launch_bounds__(256, 2) void av_mfma_kernel(
    const unsigned short* __restrict__ Sb, const float* __restrict__ factab,
    const unsigned short* __restrict__ VT,
    float* __restrict__ P0, float* __restrict__ P1,
    float* __restrict__ P2, float* __restrict__ P3)
{
    __shared__ unsigned short As[2][64][128];   // linear dest, swizzled source
    __shared__ float facsT[16][64];             // [local cb][row]

    const int bid = blockIdx.x;
    const int x = bid & 7, i = bid >> 3;        // i in [0,64)
    const int ks = i >> 4;                      // slow per XCD
    const int rb = (i & 15) * 8 + x;            // 0..127
    const int r0 = rb * 64, kbase = ks * 2048, cb0 = ks * 16;
    const int t = threadIdx.x, lane = t & 63, w = t >> 6;
    const int fr = lane & 15, kb = lane >> 4;

    for (int ii = t; ii < 1024; ii += 256)
        facsT[ii >> 6][ii & 63] =
            factab[(size_t)(r0 + (ii & 63)) * 64 + cb0 + (ii >> 6)];

    const unsigned short* vb[4];
    #pragma unroll
    for (int n = 0; n < 4; ++n)
        vb[n] = VT + (size_t)(w * 64 + n * 16 + fr) * N_NODES + kbase + kb * 8;

    #define STAGE(S_, BUF_) do {                                              \
        _Pragma("unroll")                                                     \
        for (int p = 0; p < 4; ++p) {                                         \
            int c = p * 256 + t;                                              \
            int rr = c >> 4, sl = c & 15;                                     \
            int slp = sl ^ (rr & 7);                                          \
            gll16(Sb + (size_t)(r0 + rr) * 16384 + kbase + (S_) * 128 + slp * 8, \
                  (char*)&As[BUF_][0][0] + c * 16);                           \
        } } while (0)

    f32x4 acc[4][4] = {};
    const f32x4 z4 = {0.f, 0.f, 0.f, 0.f};

    STAGE(0, 0);
    __syncthreads();

    for (int s = 0; s < 16; ++s) {
        const int b = s & 1;
        if (s + 1 < 16) STAGE(s + 1, b ^ 1);

        bf16x8 bb[4][4];
        #pragma unroll
        for (int ksl = 0; ksl < 4; ++ksl)
            #pragma unroll
            for (int n = 0; n < 4; ++n)
                bb[ksl][n] = *(const bf16x8*)(vb[n] + s * 128 + ksl * 32);

        const char* abase = (const char*)&As[b][0][0];
        #pragma unroll
        for (int m = 0; m < 4; ++m) {
            f32x4 sacc[4];
            {
                bf16x8 a = *(const bf16x8*)(abase + (m * 16 + fr) * 256 +
                                            ((kb ^ (fr & 7)) * 16));
                #pragma unroll
                for (int n = 0; n < 4; ++n)
                    sacc[n] = MFMA16(a, bb[0][n], z4, 0, 0, 0);
            }
            #pragma unroll
            for (int ksl = 1; ksl < 4; ++ksl) {
                bf16x8 a = *(const bf16x8*)(abase + (m * 16 + fr) * 256 +
                                            (((ksl * 4 + kb) ^ (fr & 7)) * 16));
                #pragma unroll
                for (int n = 0; n < 4; ++n)
                    sacc[n] = MFMA16(a, bb[ksl][n], sacc[n], 0, 0, 0);
            }
            f32x4 fac = *(const f32x4*)&facsT[s][m * 16 + kb * 4];
            #pragma unroll
            for (int n = 0; n < 4; ++n)
                acc[m][n] += fac * sacc[n];
        }
        __syncthreads();
    }
    #undef STAGE

    float* P = (ks == 0) ? P0 : (ks == 1) ? P1 : (ks == 2) ? P2 : P3;
    #pragma unroll
    for (int m = 0; m < 4; ++m)
        #pragma unroll
        for (int e = 0; e < 4; ++e) {
            int row = r0 + m * 16 + kb * 4 + e;
            #pragma unroll
            for (int n = 0; n < 4; ++n)
                P[(size_t)row * DIM + w * 64 + n * 16 + fr] = acc[m][n][e];
        }
}

// ---------------------------------------------------------------------------
// scale: attn[row] = bf2f(Sb[row]) * factor, fp32 in place over the same
// row slot. Register-staged: all reads, barrier, all writes.
// ---------------------------------------------------------------------------
__global__ __launch_bounds__(256) void scale_kernel(
    const unsigned short* __restrict__ Sb, const float* __restrict__ factab,
    float* __restrict__ attn)
{
    const int row = blockIdx.x;
    const int t = threadIdx.x;
    const unsigned short* src = Sb + (size_t)row * 16384;

    int4 v[4];
    float f[4];
    #pragma unroll
    for (int p = 0; p < 4; ++p) {
        int c = p * 256 + t;
        v[p] = *(const int4*)&src[c * 8];
        f[p] = factab[(size_t)row * 64 + (c >> 4)];
    }
    __syncthreads();

    float* dst = attn + (size_t)row * N_NODES;
    #pragma unroll
    for (int p = 0; p < 4; ++p) {
        int c = p * 256 + t;
        float4 o0, o1;
        o0.x = bf2f((unsigned short)(v[p].x & 0xffff)) * f[p];
        o0.y = bf2f((unsigned short)((unsigned)v[p].x >> 16)) * f[p];
        o0.z = bf2f((unsigned short)(v[p].y & 0xffff)) * f[p];
        o0.w = bf2f((unsigned short)((unsigned)v[p].y >> 16)) * f[p];
        o1.x = bf2f((unsigned short)(v[p].z & 0xffff)) * f[p];
        o1.y = bf2f((unsigned short)((unsigned)v[p].z >> 16)) * f[p];
        o1.z = bf2f((unsigned short)(v[p].w & 0xffff)) * f[p];
        o1.w = bf2f((unsigned short)((unsigned)v[p].w >> 16)) * f[p];
        *(float4*)(dst + c * 8)     = o0;
        *(float4*)(dst + c * 8 + 4) = o1;
    }
}

// ---------------------------------------------------------------------------
// SpMM: one 64-lane wave per node, lane holds 4 features (ushort4 loads).
// ---------------------------------------------------------------------------
__global__ __launch_bounds__(256) void spmm_kernel(
    const unsigned short* __restrict__ Hb, const int* __restrict__ erow,
    const int* __restrict__ ecol, const float* __restrict__ ew,
    float* __restrict__ out, int E)
{
    const int node = blockIdx.x * 4 + (threadIdx.x >> 6);
    const int lane = threadIdx.x & 63;

    int lo = 0, hi = E;
    while (lo < hi) { int mid = (lo + hi) >> 1; if (erow[mid] < node) lo = mid + 1; else hi = mid; }
    const int beg = lo;
    hi = E;
    while (lo < hi) { int mid = (lo + hi) >> 1; if (erow[mid] < node + 1) lo = mid + 1; else hi = mid; }
    const int end = lo;

    float4 acc = make_float4(0.f, 0.f, 0.f, 0.f);
    for (int e = beg; e < end; ++e) {
        const int col = ecol[e];
        const float wgt = ew[e];
        ushort4 h = *(const ushort4*)&Hb[(size_t)col * DIM + lane * 4];
        acc.x += wgt * bf2f(h.x);
        acc.y += wgt * bf2f(h.y);
        acc.z += wgt * bf2f(h.z);
        acc.w += wgt * bf2f(h.w);
    }
    *(float4*)&out[(size_t)node * DIM + lane * 4] = acc;
}

// ---------------------------------------------------------------------------
// Y = (0.5*(P0+P1+P2+P3) + 0.5*GNN) @ Wc + bc
// ---------------------------------------------------------------------------
__global__ __launch_bounds__(256) void blend_cls_kernel(
    const float* __restrict__ p0, const float* __restrict__ p1,
    const float* __restrict__ p2, const float* __restrict__ p3,
    const float* __restrict__ gnn,
    const float* __restrict__ Wc, const float* __restrict__ bc,
    float* __restrict__ Y)
{
    const int row = blockIdx.x;
    const int t = threadIdx.x;
    __shared__ float z[DIM];
    __shared__ float part[4][NCLS];

    const size_t i = (size_t)row * DIM + t;
    z[t] = 0.5f * (p0[i] + p1[i] + p2[i] + p3[i] + gnn[i]);
    __syncthreads();

    if (t < 160) {
        const int c = t % NCLS, q = t / NCLS;
        float acc = 0.0f;
        #pragma unroll 4
        for (int d = q * 64; d < q * 64 + 64; ++d)
            acc += z[d] * Wc[d * NCLS + c];
        part[q][c] = acc;
    }
    __syncthreads();
    if (t < NCLS)
        Y[(size_t)row * NCLS + t] =
            part[0][t] + part[1][t] + part[2][t] + part[3][t] + bc[t];
}

// ---------------------------------------------------------------------------
extern "C" void kernel_launch(void* const* d_in, const int* in_sizes, int n_in,
                              void* d_out, int out_size, void* d_ws, size_t ws_size,
                              hipStream_t stream)
{
    const float* X     = (const float*)d_in[0];
    const int*   erow  = (const int*)d_in[1];
    const int*   ecol  = (const int*)d_in[2];
    const float* ew    = (const float*)d_in[3];
    const float* W_emb = (const float*)d_in[4];
    const float* b_emb = (const float*)d_in[5];
    const float* W_q   = (const float*)d_in[6];
    const float* b_q   = (const float*)d_in[7];
    const float* W_k   = (const float*)d_in[8];
    const float* b_k   = (const float*)d_in[9];
    const float* W_v   = (const float*)d_in[10];
    const float* b_v   = (const float*)d_in[11];
    const float* W_g   = (const float*)d_in[12];
    const float* b_g   = (const float*)d_in[13];
    const float* W_c   = (const float*)d_in[14];
    const float* b_c   = (const float*)d_in[15];
    const int E = in_sizes[1];

    float* Y    = (float*)d_out;
    float* Sc   = Y + (size_t)N_NODES * NCLS;      // attn [N,N]; Sb packed in rows
    unsigned short* Sb = (unsigned short*)Sc;      // row r at ushort offset r*16384

    const size_t ND = (size_t)N_NODES * DIM;       // 2M elements (8 MB fp32)
    float* R0 = (float*)d_ws;
    float* R1 = R0 + ND;
    float* R2 = R1 + ND;
    float* R3 = R2 + ND;
    float* R4 = R3 + ND;
    float* R5 = R4 + ND;
    float* R6 = R5 + ND;

    // phase-1 aliases
    unsigned short* Xh = (unsigned short*)R0;      // 8 MB
    unsigned short* Xl = (unsigned short*)R1;      // 8 MB
    unsigned short* Wt = (unsigned short*)R2;      // packed weight transposes
    unsigned short* WembTh = Wt;                   // 256x512
    unsigned short* WembTl = Wt + 256 * 512;
    unsigned short* WqTh = WembTl + 256 * 512;     // 256x256 each
    unsigned short* WqTl = WqTh + 256 * 256;
    unsigned short* WkTh = WqTl + 256 * 256;
    unsigned short* WkTl = WkTh + 256 * 256;
    unsigned short* WvTh = WkTl + 256 * 256;
    unsigned short* WvTl = WvTh + 256 * 256;
    unsigned short* WgTh = WvTl + 256 * 256;
    unsigned short* WgTl = WgTh + 256 * 256;
    unsigned short* Z0h = (unsigned short*)R3;     // 4 MB
    unsigned short* Z0l = Z0h + ND;                // 4 MB
    float* Qf = R4;
    float* Kf = R5;
    float* Vf = R6;
    unsigned short* Hb = (unsigned short*)R0;      // first 4 MB (X dead)
    // phase-2 aliases
    unsigned short* Qh = (unsigned short*)R1;      // Xl dead
    unsigned short* Ql = Qh + ND;
    unsigned short* Kh = (unsigned short*)R2;      // weights dead
    unsigned short* Kl = Kh + ND;
    unsigned short* VT = (unsigned short*)(R0 + ND / 2);  // second 4 MB of R0
    float2* pstat = (float2*)R4;                   // Qf dead after ln_split
    float*  factab = R5;                           // Kf dead after ln_split+qkt
    // ZA partials (each 8 MB)
    float* P0 = R6;   // Vf dead after vtrans
    float* P1 = R3;   // Z0 dead after projections
    float* P2 = R4;   // pstat dead after factor
    float* P3 = R1;   // Qh/Ql dead after qkt
    float* GNN = R2;  // Kh/Kl dead after qkt

    // 1. X -> hi/lo bf16
    split_kernel<<<(N_NODES * F_IN) / 1024, 256, 0, stream>>>(X, Xh, Xl);

    // 2. weight transposes (fp32 [K,N] -> bf16 hi/lo [N,K])
    wtrans_kernel<<<dim3(F_IN / 64, DIM / 64), 256, 0, stream>>>(W_emb, WembTh, WembTl, F_IN, DIM);
    wtrans_kernel<<<dim3(DIM / 64, DIM / 64), 256, 0, stream>>>(W_q, WqTh, WqTl, DIM, DIM);
    wtrans_kernel<<<dim3(DIM / 64, DIM / 64), 256, 0, stream>>>(W_k, WkTh, WkTl, DIM, DIM);
    wtrans_kernel<<<dim3(DIM / 64, DIM / 64), 256, 0, stream>>>(W_v, WvTh, WvTl, DIM, DIM);
    wtrans_kernel<<<dim3(DIM / 64, DIM / 64), 256, 0, stream>>>(W_g, WgTh, WgTl, DIM, DIM);

    // 3. Z0 = X @ W_emb + b (split-bf16 MFMA, output hi/lo)
    mfma_gemm3_kernel<F_IN, 2><<<dim3(2, N_NODES / 64), 256, 0, stream>>>(
        Xh, Xl, WembTh, WembTl, b_emb, Z0h, Z0l);

    // 4. all four projections in one launch
    Proj4Args pa;
    pa.Bh[0] = WqTh; pa.Bl[0] = WqTl; pa.bias[0] = b_q; pa.C[0] = Qf;
    pa.Bh[1] = WkTh; pa.Bl[1] = WkTl; pa.bias[1] = b_k; pa.C[1] = Kf;
    pa.Bh[2] = WvTh; pa.Bl[2] = WvTl; pa.bias[2] = b_v; pa.C[2] = Vf;
    pa.Bh[3] = WgTh; pa.Bl[3] = WgTl; pa.bias[3] = b_g; pa.C[3] = Hb;
    proj4_kernel<<<dim3(2, N_NODES / 64, 4), 256, 0, stream>>>(Z0h, Z0l, pa);

    // 5. LN + hi/lo split
    ln_split_kernel<<<N_NODES, 256, 0, stream>>>(Qf, Qh, Ql);
    ln_split_kernel<<<N_NODES, 256, 0, stream>>>(Kf, Kh, Kl);

    // 6. V -> VT bf16
    vtrans_kernel<<<dim3(N_NODES / 64, DIM / 64), 256, 0, stream>>>(Vf, VT);

    // 7. Sb = bf16 exp(QK^T - m_block) + pstat
    qkt_kernel<<<4096, 256, 0, stream>>>(Qh, Ql, Kh, Kl, Sb, pstat);

    // 8. factor table
    factor_kernel<<<N_NODES / 4, 256, 0, stream>>>(pstat, factab);

    // 9. ZA partials = (factor * Sb) @ V   (reads Sb, must precede scale)
    av_mfma_kernel<<<512, 256, 0, stream>>>(Sb, factab, VT, P0, P1, P2, P3);

    // 10. attn = bf2f(Sb) * factor, fp32 in place
    scale_kernel<<<N_NODES, 256, 0, stream>>>(Sb, factab, Sc);

    // 11. GNN branch (bf16 H)
    spmm_kernel<<<N_NODES / 4, 256, 0, stream>>>(Hb, erow, ecol, ew, GNN, E);

    // 12. blend (partials summed inline) + classifier
    blend_cls_kernel<<<N_NODES, 256, 0, stream>>>(
        P0, P1, P2, P3, GNN, W_c, b_c, Y);
}

// Round 12
// 429.786 us; speedup vs baseline: 1.7145x; 1.0268x over previous
//
#include <hip/hip_runtime.h>
#include <hip/hip_bf16.h>

#define N_NODES 8192
#define F_IN    512
#define DIM     256
#define NCLS    40

typedef __attribute__((ext_vector_type(8))) short bf16x8;
typedef __attribute__((ext_vector_type(4))) float f32x4;

#define MFMA16 __builtin_amdgcn_mfma_f32_16x16x32_bf16

static __device__ __forceinline__ unsigned short f2bf(float x) {
    __hip_bfloat16 h = __float2bfloat16(x);
    return *reinterpret_cast<unsigned short*>(&h);
}
static __device__ __forceinline__ float bf2f(unsigned short u) {
    union { unsigned int u32; float f; } v; v.u32 = ((unsigned int)u) << 16;
    return v.f;
}
static __device__ __forceinline__ void gll16(const void* g, void* l) {
    __builtin_amdgcn_global_load_lds(
        (const __attribute__((address_space(1))) unsigned int*)g,
        (__attribute__((address_space(3))) unsigned int*)l, 16, 0, 0);
}

// ---------------------------------------------------------------------------
// split: fp32 -> (hi, lo) bf16 pair, elementwise. 4 elems/thread.
// ---------------------------------------------------------------------------
__global__ __launch_bounds__(256) void split_kernel(
    const float* __restrict__ X,
    unsigned short* __restrict__ Xh, unsigned short* __restrict__ Xl)
{
    const size_t i = ((size_t)blockIdx.x * 256 + threadIdx.x) * 4;
    float4 v = *(const float4*)&X[i];
    ushort4 h, l;
    h.x = f2bf(v.x); l.x = f2bf(v.x - bf2f(h.x));
    h.y = f2bf(v.y); l.y = f2bf(v.y - bf2f(h.y));
    h.z = f2bf(v.z); l.z = f2bf(v.z - bf2f(h.z));
    h.w = f2bf(v.w); l.w = f2bf(v.w - bf2f(h.w));
    *(ushort4*)&Xh[i] = h;
    *(ushort4*)&Xl[i] = l;
}

// ---------------------------------------------------------------------------
// wtrans: W fp32 [K,N] -> WT hi/lo bf16 [N,K]. 64x64 LDS transpose tiles.
// ---------------------------------------------------------------------------
__global__ __launch_bounds__(256) void wtrans_kernel(
    const float* __restrict__ W,
    unsigned short* __restrict__ WTh, unsigned short* __restrict__ WTl,
    int K, int N)
{
    __shared__ float tile[64][65];
    const int r0 = blockIdx.x * 64;   // K dim
    const int c0 = blockIdx.y * 64;   // N dim
    const int t = threadIdx.x;
    #pragma unroll
    for (int i = 0; i < 4; ++i) {
        int r = i * 16 + (t >> 4);
        int c = (t & 15) * 4;
        float4 v = *(const float4*)&W[(size_t)(r0 + r) * N + c0 + c];
        tile[r][c] = v.x; tile[r][c + 1] = v.y;
        tile[r][c + 2] = v.z; tile[r][c + 3] = v.w;
    }
    __syncthreads();
    #pragma unroll
    for (int i = 0; i < 4; ++i) {
        int c = i * 16 + (t >> 4);    // N-local
        int r = (t & 15) * 4;         // K-local
        ushort4 h, l;
        float x0 = tile[r][c],     x1 = tile[r + 1][c];
        float x2 = tile[r + 2][c], x3 = tile[r + 3][c];
        h.x = f2bf(x0); l.x = f2bf(x0 - bf2f(h.x));
        h.y = f2bf(x1); l.y = f2bf(x1 - bf2f(h.y));
        h.z = f2bf(x2); l.z = f2bf(x2 - bf2f(h.z));
        h.w = f2bf(x3); l.w = f2bf(x3 - bf2f(h.w));
        *(ushort4*)&WTh[(size_t)(c0 + c) * K + r0 + r] = h;
        *(ushort4*)&WTl[(size_t)(c0 + c) * K + r0 + r] = l;
    }
}

// ---------------------------------------------------------------------------
// mfma_gemm3: C[M,256] = (Ah+Al)[M,K] x (Bh+Bl)[256,K]^T + bias, 3-term
// split-bf16 MFMA. BM=128, BN=128, BK=32, 4 waves. Hoisted stage pointers.
// OUTMODE: 0 = fp32 C0; 1 = bf16 C0; 2 = hi/lo split into C0,C1.
// Z < 0: Bh_/Bl_/bias/C args used directly. Z >= 0 handled by proj4 wrapper.
// ---------------------------------------------------------------------------
template<int KDIM, int OUTMODE>
__device__ __forceinline__ void gemm3_body(
    const unsigned short* __restrict__ Ah_, const unsigned short* __restrict__ Al_,
    const unsigned short* __restrict__ Bh_, const unsigned short* __restrict__ Bl_,
    const float* __restrict__ bias,
    void* __restrict__ C0, void* __restrict__ C1,
    int m0, int n0,
    short (*Ah)[32], short (*Al)[32], short (*Bh)[32], short (*Bl)[32])
{
    const int t = threadIdx.x, lane = t & 63, w = t >> 6;
    const int wm = w >> 1, wn = w & 1;
    const int fr = lane & 15, kb = lane >> 4;

    // hoisted staging maps: 4 chunks A-side, 4 chunks B-side per thread
    const unsigned short* asrc[4];
    const unsigned short* bsrc[4];
    char* adst[4];
    char* bdst[4];
    #pragma unroll
    for (int r = 0; r < 4; ++r) {
        int c = r * 256 + t;
        int tens = c >> 9, idx = c & 511;
        int row = idx >> 2, slot = idx & 3;
        asrc[r] = (tens ? Al_ : Ah_) + (size_t)(m0 + row) * KDIM + slot * 8;
        adst[r] = (char*)(tens ? &Al[0][0] : &Ah[0][0]) + idx * 16;
        bsrc[r] = (tens ? Bl_ : Bh_) + (size_t)(n0 + row) * KDIM + slot * 8;
        bdst[r] = (char*)(tens ? &Bl[0][0] : &Bh[0][0]) + idx * 16;
    }

    f32x4 acc[4][4] = {};

    for (int k0 = 0; k0 < KDIM; k0 += 32) {
        #pragma unroll
        for (int r = 0; r < 4; ++r) { gll16(asrc[r], adst[r]); asrc[r] += 32; }
        #pragma unroll
        for (int r = 0; r < 4; ++r) { gll16(bsrc[r], bdst[r]); bsrc[r] += 32; }
        __syncthreads();

        bf16x8 ah[4], al[4], bh[4], bl[4];
        #pragma unroll
        for (int m = 0; m < 4; ++m) {
            int row = wm * 64 + m * 16 + fr;
            ah[m] = *(const bf16x8*)&Ah[row][kb * 8];
            al[m] = *(const bf16x8*)&Al[row][kb * 8];
        }
        #pragma unroll
        for (int n = 0; n < 4; ++n) {
            int col = wn * 64 + n * 16 + fr;
            bh[n] = *(const bf16x8*)&Bh[col][kb * 8];
            bl[n] = *(const bf16x8*)&Bl[col][kb * 8];
        }
        #pragma unroll
        for (int m = 0; m < 4; ++m)
            #pragma unroll
            for (int n = 0; n < 4; ++n) {
                acc[m][n] = MFMA16(ah[m], bh[n], acc[m][n], 0, 0, 0);
                acc[m][n] = MFMA16(ah[m], bl[n], acc[m][n], 0, 0, 0);
                acc[m][n] = MFMA16(al[m], bh[n], acc[m][n], 0, 0, 0);
            }
        __syncthreads();
    }

    #pragma unroll
    for (int m = 0; m < 4; ++m)
        #pragma unroll
        for (int e = 0; e < 4; ++e) {
            const int row = m0 + wm * 64 + m * 16 + kb * 4 + e;
            #pragma unroll
            for (int n = 0; n < 4; ++n) {
                const int col = n0 + wn * 64 + n * 16 + fr;
                float v = acc[m][n][e] + bias[col];
                if (OUTMODE == 0) {
                    ((float*)C0)[(size_t)row * 256 + col] = v;
                } else if (OUTMODE == 1) {
                    ((unsigned short*)C0)[(size_t)row * 256 + col] = f2bf(v);
                } else {
                    unsigned short h = f2bf(v);
                    ((unsigned short*)C0)[(size_t)row * 256 + col] = h;
                    ((unsigned short*)C1)[(size_t)row * 256 + col] =
                        f2bf(v - bf2f(h));
                }
            }
        }
}

template<int KDIM, int OUTMODE>
__global__ __launch_bounds__(256, 2) void mfma_gemm3_kernel(
    const unsigned short* __restrict__ Ah_, const unsigned short* __restrict__ Al_,
    const unsigned short* __restrict__ Bh_, const unsigned short* __restrict__ Bl_,
    const float* __restrict__ bias,
    void* __restrict__ C0, void* __restrict__ C1)
{
    __shared__ short Ah[128][32], Al[128][32], Bh[128][32], Bl[128][32];
    gemm3_body<KDIM, OUTMODE>(Ah_, Al_, Bh_, Bl_, bias, C0, C1,
                              blockIdx.y * 128, blockIdx.x * 128,
                              Ah, Al, Bh, Bl);
}

// ---------------------------------------------------------------------------
// proj4: all four DIM x DIM projections in one launch (z selects weights).
// z=0..2 -> fp32 out (Q,K,V); z=3 -> bf16 out (H). Shared Z0 A-panels.
// ---------------------------------------------------------------------------
struct Proj4Args {
    const unsigned short* Bh[4];
    const unsigned short* Bl[4];
    const float* bias[4];
    void* C[4];
};

__global__ __launch_bounds__(256, 2) void proj4_kernel(
    const unsigned short* __restrict__ Ah_, const unsigned short* __restrict__ Al_,
    Proj4Args p)
{
    __shared__ short Ah[128][32], Al[128][32], Bh[128][32], Bl[128][32];
    const int z = blockIdx.z;
    if (z < 3)
        gemm3_body<DIM, 0>(Ah_, Al_, p.Bh[z], p.Bl[z], p.bias[z], p.C[z],
                           nullptr, blockIdx.y * 128, blockIdx.x * 128,
                           Ah, Al, Bh, Bl);
    else
        gemm3_body<DIM, 1>(Ah_, Al_, p.Bh[z], p.Bl[z], p.bias[z], p.C[z],
                           nullptr, blockIdx.y * 128, blockIdx.x * 128,
                           Ah, Al, Bh, Bl);
}

// ---------------------------------------------------------------------------
// LayerNorm + hi/lo bf16 split.
// ---------------------------------------------------------------------------
__global__ __launch_bounds__(256) void ln_split_kernel(
    const float* __restrict__ X,
    unsigned short* __restrict__ Hi, unsigned short* __restrict__ Lo)
{
    const int row = blockIdx.x;
    const int t = threadIdx.x;
    float x = X[(size_t)row * DIM + t];

    float s1 = x, s2 = x * x;
    #pragma unroll
    for (int o = 32; o; o >>= 1) {
        s1 += __shfl_xor(s1, o);
        s2 += __shfl_xor(s2, o);
    }
    __shared__ float r1[4], r2[4];
    const int wid = t >> 6;
    if ((t & 63) == 0) { r1[wid] = s1; r2[wid] = s2; }
    __syncthreads();
    const float sum = r1[0] + r1[1] + r1[2] + r1[3];
    const float ssq = r2[0] + r2[1] + r2[2] + r2[3];
    const float mean = sum * (1.0f / DIM);
    const float var  = ssq * (1.0f / DIM) - mean * mean;
    const float y = (x - mean) * rsqrtf(var + 1e-5f);

    const unsigned short h = f2bf(y);
    Hi[(size_t)row * DIM + t] = h;
    Lo[(size_t)row * DIM + t] = f2bf(y - bf2f(h));
}

// ---------------------------------------------------------------------------
// V [8192,256] fp32 -> VT [256,8192] bf16.
// ---------------------------------------------------------------------------
__global__ __launch_bounds__(256) void vtrans_kernel(
    const float* __restrict__ V, unsigned short* __restrict__ VT)
{
    __shared__ float tile[64][65];
    const int r0 = blockIdx.x * 64;
    const int c0 = blockIdx.y * 64;
    const int t = threadIdx.x;
    #pragma unroll
    for (int i = 0; i < 4; ++i) {
        int r = i * 16 + (t >> 4);
        int c = (t & 15) * 4;
        float4 v = *(const float4*)&V[(size_t)(r0 + r) * DIM + c0 + c];
        tile[r][c] = v.x; tile[r][c + 1] = v.y;
        tile[r][c + 2] = v.z; tile[r][c + 3] = v.w;
    }
    __syncthreads();
    #pragma unroll
    for (int i = 0; i < 4; ++i) {
        int c = i * 16 + (t >> 4);
        int r = (t & 15) * 4;
        ushort4 o;
        o.x = f2bf(tile[r][c]);     o.y = f2bf(tile[r + 1][c]);
        o.z = f2bf(tile[r + 2][c]); o.w = f2bf(tile[r + 3][c]);
        *(ushort4*)&VT[(size_t)(c0 + c) * N_NODES + r0 + r] = o;
    }
}

// ---------------------------------------------------------------------------
// scores = Q @ K^T (split-bf16, 3 MFMA terms). 2D-chunked XCD ordering,
// hoisted staging pointers, single-exp epilogue.
// Sb row stride 16384 ushorts (32KB attn slot); pstat=(m_blk, sumexp_blk).
// ---------------------------------------------------------------------------
__global__ __launch_bounds__(256, 4) void qkt_kernel(
    const unsigned short* __restrict__ Qh, const unsigned short* __restrict__ Ql,
    const unsigned short* __restrict__ Kh, const unsigned short* __restrict__ Kl,
    unsigned short* __restrict__ Sb, float2* __restrict__ pstat)
{
    __shared__ short stage[4][128][32];   // Ah/Al/Bh/Bl; reused as bf16 out-tile
    __shared__ float2 ps[2][128];
    __shared__ float gmr[128];

    // 2D-chunked XCD swizzle: xcd owns mb in [x*8,x*8+8); nb grouped by 8.
    const int bid = blockIdx.x;
    const int x   = bid & 7;
    const int i   = bid >> 3;          // 0..511
    const int nbs = i >> 6;            // 0..7
    const int j   = i & 63;
    const int mb  = x * 8 + (j & 7);
    const int nb  = nbs * 8 + (j >> 3);
    const int m0 = mb * 128, n0 = nb * 128;

    const int t = threadIdx.x, lane = t & 63, w = t >> 6;
    const int wm = w >> 1, wn = w & 1;
    const int fr = lane & 15, kb = lane >> 4;

    // hoisted staging pointers (2 chunks x 4 tensors per thread)
    const unsigned short* qsrc[2][2];
    const unsigned short* ksrc[2][2];
    char* qdst[2][2];
    char* kdst[2][2];
    #pragma unroll
    for (int r = 0; r < 2; ++r) {
        int c = r * 256 + t;
        int row = c >> 2, slot = c & 3;
        size_t ga = (size_t)(m0 + row) * DIM + slot * 8;
        size_t gb = (size_t)(n0 + row) * DIM + slot * 8;
        qsrc[r][0] = Qh + ga; qsrc[r][1] = Ql + ga;
        ksrc[r][0] = Kh + gb; ksrc[r][1] = Kl + gb;
        qdst[r][0] = (char*)&stage[0][0][0] + c * 16;
        qdst[r][1] = (char*)&stage[1][0][0] + c * 16;
        kdst[r][0] = (char*)&stage[2][0][0] + c * 16;
        kdst[r][1] = (char*)&stage[3][0][0] + c * 16;
    }

    f32x4 acc[4][4] = {};

    for (int k0 = 0; k0 < DIM; k0 += 32) {
        #pragma unroll
        for (int r = 0; r < 2; ++r) {
            gll16(qsrc[r][0], qdst[r][0]); qsrc[r][0] += 32;
            gll16(qsrc[r][1], qdst[r][1]); qsrc[r][1] += 32;
            gll16(ksrc[r][0], kdst[r][0]); ksrc[r][0] += 32;
            gll16(ksrc[r][1], kdst[r][1]); ksrc[r][1] += 32;
        }
        __syncthreads();

        bf16x8 ah[4], al[4], bh[4], bl[4];
        #pragma unroll
        for (int m = 0; m < 4; ++m) {
            int row = wm * 64 + m * 16 + fr;
            ah[m] = *(const bf16x8*)&stage[0][row][kb * 8];
            al[m] = *(const bf16x8*)&stage[1][row][kb * 8];
        }
        #pragma unroll
        for (int n = 0; n < 4; ++n) {
            int col = wn * 64 + n * 16 + fr;
            bh[n] = *(const bf16x8*)&stage[2][col][kb * 8];
            bl[n] = *(const bf16x8*)&stage[3][col][kb * 8];
        }
        #pragma unroll
        for (int m = 0; m < 4; ++m)
            #pragma unroll
            for (int n = 0; n < 4; ++n) {
                acc[m][n] = MFMA16(ah[m], bh[n], acc[m][n], 0, 0, 0);
                acc[m][n] = MFMA16(ah[m], bl[n], acc[m][n], 0, 0, 0);
                acc[m][n] = MFMA16(al[m], bh[n], acc[m][n], 0, 0, 0);
            }
        __syncthreads();
    }

    // ---- phase A: per-row max over this block's 128 cols
    #pragma unroll
    for (int m = 0; m < 4; ++m)
        #pragma unroll
        for (int e = 0; e < 4; ++e) {
            float mx = acc[m][0][e];
            #pragma unroll
            for (int n = 1; n < 4; ++n) mx = fmaxf(mx, acc[m][n][e]);
            #pragma unroll
            for (int o = 1; o < 16; o <<= 1) mx = fmaxf(mx, __shfl_xor(mx, o));
            if (fr == 0) ps[wn][wm * 64 + m * 16 + kb * 4 + e].x = mx;
        }
    __syncthreads();
    if (t < 128) gmr[t] = fmaxf(ps[0][t].x, ps[1][t].x);
    __syncthreads();

    // ---- phase B: single exp pass -> bf16 tile (XOR-swizzled) + sumexp
    unsigned short* tile = (unsigned short*)&stage[0][0][0];   // [128][128]
    #pragma unroll
    for (int m = 0; m < 4; ++m)
        #pragma unroll
        for (int e = 0; e < 4; ++e) {
            const int rl = wm * 64 + m * 16 + kb * 4 + e;
            const float g = gmr[rl];
            const int key = kb << 1;           // (rl>>2)&3 == kb
            float se = 0.f;
            #pragma unroll
            for (int n = 0; n < 4; ++n) {
                float ev = __expf(acc[m][n][e] - g);
                se += ev;
                const int col = wn * 64 + n * 16 + fr;
                tile[rl * 128 + (((col >> 3) ^ key) << 3) + (col & 7)] =
                    f2bf(ev);
            }
            #pragma unroll
            for (int o = 1; o < 16; o <<= 1) se += __shfl_xor(se, o);
            if (fr == 0) ps[wn][rl].y = se;
        }
    __syncthreads();
    if (t < 128)
        pstat[(size_t)(m0 + t) * 64 + nb] =
            make_float2(gmr[t], ps[0][t].y + ps[1][t].y);

    // ---- coalesced bf16 store (undo the chunk XOR on the LDS read side)
    #pragma unroll
    for (int p = 0; p < 8; ++p) {
        int c = p * 256 + t;            // 16B chunk id (2048 total)
        int r = c >> 4, sl = c & 15;
        int slx = sl ^ (((r >> 2) & 3) << 1);
        *(int4*)&Sb[(size_t)(m0 + r) * 16384 + n0 + sl * 8] =
            *(const int4*)((const char*)tile + (r * 16 + slx) * 16);
    }
}

// ---------------------------------------------------------------------------
// factab[row][cb] = exp(m_cb - m_row) / Z_row. 4 rows/block, 64 lanes/row.
// ---------------------------------------------------------------------------
__global__ __launch_bounds__(256) void factor_kernel(
    const float2* __restrict__ pstat, float* __restrict__ factab)
{
    const int row = blockIdx.x * 4 + (threadIdx.x >> 6);
    const int lane = threadIdx.x & 63;
    float2 v = pstat[(size_t)row * 64 + lane];
    float gm = v.x;
    #pragma unroll
    for (int o = 1; o < 64; o <<= 1) gm = fmaxf(gm, __shfl_xor(gm, o));
    float s = v.y * __expf(v.x - gm);
    #pragma unroll
    for (int o = 1; o < 64; o <<= 1) s += __shfl_xor(s, o);
    factab[(size_t)row * 64 + lane] = __expf(v.x - gm) / s;
}

// ---------------------------------------------------------------------------
// av_mfma: ZA partials = (factor * Sb) @ VT^T via per-step scaled MFMA.
// Hoisted STAGE pointers; ks slow per XCD for VT L2 residency.
// ---------------------------------------------------------------------------
__global__ __launch_bounds__(256, 2) void av_mfma_kernel(
    const unsigned short* __restrict__ Sb, const float* __restrict__ factab,
    const unsigned short* __restrict__ VT,
    float* __restrict__ P0, float* __restrict__ P1,
    float* __restrict__ P2, float* __restrict__ P3)
{
    __shared__ unsigned short As[2][64][128];   // linear dest, swizzled source
    __shared__ float facsT[16][64];             // [local cb][row]

    const int bid = blockIdx.x;
    const int x = bid & 7, i = bid >> 3;        // i in [0,64)
    const int ks = i >> 4;                      // slow per XCD
    const int rb = (i & 15) * 8 + x;            // 0..127
    const int r0 = rb * 64, kbase = ks * 2048, cb0 = ks * 16;
    const int t = threadIdx.x, lane = t & 63, w = t >> 6;
    const int fr = lane & 15, kb = lane >> 4;

    for (int ii = t; ii < 1024; ii += 256)
        facsT[ii >> 6][ii & 63] =
            factab[(size_t)(r0 + (ii & 63)) * 64 + cb0 + (ii >> 6)];

    const unsigned short* vb[4];
    #pragma unroll
    for (int n = 0; n < 4; ++n)
        vb[n] = VT + (size_t)(w * 64 + n * 16 + fr) * N_NODES + kbase + kb * 8;

    // hoisted STAGE pointers
    const unsigned short* ssrc[4];
    char* sdst[4];
    #pragma unroll
    for (int p = 0; p < 4; ++p) {
        int c = p * 256 + t;
        int rr = c >> 4, sl = c & 15;
        int slp = sl ^ (rr & 7);
        ssrc[p] = Sb + (size_t)(r0 + rr) * 16384 + kbase + slp * 8;
        sdst[p] = (char*)&As[0][0][0] + c * 16;
    }

    #define STAGE(BUF_) do {                                                  \
        _Pragma("unroll")                                                     \
        for (int p = 0; p < 4; ++p) {                                         \
            gll16(ssrc[p], sdst[p] + (BUF_) * 16384);                         \
            ssrc[p] += 128;                                                   \
        } } while (0)

    f32x4 acc[4][4] = {};
    const f32x4 z4 = {0.f, 0.f, 0.f, 0.f};

    STAGE(0);
    __syncthreads();

    for (int s = 0; s < 16; ++s) {
        const int b = s & 1;
        if (s + 1 < 16) STAGE(b ^ 1);

        bf16x8 bb[4][4];
        #pragma unroll
        for (int ksl = 0; ksl < 4; ++ksl)
            #pragma unroll
            for (int n = 0; n < 4; ++n)
                bb[ksl][n] = *(const bf16x8*)(vb[n] + s * 128 + ksl * 32);

        const char* abase = (const char*)&As[b][0][0];
        #pragma unroll
        for (int m = 0; m < 4; ++m) {
            f32x4 sacc[4];
            {
                bf16x8 a = *(const bf16x8*)(abase + (m * 16 + fr) * 256 +
                                            ((kb ^ (fr & 7)) * 16));
                #pragma unroll
                for (int n = 0; n < 4; ++n)
                    sacc[n] = MFMA16(a, bb[0][n], z4, 0, 0, 0);
            }
            #pragma unroll
            for (int ksl = 1; ksl < 4; ++ksl) {
                bf16x8 a = *(const bf16x8*)(abase + (m * 16 + fr) * 256 +
                                            (((ksl * 4 + kb) ^ (fr & 7)) * 16));
                #pragma unroll
                for (int n = 0; n < 4; ++n)
                    sacc[n] = MFMA16(a, bb[ksl][n], sacc[n], 0, 0, 0);
            }
            f32x4 fac = *(const f32x4*)&facsT[s][m * 16 + kb * 4];
            #pragma unroll
            for (int n = 0; n < 4; ++n)
                acc[m][n] += fac * sacc[n];
        }
        __syncthreads();
    }
    #undef STAGE

    float* P = (ks == 0) ? P0 : (ks == 1) ? P1 : (ks == 2) ? P2 : P3;
    #pragma unroll
    for (int m = 0; m < 4; ++m)
        #pragma unroll
        for (int e = 0; e < 4; ++e) {
            int row = r0 + m * 16 + kb * 4 + e;
            #pragma unroll
            for (int n = 0; n < 4; ++n)
                P[(size_t)row * DIM + w * 64 + n * 16 + fr] = acc[m][n][e];
        }
}

// ---------------------------------------------------------------------------
// scale: attn[row] = bf2f(Sb[row]) * factor, fp32 in place over the same
// row slot. Register-staged: all reads, barrier, all writes.
// ---------------------------------------------------------------------------
__global__ __launch_bounds__(256) void scale_kernel(
    const unsigned short* __restrict__ Sb, const float* __restrict__ factab,
    float* __restrict__ attn)
{
    const int row = blockIdx.x;
    const int t = threadIdx.x;
    const unsigned short* src = Sb + (size_t)row * 16384;

    int4 v[4];
    float f[4];
    #pragma unroll
    for (int p = 0; p < 4; ++p) {
        int c = p * 256 + t;
        v[p] = *(const int4*)&src[c * 8];
        f[p] = factab[(size_t)row * 64 + (c >> 4)];
    }
    __syncthreads();

    float* dst = attn + (size_t)row * N_NODES;
    #pragma unroll
    for (int p = 0; p < 4; ++p) {
        int c = p * 256 + t;
        float4 o0, o1;
        o0.x = bf2f((unsigned short)(v[p].x & 0xffff)) * f[p];
        o0.y = bf2f((unsigned short)((unsigned)v[p].x >> 16)) * f[p];
        o0.z = bf2f((unsigned short)(v[p].y & 0xffff)) * f[p];
        o0.w = bf2f((unsigned short)((unsigned)v[p].y >> 16)) * f[p];
        o1.x = bf2f((unsigned short)(v[p].z & 0xffff)) * f[p];
        o1.y = bf2f((unsigned short)((unsigned)v[p].z >> 16)) * f[p];
        o1.z = bf2f((unsigned short)(v[p].w & 0xffff)) * f[p];
        o1.w = bf2f((unsigned short)((unsigned)v[p].w >> 16)) * f[p];
        *(float4*)(dst + c * 8)     = o0;
        *(float4*)(dst + c * 8 + 4) = o1;
    }
}

// ---------------------------------------------------------------------------
// SpMM: one 64-lane wave per node, lane holds 4 features (ushort4 loads).
// ---------------------------------------------------------------------------
__global__ __launch_bounds__(256) void spmm_kernel(
    const unsigned short* __restrict__ Hb, const int* __restrict__ erow,
    const int* __restrict__ ecol, const float* __restrict__ ew,
    float* __restrict__ out, int E)
{
    const int node = blockIdx.x * 4 + (threadIdx.x >> 6);
    const int lane = threadIdx.x & 63;

    int lo = 0, hi = E;
    while (lo < hi) { int mid = (lo + hi) >> 1; if (erow[mid] < node) lo = mid + 1; else hi = mid; }
    const int beg = lo;
    hi = E;
    while (lo < hi) { int mid = (lo + hi) >> 1; if (erow[mid] < node + 1) lo = mid + 1; else hi = mid; }
    const int end = lo;

    float4 acc = make_float4(0.f, 0.f, 0.f, 0.f);
    for (int e = beg; e < end; ++e) {
        const int col = ecol[e];
        const float wgt = ew[e];
        ushort4 h = *(const ushort4*)&Hb[(size_t)col * DIM + lane * 4];
        acc.x += wgt * bf2f(h.x);
        acc.y += wgt * bf2f(h.y);
        acc.z += wgt * bf2f(h.z);
        acc.w += wgt * bf2f(h.w);
    }
    *(float4*)&out[(size_t)node * DIM + lane * 4] = acc;
}

// ---------------------------------------------------------------------------
// Y = (0.5*(P0+P1+P2+P3) + 0.5*GNN) @ Wc + bc
// ---------------------------------------------------------------------------
__global__ __launch_bounds__(256) void blend_cls_kernel(
    const float* __restrict__ p0, const float* __restrict__ p1,
    const float* __restrict__ p2, const float* __restrict__ p3,
    const float* __restrict__ gnn,
    const float* __restrict__ Wc, const float* __restrict__ bc,
    float* __restrict__ Y)
{
    const int row = blockIdx.x;
    const int t = threadIdx.x;
    __shared__ float z[DIM];
    __shared__ float part[4][NCLS];

    const size_t i = (size_t)row * DIM + t;
    z[t] = 0.5f * (p0[i] + p1[i] + p2[i] + p3[i] + gnn[i]);
    __syncthreads();

    if (t < 160) {
        const int c = t % NCLS, q = t / NCLS;
        float acc = 0.0f;
        #pragma unroll 4
        for (int d = q * 64; d < q * 64 + 64; ++d)
            acc += z[d] * Wc[d * NCLS + c];
        part[q][c] = acc;
    }
    __syncthreads();
    if (t < NCLS)
        Y[(size_t)row * NCLS + t] =
            part[0][t] + part[1][t] + part[2][t] + part[3][t] + bc[t];
}

// ---------------------------------------------------------------------------
extern "C" void kernel_launch(void* const* d_in, const int* in_sizes, int n_in,
                              void* d_out, int out_size, void* d_ws, size_t ws_size,
                              hipStream_t stream)
{
    const float* X     = (const float*)d_in[0];
    const int*   erow  = (const int*)d_in[1];
    const int*   ecol  = (const int*)d_in[2];
    const float* ew    = (const float*)d_in[3];
    const float* W_emb = (const float*)d_in[4];
    const float* b_emb = (const float*)d_in[5];
    const float* W_q   = (const float*)d_in[6];
    const float* b_q   = (const float*)d_in[7];
    const float* W_k   = (const float*)d_in[8];
    const float* b_k   = (const float*)d_in[9];
    const float* W_v   = (const float*)d_in[10];
    const float* b_v   = (const float*)d_in[11];
    const float* W_g   = (const float*)d_in[12];
    const float* b_g   = (const float*)d_in[13];
    const float* W_c   = (const float*)d_in[14];
    const float* b_c   = (const float*)d_in[15];
    const int E = in_sizes[1];

    float* Y    = (float*)d_out;
    float* Sc   = Y + (size_t)N_NODES * NCLS;      // attn [N,N]; Sb packed in rows
    unsigned short* Sb = (unsigned short*)Sc;      // row r at ushort offset r*16384

    const size_t ND = (size_t)N_NODES * DIM;       // 2M elements (8 MB fp32)
    float* R0 = (float*)d_ws;
    float* R1 = R0 + ND;
    float* R2 = R1 + ND;
    float* R3 = R2 + ND;
    float* R4 = R3 + ND;
    float* R5 = R4 + ND;
    float* R6 = R5 + ND;

    // phase-1 aliases
    unsigned short* Xh = (unsigned short*)R0;      // 8 MB
    unsigned short* Xl = (unsigned short*)R1;      // 8 MB
    unsigned short* Wt = (unsigned short*)R2;      // packed weight transposes
    unsigned short* WembTh = Wt;                   // 256x512
    unsigned short* WembTl = Wt + 256 * 512;
    unsigned short* WqTh = WembTl + 256 * 512;     // 256x256 each
    unsigned short* WqTl = WqTh + 256 * 256;
    unsigned short* WkTh = WqTl + 256 * 256;
    unsigned short* WkTl = WkTh + 256 * 256;
    unsigned short* WvTh = WkTl + 256 * 256;
    unsigned short* WvTl = WvTh + 256 * 256;
    unsigned short* WgTh = WvTl + 256 * 256;
    unsigned short* WgTl = WgTh + 256 * 256;
    unsigned short* Z0h = (unsigned short*)R3;     // 4 MB
    unsigned short* Z0l = Z0h + ND;                // 4 MB
    float* Qf = R4;
    float* Kf = R5;
    float* Vf = R6;
    unsigned short* Hb = (unsigned short*)R0;      // first 4 MB (X dead)
    // phase-2 aliases
    unsigned short* Qh = (unsigned short*)R1;      // Xl dead
    unsigned short* Ql = Qh + ND;
    unsigned short* Kh = (unsigned short*)R2;      // weights dead
    unsigned short* Kl = Kh + ND;
    unsigned short* VT = (unsigned short*)(R0 + ND / 2);  // second 4 MB of R0
    float2* pstat = (float2*)R4;                   // Qf dead after ln_split
    float*  factab = R5;                           // Kf dead after ln_split+qkt
    // ZA partials (each 8 MB)
    float* P0 = R6;   // Vf dead after vtrans
    float* P1 = R3;   // Z0 dead after projections
    float* P2 = R4;   // pstat dead after factor
    float* P3 = R1;   // Qh/Ql dead after qkt
    float* GNN = R2;  // Kh/Kl dead after qkt

    // 1. X -> hi/lo bf16
    split_kernel<<<(N_NODES * F_IN) / 1024, 256, 0, stream>>>(X, Xh, Xl);

    // 2. weight transposes (fp32 [K,N] -> bf16 hi/lo [N,K])
    wtrans_kernel<<<dim3(F_IN / 64, DIM / 64), 256, 0, stream>>>(W_emb, WembTh, WembTl, F_IN, DIM);
    wtrans_kernel<<<dim3(DIM / 64, DIM / 64), 256, 0, stream>>>(W_q, WqTh, WqTl, DIM, DIM);
    wtrans_kernel<<<dim3(DIM / 64, DIM / 64), 256, 0, stream>>>(W_k, WkTh, WkTl, DIM, DIM);
    wtrans_kernel<<<dim3(DIM / 64, DIM / 64), 256, 0, stream>>>(W_v, WvTh, WvTl, DIM, DIM);
    wtrans_kernel<<<dim3(DIM / 64, DIM / 64), 256, 0, stream>>>(W_g, WgTh, WgTl, DIM, DIM);

    // 3. Z0 = X @ W_emb + b (split-bf16 MFMA, output hi/lo)
    mfma_gemm3_kernel<F_IN, 2><<<dim3(2, N_NODES / 128), 256, 0, stream>>>(
        Xh, Xl, WembTh, WembTl, b_emb, Z0h, Z0l);

    // 4. all four projections in one launch
    Proj4Args pa;
    pa.Bh[0] = WqTh; pa.Bl[0] = WqTl; pa.bias[0] = b_q; pa.C[0] = Qf;
    pa.Bh[1] = WkTh; pa.Bl[1] = WkTl; pa.bias[1] = b_k; pa.C[1] = Kf;
    pa.Bh[2] = WvTh; pa.Bl[2] = WvTl; pa.bias[2] = b_v; pa.C[2] = Vf;
    pa.Bh[3] = WgTh; pa.Bl[3] = WgTl; pa.bias[3] = b_g; pa.C[3] = Hb;
    proj4_kernel<<<dim3(2, N_NODES / 128, 4), 256, 0, stream>>>(Z0h, Z0l, pa);

    // 5. LN + hi/lo split
    ln_split_kernel<<<N_NODES, 256, 0, stream>>>(Qf, Qh, Ql);
    ln_split_kernel<<<N_NODES, 256, 0, stream>>>(Kf, Kh, Kl);

    // 6. V -> VT bf16
    vtrans_kernel<<<dim3(N_NODES / 64, DIM / 64), 256, 0, stream>>>(Vf, VT);

    // 7. Sb = bf16 exp(QK^T - m_block) + pstat
    qkt_kernel<<<4096, 256, 0, stream>>>(Qh, Ql, Kh, Kl, Sb, pstat);

    // 8. factor table
    factor_kernel<<<N_NODES / 4, 256, 0, stream>>>(pstat, factab);

    // 9. ZA partials = (factor * Sb) @ V   (reads Sb, must precede scale)
    av_mfma_kernel<<<512, 256, 0, stream>>>(Sb, factab, VT, P0, P1, P2, P3);

    // 10. attn = bf2f(Sb) * factor, fp32 in place
    scale_kernel<<<N_NODES, 256, 0, stream>>>(Sb, factab, Sc);

    // 11. GNN branch (bf16 H)
    spmm_kernel<<<N_NODES / 4, 256, 0, stream>>>(Hb, erow, ecol, ew, GNN, E);

    // 12. blend (partials summed inline) + classifier
    blend_cls_kernel<<<N_NODES, 256, 0, stream>>>(
        P0, P1, P2, P3, GNN, W_c, b_c, Y);
}

// Round 13
// 411.619 us; speedup vs baseline: 1.7902x; 1.0441x over previous
//
#include <hip/hip_runtime.h>
#include <hip/hip_bf16.h>

#define N_NODES 8192
#define F_IN    512
#define DIM     256
#define NCLS    40

typedef __attribute__((ext_vector_type(8))) short bf16x8;
typedef __attribute__((ext_vector_type(4))) float f32x4;

#define MFMA16 __builtin_amdgcn_mfma_f32_16x16x32_bf16

static __device__ __forceinline__ unsigned short f2bf(float x) {
    __hip_bfloat16 h = __float2bfloat16(x);
    return *reinterpret_cast<unsigned short*>(&h);
}
static __device__ __forceinline__ float bf2f(unsigned short u) {
    union { unsigned int u32; float f; } v; v.u32 = ((unsigned int)u) << 16;
    return v.f;
}
static __device__ __forceinline__ void gll16(const void* g, void* l) {
    __builtin_amdgcn_global_load_lds(
        (const __attribute__((address_space(1))) unsigned int*)g,
        (__attribute__((address_space(3))) unsigned int*)l, 16, 0, 0);
}

// ---------------------------------------------------------------------------
// split: fp32 -> (hi, lo) bf16 pair, elementwise. 4 elems/thread.
// ---------------------------------------------------------------------------
__global__ __launch_bounds__(256) void split_kernel(
    const float* __restrict__ X,
    unsigned short* __restrict__ Xh, unsigned short* __restrict__ Xl)
{
    const size_t i = ((size_t)blockIdx.x * 256 + threadIdx.x) * 4;
    float4 v = *(const float4*)&X[i];
    ushort4 h, l;
    h.x = f2bf(v.x); l.x = f2bf(v.x - bf2f(h.x));
    h.y = f2bf(v.y); l.y = f2bf(v.y - bf2f(h.y));
    h.z = f2bf(v.z); l.z = f2bf(v.z - bf2f(h.z));
    h.w = f2bf(v.w); l.w = f2bf(v.w - bf2f(h.w));
    *(ushort4*)&Xh[i] = h;
    *(ushort4*)&Xl[i] = l;
}

// ---------------------------------------------------------------------------
// wtrans: W fp32 [K,N] -> WT hi/lo bf16 [N,K]. 64x64 LDS transpose tiles.
// ---------------------------------------------------------------------------
__global__ __launch_bounds__(256) void wtrans_kernel(
    const float* __restrict__ W,
    unsigned short* __restrict__ WTh, unsigned short* __restrict__ WTl,
    int K, int N)
{
    __shared__ float tile[64][65];
    const int r0 = blockIdx.x * 64;   // K dim
    const int c0 = blockIdx.y * 64;   // N dim
    const int t = threadIdx.x;
    #pragma unroll
    for (int i = 0; i < 4; ++i) {
        int r = i * 16 + (t >> 4);
        int c = (t & 15) * 4;
        float4 v = *(const float4*)&W[(size_t)(r0 + r) * N + c0 + c];
        tile[r][c] = v.x; tile[r][c + 1] = v.y;
        tile[r][c + 2] = v.z; tile[r][c + 3] = v.w;
    }
    __syncthreads();
    #pragma unroll
    for (int i = 0; i < 4; ++i) {
        int c = i * 16 + (t >> 4);    // N-local
        int r = (t & 15) * 4;         // K-local
        ushort4 h, l;
        float x0 = tile[r][c],     x1 = tile[r + 1][c];
        float x2 = tile[r + 2][c], x3 = tile[r + 3][c];
        h.x = f2bf(x0); l.x = f2bf(x0 - bf2f(h.x));
        h.y = f2bf(x1); l.y = f2bf(x1 - bf2f(h.y));
        h.z = f2bf(x2); l.z = f2bf(x2 - bf2f(h.z));
        h.w = f2bf(x3); l.w = f2bf(x3 - bf2f(h.w));
        *(ushort4*)&WTh[(size_t)(c0 + c) * K + r0 + r] = h;
        *(ushort4*)&WTl[(size_t)(c0 + c) * K + r0 + r] = l;
    }
}

// ---------------------------------------------------------------------------
// mfma_gemm3 body: 3-term split-bf16 MFMA, BM=128, BN=128, BK=32, 4 waves.
// OUTMODE: 0 = fp32 C0; 1 = bf16 C0; 2 = hi/lo split into C0,C1.
// ---------------------------------------------------------------------------
template<int KDIM, int OUTMODE>
__device__ __forceinline__ void gemm3_body(
    const unsigned short* __restrict__ Ah_, const unsigned short* __restrict__ Al_,
    const unsigned short* __restrict__ Bh_, const unsigned short* __restrict__ Bl_,
    const float* __restrict__ bias,
    void* __restrict__ C0, void* __restrict__ C1,
    int m0, int n0,
    short (*Ah)[32], short (*Al)[32], short (*Bh)[32], short (*Bl)[32])
{
    const int t = threadIdx.x, lane = t & 63, w = t >> 6;
    const int wm = w >> 1, wn = w & 1;
    const int fr = lane & 15, kb = lane >> 4;

    const unsigned short* asrc[4];
    const unsigned short* bsrc[4];
    char* adst[4];
    char* bdst[4];
    #pragma unroll
    for (int r = 0; r < 4; ++r) {
        int c = r * 256 + t;
        int tens = c >> 9, idx = c & 511;
        int row = idx >> 2, slot = idx & 3;
        asrc[r] = (tens ? Al_ : Ah_) + (size_t)(m0 + row) * KDIM + slot * 8;
        adst[r] = (char*)(tens ? &Al[0][0] : &Ah[0][0]) + idx * 16;
        bsrc[r] = (tens ? Bl_ : Bh_) + (size_t)(n0 + row) * KDIM + slot * 8;
        bdst[r] = (char*)(tens ? &Bl[0][0] : &Bh[0][0]) + idx * 16;
    }

    f32x4 acc[4][4] = {};

    for (int k0 = 0; k0 < KDIM; k0 += 32) {
        #pragma unroll
        for (int r = 0; r < 4; ++r) { gll16(asrc[r], adst[r]); asrc[r] += 32; }
        #pragma unroll
        for (int r = 0; r < 4; ++r) { gll16(bsrc[r], bdst[r]); bsrc[r] += 32; }
        __syncthreads();

        bf16x8 ah[4], al[4], bh[4], bl[4];
        #pragma unroll
        for (int m = 0; m < 4; ++m) {
            int row = wm * 64 + m * 16 + fr;
            ah[m] = *(const bf16x8*)&Ah[row][kb * 8];
            al[m] = *(const bf16x8*)&Al[row][kb * 8];
        }
        #pragma unroll
        for (int n = 0; n < 4; ++n) {
            int col = wn * 64 + n * 16 + fr;
            bh[n] = *(const bf16x8*)&Bh[col][kb * 8];
            bl[n] = *(const bf16x8*)&Bl[col][kb * 8];
        }
        #pragma unroll
        for (int m = 0; m < 4; ++m)
            #pragma unroll
            for (int n = 0; n < 4; ++n) {
                acc[m][n] = MFMA16(ah[m], bh[n], acc[m][n], 0, 0, 0);
                acc[m][n] = MFMA16(ah[m], bl[n], acc[m][n], 0, 0, 0);
                acc[m][n] = MFMA16(al[m], bh[n], acc[m][n], 0, 0, 0);
            }
        __syncthreads();
    }

    #pragma unroll
    for (int m = 0; m < 4; ++m)
        #pragma unroll
        for (int e = 0; e < 4; ++e) {
            const int row = m0 + wm * 64 + m * 16 + kb * 4 + e;
            #pragma unroll
            for (int n = 0; n < 4; ++n) {
                const int col = n0 + wn * 64 + n * 16 + fr;
                float v = acc[m][n][e] + bias[col];
                if (OUTMODE == 0) {
                    ((float*)C0)[(size_t)row * 256 + col] = v;
                } else if (OUTMODE == 1) {
                    ((unsigned short*)C0)[(size_t)row * 256 + col] = f2bf(v);
                } else {
                    unsigned short h = f2bf(v);
                    ((unsigned short*)C0)[(size_t)row * 256 + col] = h;
                    ((unsigned short*)C1)[(size_t)row * 256 + col] =
                        f2bf(v - bf2f(h));
                }
            }
        }
}

template<int KDIM, int OUTMODE>
__global__ __launch_bounds__(256, 2) void mfma_gemm3_kernel(
    const unsigned short* __restrict__ Ah_, const unsigned short* __restrict__ Al_,
    const unsigned short* __restrict__ Bh_, const unsigned short* __restrict__ Bl_,
    const float* __restrict__ bias,
    void* __restrict__ C0, void* __restrict__ C1)
{
    __shared__ short Ah[128][32], Al[128][32], Bh[128][32], Bl[128][32];
    gemm3_body<KDIM, OUTMODE>(Ah_, Al_, Bh_, Bl_, bias, C0, C1,
                              blockIdx.y * 128, blockIdx.x * 128,
                              Ah, Al, Bh, Bl);
}

// ---------------------------------------------------------------------------
// proj4: all four DIM x DIM projections in one launch (z selects weights).
// ---------------------------------------------------------------------------
struct Proj4Args {
    const unsigned short* Bh[4];
    const unsigned short* Bl[4];
    const float* bias[4];
    void* C[4];
};

__global__ __launch_bounds__(256, 2) void proj4_kernel(
    const unsigned short* __restrict__ Ah_, const unsigned short* __restrict__ Al_,
    Proj4Args p)
{
    __shared__ short Ah[128][32], Al[128][32], Bh[128][32], Bl[128][32];
    const int z = blockIdx.z;
    if (z < 3)
        gemm3_body<DIM, 0>(Ah_, Al_, p.Bh[z], p.Bl[z], p.bias[z], p.C[z],
                           nullptr, blockIdx.y * 128, blockIdx.x * 128,
                           Ah, Al, Bh, Bl);
    else
        gemm3_body<DIM, 1>(Ah_, Al_, p.Bh[z], p.Bl[z], p.bias[z], p.C[z],
                           nullptr, blockIdx.y * 128, blockIdx.x * 128,
                           Ah, Al, Bh, Bl);
}

// ---------------------------------------------------------------------------
// LayerNorm + hi/lo bf16 split.
// ---------------------------------------------------------------------------
__global__ __launch_bounds__(256) void ln_split_kernel(
    const float* __restrict__ X,
    unsigned short* __restrict__ Hi, unsigned short* __restrict__ Lo)
{
    const int row = blockIdx.x;
    const int t = threadIdx.x;
    float x = X[(size_t)row * DIM + t];

    float s1 = x, s2 = x * x;
    #pragma unroll
    for (int o = 32; o; o >>= 1) {
        s1 += __shfl_xor(s1, o);
        s2 += __shfl_xor(s2, o);
    }
    __shared__ float r1[4], r2[4];
    const int wid = t >> 6;
    if ((t & 63) == 0) { r1[wid] = s1; r2[wid] = s2; }
    __syncthreads();
    const float sum = r1[0] + r1[1] + r1[2] + r1[3];
    const float ssq = r2[0] + r2[1] + r2[2] + r2[3];
    const float mean = sum * (1.0f / DIM);
    const float var  = ssq * (1.0f / DIM) - mean * mean;
    const float y = (x - mean) * rsqrtf(var + 1e-5f);

    const unsigned short h = f2bf(y);
    Hi[(size_t)row * DIM + t] = h;
    Lo[(size_t)row * DIM + t] = f2bf(y - bf2f(h));
}

// ---------------------------------------------------------------------------
// V [8192,256] fp32 -> VT [256,8192] bf16.
// ---------------------------------------------------------------------------
__global__ __launch_bounds__(256) void vtrans_kernel(
    const float* __restrict__ V, unsigned short* __restrict__ VT)
{
    __shared__ float tile[64][65];
    const int r0 = blockIdx.x * 64;
    const int c0 = blockIdx.y * 64;
    const int t = threadIdx.x;
    #pragma unroll
    for (int i = 0; i < 4; ++i) {
        int r = i * 16 + (t >> 4);
        int c = (t & 15) * 4;
        float4 v = *(const float4*)&V[(size_t)(r0 + r) * DIM + c0 + c];
        tile[r][c] = v.x; tile[r][c + 1] = v.y;
        tile[r][c + 2] = v.z; tile[r][c + 3] = v.w;
    }
    __syncthreads();
    #pragma unroll
    for (int i = 0; i < 4; ++i) {
        int c = i * 16 + (t >> 4);
        int r = (t & 15) * 4;
        ushort4 o;
        o.x = f2bf(tile[r][c]);     o.y = f2bf(tile[r + 1][c]);
        o.z = f2bf(tile[r + 2][c]); o.w = f2bf(tile[r + 3][c]);
        *(ushort4*)&VT[(size_t)(c0 + c) * N_NODES + r0 + r] = o;
    }
}

// ---------------------------------------------------------------------------
// scores = Q @ K^T (split-bf16). Sb = bf16 exp(s-m_blk) packed into the
// SECOND HALF of each k-slice's fp32 target range within the attn row slot:
// row byte offset = ks*8192 + 4096 + lb*256  (ks = nb>>4, lb = nb&15).
// This makes av's in-place fp32 expansion race-free across k-split blocks.
// ---------------------------------------------------------------------------
__global__ __launch_bounds__(256, 4) void qkt_kernel(
    const unsigned short* __restrict__ Qh, const unsigned short* __restrict__ Ql,
    const unsigned short* __restrict__ Kh, const unsigned short* __restrict__ Kl,
    unsigned short* __restrict__ Sb, float2* __restrict__ pstat)
{
    __shared__ short stage[4][128][32];   // Ah/Al/Bh/Bl; reused as bf16 out-tile
    __shared__ float2 ps[2][128];
    __shared__ float gmr[128];

    // 2D-chunked XCD swizzle: xcd owns mb in [x*8,x*8+8); nb grouped by 8.
    const int bid = blockIdx.x;
    const int x   = bid & 7;
    const int i   = bid >> 3;          // 0..511
    const int nbs = i >> 6;            // 0..7
    const int j   = i & 63;
    const int mb  = x * 8 + (j & 7);
    const int nb  = nbs * 8 + (j >> 3);
    const int m0 = mb * 128, n0 = nb * 128;
    const int sbbase = (nb >> 4) * 4096 + 2048 + (nb & 15) * 128;  // ushorts

    const int t = threadIdx.x, lane = t & 63, w = t >> 6;
    const int wm = w >> 1, wn = w & 1;
    const int fr = lane & 15, kb = lane >> 4;

    // hoisted staging pointers (2 chunks x 4 tensors per thread)
    const unsigned short* qsrc[2][2];
    const unsigned short* ksrc[2][2];
    char* qdst[2][2];
    char* kdst[2][2];
    #pragma unroll
    for (int r = 0; r < 2; ++r) {
        int c = r * 256 + t;
        int row = c >> 2, slot = c & 3;
        size_t ga = (size_t)(m0 + row) * DIM + slot * 8;
        size_t gb = (size_t)(n0 + row) * DIM + slot * 8;
        qsrc[r][0] = Qh + ga; qsrc[r][1] = Ql + ga;
        ksrc[r][0] = Kh + gb; ksrc[r][1] = Kl + gb;
        qdst[r][0] = (char*)&stage[0][0][0] + c * 16;
        qdst[r][1] = (char*)&stage[1][0][0] + c * 16;
        kdst[r][0] = (char*)&stage[2][0][0] + c * 16;
        kdst[r][1] = (char*)&stage[3][0][0] + c * 16;
    }

    f32x4 acc[4][4] = {};

    for (int k0 = 0; k0 < DIM; k0 += 32) {
        #pragma unroll
        for (int r = 0; r < 2; ++r) {
            gll16(qsrc[r][0], qdst[r][0]); qsrc[r][0] += 32;
            gll16(qsrc[r][1], qdst[r][1]); qsrc[r][1] += 32;
            gll16(ksrc[r][0], kdst[r][0]); ksrc[r][0] += 32;
            gll16(ksrc[r][1], kdst[r][1]); ksrc[r][1] += 32;
        }
        __syncthreads();

        bf16x8 ah[4], al[4], bh[4], bl[4];
        #pragma unroll
        for (int m = 0; m < 4; ++m) {
            int row = wm * 64 + m * 16 + fr;
            ah[m] = *(const bf16x8*)&stage[0][row][kb * 8];
            al[m] = *(const bf16x8*)&stage[1][row][kb * 8];
        }
        #pragma unroll
        for (int n = 0; n < 4; ++n) {
            int col = wn * 64 + n * 16 + fr;
            bh[n] = *(const bf16x8*)&stage[2][col][kb * 8];
            bl[n] = *(const bf16x8*)&stage[3][col][kb * 8];
        }
        #pragma unroll
        for (int m = 0; m < 4; ++m)
            #pragma unroll
            for (int n = 0; n < 4; ++n) {
                acc[m][n] = MFMA16(ah[m], bh[n], acc[m][n], 0, 0, 0);
                acc[m][n] = MFMA16(ah[m], bl[n], acc[m][n], 0, 0, 0);
                acc[m][n] = MFMA16(al[m], bh[n], acc[m][n], 0, 0, 0);
            }
        __syncthreads();
    }

    // ---- phase A: per-row max over this block's 128 cols
    #pragma unroll
    for (int m = 0; m < 4; ++m)
        #pragma unroll
        for (int e = 0; e < 4; ++e) {
            float mx = acc[m][0][e];
            #pragma unroll
            for (int n = 1; n < 4; ++n) mx = fmaxf(mx, acc[m][n][e]);
            #pragma unroll
            for (int o = 1; o < 16; o <<= 1) mx = fmaxf(mx, __shfl_xor(mx, o));
            if (fr == 0) ps[wn][wm * 64 + m * 16 + kb * 4 + e].x = mx;
        }
    __syncthreads();
    if (t < 128) gmr[t] = fmaxf(ps[0][t].x, ps[1][t].x);
    __syncthreads();

    // ---- phase B: single exp pass -> bf16 tile (XOR-swizzled) + sumexp
    unsigned short* tile = (unsigned short*)&stage[0][0][0];   // [128][128]
    #pragma unroll
    for (int m = 0; m < 4; ++m)
        #pragma unroll
        for (int e = 0; e < 4; ++e) {
            const int rl = wm * 64 + m * 16 + kb * 4 + e;
            const float g = gmr[rl];
            const int key = kb << 1;           // (rl>>2)&3 == kb
            float se = 0.f;
            #pragma unroll
            for (int n = 0; n < 4; ++n) {
                float ev = __expf(acc[m][n][e] - g);
                se += ev;
                const int col = wn * 64 + n * 16 + fr;
                tile[rl * 128 + (((col >> 3) ^ key) << 3) + (col & 7)] =
                    f2bf(ev);
            }
            #pragma unroll
            for (int o = 1; o < 16; o <<= 1) se += __shfl_xor(se, o);
            if (fr == 0) ps[wn][rl].y = se;
        }
    __syncthreads();
    if (t < 128)
        pstat[(size_t)(m0 + t) * 64 + nb] =
            make_float2(gmr[t], ps[0][t].y + ps[1][t].y);

    // ---- coalesced bf16 store into the packed slot
    #pragma unroll
    for (int p = 0; p < 8; ++p) {
        int c = p * 256 + t;            // 16B chunk id (2048 total)
        int r = c >> 4, sl = c & 15;
        int slx = sl ^ (((r >> 2) & 3) << 1);
        *(int4*)&Sb[(size_t)(m0 + r) * 16384 + sbbase + sl * 8] =
            *(const int4*)((const char*)tile + (r * 16 + slx) * 16);
    }
}

// ---------------------------------------------------------------------------
// factab[row][cb] = exp(m_cb - m_row) / Z_row. 4 rows/block, 64 lanes/row.
// ---------------------------------------------------------------------------
__global__ __launch_bounds__(256) void factor_kernel(
    const float2* __restrict__ pstat, float* __restrict__ factab)
{
    const int row = blockIdx.x * 4 + (threadIdx.x >> 6);
    const int lane = threadIdx.x & 63;
    float2 v = pstat[(size_t)row * 64 + lane];
    float gm = v.x;
    #pragma unroll
    for (int o = 1; o < 64; o <<= 1) gm = fmaxf(gm, __shfl_xor(gm, o));
    float s = v.y * __expf(v.x - gm);
    #pragma unroll
    for (int o = 1; o < 64; o <<= 1) s += __shfl_xor(s, o);
    factab[(size_t)row * 64 + lane] = __expf(v.x - gm) / s;
}

// ---------------------------------------------------------------------------
// av_mfma: ZA partials = (factor * Sb) @ VT^T via per-step scaled MFMA,
// PLUS in-place fp32 attn expansion from the staged LDS tile (scale fused).
// Safety: Sb for slice ks lives at row bytes [ks*8192+4096, +4096); step-s
// fp32 writes [ks*8192+s*512, +512) never overlap the step-(s+1) prefetch.
// ---------------------------------------------------------------------------
__global__ __launch_bounds__(256, 2) void av_mfma_kernel(
    const unsigned short* __restrict__ Sb, const float* __restrict__ factab,
    const unsigned short* __restrict__ VT, float* __restrict__ attn,
    float* __restrict__ P0, float* __restrict__ P1,
    float* __restrict__ P2, float* __restrict__ P3)
{
    __shared__ unsigned short As[2][64][128];   // linear dest, swizzled source
    __shared__ float facsT[16][64];             // [local cb][row]

    const int bid = blockIdx.x;
    const int x = bid & 7, i = bid >> 3;        // i in [0,64)
    const int ks = i >> 4;                      // slow per XCD
    const int rb = (i & 15) * 8 + x;            // 0..127
    const int r0 = rb * 64, kbase = ks * 2048, cb0 = ks * 16;
    const int t = threadIdx.x, lane = t & 63, w = t >> 6;
    const int fr = lane & 15, kb = lane >> 4;

    for (int ii = t; ii < 1024; ii += 256)
        facsT[ii >> 6][ii & 63] =
            factab[(size_t)(r0 + (ii & 63)) * 64 + cb0 + (ii >> 6)];

    const unsigned short* vb[4];
    #pragma unroll
    for (int n = 0; n < 4; ++n)
        vb[n] = VT + (size_t)(w * 64 + n * 16 + fr) * N_NODES + kbase + kb * 8;

    // hoisted STAGE pointers (packed Sb base: ks*4096 + 2048)
    const unsigned short* ssrc[4];
    char* sdst[4];
    #pragma unroll
    for (int p = 0; p < 4; ++p) {
        int c = p * 256 + t;
        int rr = c >> 4, sl = c & 15;
        int slp = sl ^ (rr & 7);
        ssrc[p] = Sb + (size_t)(r0 + rr) * 16384 + ks * 4096 + 2048 + slp * 8;
        sdst[p] = (char*)&As[0][0][0] + c * 16;
    }

    #define STAGE(BUF_) do {                                                  \
        _Pragma("unroll")                                                     \
        for (int p = 0; p < 4; ++p) {                                         \
            gll16(ssrc[p], sdst[p] + (BUF_) * 16384);                         \
            ssrc[p] += 128;                                                   \
        } } while (0)

    f32x4 acc[4][4] = {};
    const f32x4 z4 = {0.f, 0.f, 0.f, 0.f};

    STAGE(0);
    __syncthreads();

    for (int s = 0; s < 16; ++s) {
        const int b = s & 1;
        if (s + 1 < 16) STAGE(b ^ 1);

        bf16x8 bb[4][4];
        #pragma unroll
        for (int ksl = 0; ksl < 4; ++ksl)
            #pragma unroll
            for (int n = 0; n < 4; ++n)
                bb[ksl][n] = *(const bf16x8*)(vb[n] + s * 128 + ksl * 32);

        const char* abase = (const char*)&As[b][0][0];
        #pragma unroll
        for (int m = 0; m < 4; ++m) {
            f32x4 sacc[4];
            {
                bf16x8 a = *(const bf16x8*)(abase + (m * 16 + fr) * 256 +
                                            ((kb ^ (fr & 7)) * 16));
                #pragma unroll
                for (int n = 0; n < 4; ++n)
                    sacc[n] = MFMA16(a, bb[0][n], z4, 0, 0, 0);
            }
            #pragma unroll
            for (int ksl = 1; ksl < 4; ++ksl) {
                bf16x8 a = *(const bf16x8*)(abase + (m * 16 + fr) * 256 +
                                            (((ksl * 4 + kb) ^ (fr & 7)) * 16));
                #pragma unroll
                for (int n = 0; n < 4; ++n)
                    sacc[n] = MFMA16(a, bb[ksl][n], sacc[n], 0, 0, 0);
            }
            f32x4 fac = *(const f32x4*)&facsT[s][m * 16 + kb * 4];
            #pragma unroll
            for (int n = 0; n < 4; ++n)
                acc[m][n] += fac * sacc[n];
        }

        // ---- fused attn epilogue: expand this step's LDS tile to fp32
        #pragma unroll
        for (int p = 0; p < 4; ++p) {
            int ci = p * 256 + t;
            int rr = ci >> 4, g = ci & 15;
            const float fac = facsT[s][rr];
            int4 v = *(const int4*)(abase + (rr * 16 + (g ^ (rr & 7))) * 16);
            float* dst = attn + (size_t)(r0 + rr) * N_NODES +
                         kbase + s * 128 + g * 8;
            float4 o0, o1;
            o0.x = bf2f((unsigned short)(v.x & 0xffff)) * fac;
            o0.y = bf2f((unsigned short)((unsigned)v.x >> 16)) * fac;
            o0.z = bf2f((unsigned short)(v.y & 0xffff)) * fac;
            o0.w = bf2f((unsigned short)((unsigned)v.y >> 16)) * fac;
            o1.x = bf2f((unsigned short)(v.z & 0xffff)) * fac;
            o1.y = bf2f((unsigned short)((unsigned)v.z >> 16)) * fac;
            o1.z = bf2f((unsigned short)(v.w & 0xffff)) * fac;
            o1.w = bf2f((unsigned short)((unsigned)v.w >> 16)) * fac;
            *(float4*)dst       = o0;
            *(float4*)(dst + 4) = o1;
        }
        __syncthreads();
    }
    #undef STAGE

    float* P = (ks == 0) ? P0 : (ks == 1) ? P1 : (ks == 2) ? P2 : P3;
    #pragma unroll
    for (int m = 0; m < 4; ++m)
        #pragma unroll
        for (int e = 0; e < 4; ++e) {
            int row = r0 + m * 16 + kb * 4 + e;
            #pragma unroll
            for (int n = 0; n < 4; ++n)
                P[(size_t)row * DIM + w * 64 + n * 16 + fr] = acc[m][n][e];
        }
}

// ---------------------------------------------------------------------------
// SpMM: one 64-lane wave per node, lane holds 4 features (ushort4 loads).
// ---------------------------------------------------------------------------
__global__ __launch_bounds__(256) void spmm_kernel(
    const unsigned short* __restrict__ Hb, const int* __restrict__ erow,
    const int* __restrict__ ecol, const float* __restrict__ ew,
    float* __restrict__ out, int E)
{
    const int node = blockIdx.x * 4 + (threadIdx.x >> 6);
    const int lane = threadIdx.x & 63;

    int lo = 0, hi = E;
    while (lo < hi) { int mid = (lo + hi) >> 1; if (erow[mid] < node) lo = mid + 1; else hi = mid; }
    const int beg = lo;
    hi = E;
    while (lo < hi) { int mid = (lo + hi) >> 1; if (erow[mid] < node + 1) lo = mid + 1; else hi = mid; }
    const int end = lo;

    float4 acc = make_float4(0.f, 0.f, 0.f, 0.f);
    for (int e = beg; e < end; ++e) {
        const int col = ecol[e];
        const float wgt = ew[e];
        ushort4 h = *(const ushort4*)&Hb[(size_t)col * DIM + lane * 4];
        acc.x += wgt * bf2f(h.x);
        acc.y += wgt * bf2f(h.y);
        acc.z += wgt * bf2f(h.z);
        acc.w += wgt * bf2f(h.w);
    }
    *(float4*)&out[(size_t)node * DIM + lane * 4] = acc;
}

// ---------------------------------------------------------------------------
// Y = (0.5*(P0+P1+P2+P3) + 0.5*GNN) @ Wc + bc
// ---------------------------------------------------------------------------
__global__ __launch_bounds__(256) void blend_cls_kernel(
    const float* __restrict__ p0, const float* __restrict__ p1,
    const float* __restrict__ p2, const float* __restrict__ p3,
    const float* __restrict__ gnn,
    const float* __restrict__ Wc, const float* __restrict__ bc,
    float* __restrict__ Y)
{
    const int row = blockIdx.x;
    const int t = threadIdx.x;
    __shared__ float z[DIM];
    __shared__ float part[4][NCLS];

    const size_t i = (size_t)row * DIM + t;
    z[t] = 0.5f * (p0[i] + p1[i] + p2[i] + p3[i] + gnn[i]);
    __syncthreads();

    if (t < 160) {
        const int c = t % NCLS, q = t / NCLS;
        float acc = 0.0f;
        #pragma unroll 4
        for (int d = q * 64; d < q * 64 + 64; ++d)
            acc += z[d] * Wc[d * NCLS + c];
        part[q][c] = acc;
    }
    __syncthreads();
    if (t < NCLS)
        Y[(size_t)row * NCLS + t] =
            part[0][t] + part[1][t] + part[2][t] + part[3][t] + bc[t];
}

// ---------------------------------------------------------------------------
extern "C" void kernel_launch(void* const* d_in, const int* in_sizes, int n_in,
                              void* d_out, int out_size, void* d_ws, size_t ws_size,
                              hipStream_t stream)
{
    const float* X     = (const float*)d_in[0];
    const int*   erow  = (const int*)d_in[1];
    const int*   ecol  = (const int*)d_in[2];
    const float* ew    = (const float*)d_in[3];
    const float* W_emb = (const float*)d_in[4];
    const float* b_emb = (const float*)d_in[5];
    const float* W_q   = (const float*)d_in[6];
    const float* b_q   = (const float*)d_in[7];
    const float* W_k   = (const float*)d_in[8];
    const float* b_k   = (const float*)d_in[9];
    const float* W_v   = (const float*)d_in[10];
    const float* b_v   = (const float*)d_in[11];
    const float* W_g   = (const float*)d_in[12];
    const float* b_g   = (const float*)d_in[13];
    const float* W_c   = (const float*)d_in[14];
    const float* b_c   = (const float*)d_in[15];
    const int E = in_sizes[1];

    float* Y    = (float*)d_out;
    float* Sc   = Y + (size_t)N_NODES * NCLS;      // attn [N,N]; Sb packed inside
    unsigned short* Sb = (unsigned short*)Sc;      // row r at ushort offset r*16384

    const size_t ND = (size_t)N_NODES * DIM;       // 2M elements (8 MB fp32)
    float* R0 = (float*)d_ws;
    float* R1 = R0 + ND;
    float* R2 = R1 + ND;
    float* R3 = R2 + ND;
    float* R4 = R3 + ND;
    float* R5 = R4 + ND;
    float* R6 = R5 + ND;

    // phase-1 aliases
    unsigned short* Xh = (unsigned short*)R0;      // 8 MB
    unsigned short* Xl = (unsigned short*)R1;      // 8 MB
    unsigned short* Wt = (unsigned short*)R2;      // packed weight transposes
    unsigned short* WembTh = Wt;                   // 256x512
    unsigned short* WembTl = Wt + 256 * 512;
    unsigned short* WqTh = WembTl + 256 * 512;     // 256x256 each
    unsigned short* WqTl = WqTh + 256 * 256;
    unsigned short* WkTh = WqTl + 256 * 256;
    unsigned short* WkTl = WkTh + 256 * 256;
    unsigned short* WvTh = WkTl + 256 * 256;
    unsigned short* WvTl = WvTh + 256 * 256;
    unsigned short* WgTh = WvTl + 256 * 256;
    unsigned short* WgTl = WgTh + 256 * 256;
    unsigned short* Z0h = (unsigned short*)R3;     // 4 MB
    unsigned short* Z0l = Z0h + ND;                // 4 MB
    float* Qf = R4;
    float* Kf = R5;
    float* Vf = R6;
    unsigned short* Hb = (unsigned short*)R0;      // first 4 MB (X dead)
    // phase-2 aliases
    unsigned short* Qh = (unsigned short*)R1;      // Xl dead
    unsigned short* Ql = Qh + ND;
    unsigned short* Kh = (unsigned short*)R2;      // weights dead
    unsigned short* Kl = Kh + ND;
    unsigned short* VT = (unsigned short*)(R0 + ND / 2);  // second 4 MB of R0
    float2* pstat = (float2*)R4;                   // Qf dead after ln_split
    float*  factab = R5;                           // Kf dead after ln_split+qkt
    // ZA partials (each 8 MB)
    float* P0 = R6;   // Vf dead after vtrans
    float* P1 = R3;   // Z0 dead after projections
    float* P2 = R4;   // pstat dead after factor
    float* P3 = R1;   // Qh/Ql dead after qkt
    float* GNN = R2;  // Kh/Kl dead after qkt

    // 1. X -> hi/lo bf16
    split_kernel<<<(N_NODES * F_IN) / 1024, 256, 0, stream>>>(X, Xh, Xl);

    // 2. weight transposes (fp32 [K,N] -> bf16 hi/lo [N,K])
    wtrans_kernel<<<dim3(F_IN / 64, DIM / 64), 256, 0, stream>>>(W_emb, WembTh, WembTl, F_IN, DIM);
    wtrans_kernel<<<dim3(DIM / 64, DIM / 64), 256, 0, stream>>>(W_q, WqTh, WqTl, DIM, DIM);
    wtrans_kernel<<<dim3(DIM / 64, DIM / 64), 256, 0, stream>>>(W_k, WkTh, WkTl, DIM, DIM);
    wtrans_kernel<<<dim3(DIM / 64, DIM / 64), 256, 0, stream>>>(W_v, WvTh, WvTl, DIM, DIM);
    wtrans_kernel<<<dim3(DIM / 64, DIM / 64), 256, 0, stream>>>(W_g, WgTh, WgTl, DIM, DIM);

    // 3. Z0 = X @ W_emb + b (split-bf16 MFMA, output hi/lo)
    mfma_gemm3_kernel<F_IN, 2><<<dim3(2, N_NODES / 128), 256, 0, stream>>>(
        Xh, Xl, WembTh, WembTl, b_emb, Z0h, Z0l);

    // 4. all four projections in one launch
    Proj4Args pa;
    pa.Bh[0] = WqTh; pa.Bl[0] = WqTl; pa.bias[0] = b_q; pa.C[0] = Qf;
    pa.Bh[1] = WkTh; pa.Bl[1] = WkTl; pa.bias[1] = b_k; pa.C[1] = Kf;
    pa.Bh[2] = WvTh; pa.Bl[2] = WvTl; pa.bias[2] = b_v; pa.C[2] = Vf;
    pa.Bh[3] = WgTh; pa.Bl[3] = WgTl; pa.bias[3] = b_g; pa.C[3] = Hb;
    proj4_kernel<<<dim3(2, N_NODES / 128, 4), 256, 0, stream>>>(Z0h, Z0l, pa);

    // 5. LN + hi/lo split
    ln_split_kernel<<<N_NODES, 256, 0, stream>>>(Qf, Qh, Ql);
    ln_split_kernel<<<N_NODES, 256, 0, stream>>>(Kf, Kh, Kl);

    // 6. V -> VT bf16
    vtrans_kernel<<<dim3(N_NODES / 64, DIM / 64), 256, 0, stream>>>(Vf, VT);

    // 7. Sb = bf16 exp(QK^T - m_block) (packed) + pstat
    qkt_kernel<<<4096, 256, 0, stream>>>(Qh, Ql, Kh, Kl, Sb, pstat);

    // 8. factor table
    factor_kernel<<<N_NODES / 4, 256, 0, stream>>>(pstat, factab);

    // 9. ZA partials + fused in-place attn fp32 expansion
    av_mfma_kernel<<<512, 256, 0, stream>>>(
        Sb, factab, VT, Sc, P0, P1, P2, P3);

    // 10. GNN branch (bf16 H)
    spmm_kernel<<<N_NODES / 4, 256, 0, stream>>>(Hb, erow, ecol, ew, GNN, E);

    // 11. blend (partials summed inline) + classifier
    blend_cls_kernel<<<N_NODES, 256, 0, stream>>>(
        P0, P1, P2, P3, GNN, W_c, b_c, Y);
}

// Round 14
// 402.568 us; speedup vs baseline: 1.8304x; 1.0225x over previous
//
#include <hip/hip_runtime.h>
#include <hip/hip_bf16.h>

#define N_NODES 8192
#define F_IN    512
#define DIM     256
#define NCLS    40

typedef __attribute__((ext_vector_type(8))) short bf16x8;
typedef __attribute__((ext_vector_type(4))) float f32x4;

#define MFMA16 __builtin_amdgcn_mfma_f32_16x16x32_bf16

static __device__ __forceinline__ unsigned short f2bf(float x) {
    __hip_bfloat16 h = __float2bfloat16(x);
    return *reinterpret_cast<unsigned short*>(&h);
}
static __device__ __forceinline__ float bf2f(unsigned short u) {
    union { unsigned int u32; float f; } v; v.u32 = ((unsigned int)u) << 16;
    return v.f;
}
static __device__ __forceinline__ void gll16(const void* g, void* l) {
    __builtin_amdgcn_global_load_lds(
        (const __attribute__((address_space(1))) unsigned int*)g,
        (__attribute__((address_space(3))) unsigned int*)l, 16, 0, 0);
}

// ---------------------------------------------------------------------------
// split: fp32 -> (hi, lo) bf16 pair, elementwise. 4 elems/thread.
// ---------------------------------------------------------------------------
__global__ __launch_bounds__(256) void split_kernel(
    const float* __restrict__ X,
    unsigned short* __restrict__ Xh, unsigned short* __restrict__ Xl)
{
    const size_t i = ((size_t)blockIdx.x * 256 + threadIdx.x) * 4;
    float4 v = *(const float4*)&X[i];
    ushort4 h, l;
    h.x = f2bf(v.x); l.x = f2bf(v.x - bf2f(h.x));
    h.y = f2bf(v.y); l.y = f2bf(v.y - bf2f(h.y));
    h.z = f2bf(v.z); l.z = f2bf(v.z - bf2f(h.z));
    h.w = f2bf(v.w); l.w = f2bf(v.w - bf2f(h.w));
    *(ushort4*)&Xh[i] = h;
    *(ushort4*)&Xl[i] = l;
}

// ---------------------------------------------------------------------------
// wtrans body: W fp32 [K,N] -> WT hi/lo bf16 [N,K]. 64x64 LDS transpose.
// ---------------------------------------------------------------------------
static __device__ __forceinline__ void wtrans_body(
    const float* __restrict__ W,
    unsigned short* __restrict__ WTh, unsigned short* __restrict__ WTl,
    int K, int N, int r0, int c0, float (*tile)[65])
{
    const int t = threadIdx.x;
    #pragma unroll
    for (int i = 0; i < 4; ++i) {
        int r = i * 16 + (t >> 4);
        int c = (t & 15) * 4;
        float4 v = *(const float4*)&W[(size_t)(r0 + r) * N + c0 + c];
        tile[r][c] = v.x; tile[r][c + 1] = v.y;
        tile[r][c + 2] = v.z; tile[r][c + 3] = v.w;
    }
    __syncthreads();
    #pragma unroll
    for (int i = 0; i < 4; ++i) {
        int c = i * 16 + (t >> 4);    // N-local
        int r = (t & 15) * 4;         // K-local
        ushort4 h, l;
        float x0 = tile[r][c],     x1 = tile[r + 1][c];
        float x2 = tile[r + 2][c], x3 = tile[r + 3][c];
        h.x = f2bf(x0); l.x = f2bf(x0 - bf2f(h.x));
        h.y = f2bf(x1); l.y = f2bf(x1 - bf2f(h.y));
        h.z = f2bf(x2); l.z = f2bf(x2 - bf2f(h.z));
        h.w = f2bf(x3); l.w = f2bf(x3 - bf2f(h.w));
        *(ushort4*)&WTh[(size_t)(c0 + c) * K + r0 + r] = h;
        *(ushort4*)&WTl[(size_t)(c0 + c) * K + r0 + r] = l;
    }
}

__global__ __launch_bounds__(256) void wtrans_kernel(
    const float* __restrict__ W,
    unsigned short* __restrict__ WTh, unsigned short* __restrict__ WTl,
    int K, int N)
{
    __shared__ float tile[64][65];
    wtrans_body(W, WTh, WTl, K, N, blockIdx.x * 64, blockIdx.y * 64, tile);
}

struct Wt4Args {
    const float* W[4];
    unsigned short* Th[4];
    unsigned short* Tl[4];
};

__global__ __launch_bounds__(256) void wtrans4_kernel(Wt4Args a)
{
    __shared__ float tile[64][65];
    const int z = blockIdx.z;
    wtrans_body(a.W[z], a.Th[z], a.Tl[z], DIM, DIM,
                blockIdx.x * 64, blockIdx.y * 64, tile);
}

// ---------------------------------------------------------------------------
// gemm3 body: 3-term split-bf16 MFMA, BM x 128, BK=32, 4 waves.
// BM in {64,128}. OUTMODE: 0 fp32; 1 bf16; 2 hi/lo split.
// ---------------------------------------------------------------------------
template<int KDIM, int OUTMODE, int BM>
__device__ __forceinline__ void gemm3_body(
    const unsigned short* __restrict__ Ah_, const unsigned short* __restrict__ Al_,
    const unsigned short* __restrict__ Bh_, const unsigned short* __restrict__ Bl_,
    const float* __restrict__ bias,
    void* __restrict__ C0, void* __restrict__ C1,
    int m0, int n0,
    short (*Ah)[32], short (*Al)[32], short (*Bh)[32], short (*Bl)[32])
{
    constexpr int MFRAG = BM / 32;        // m-fragments per wave-row
    constexpr int ACH   = BM / 32;        // A chunks per thread (BM*8/256)

    const int t = threadIdx.x, lane = t & 63, w = t >> 6;
    const int wm = w >> 1, wn = w & 1;
    const int fr = lane & 15, kb = lane >> 4;

    const unsigned short* asrc[ACH];
    const unsigned short* bsrc[4];
    char* adst[ACH];
    char* bdst[4];
    #pragma unroll
    for (int r = 0; r < ACH; ++r) {
        int c = r * 256 + t;
        int tens = c / (BM * 4), idx = c & (BM * 4 - 1);
        int row = idx >> 2, slot = idx & 3;
        asrc[r] = (tens ? Al_ : Ah_) + (size_t)(m0 + row) * KDIM + slot * 8;
        adst[r] = (char*)(tens ? &Al[0][0] : &Ah[0][0]) + idx * 16;
    }
    #pragma unroll
    for (int r = 0; r < 4; ++r) {
        int c = r * 256 + t;
        int tens = c >> 9, idx = c & 511;
        int row = idx >> 2, slot = idx & 3;
        bsrc[r] = (tens ? Bl_ : Bh_) + (size_t)(n0 + row) * KDIM + slot * 8;
        bdst[r] = (char*)(tens ? &Bl[0][0] : &Bh[0][0]) + idx * 16;
    }

    f32x4 acc[MFRAG][4] = {};

    for (int k0 = 0; k0 < KDIM; k0 += 32) {
        #pragma unroll
        for (int r = 0; r < ACH; ++r) { gll16(asrc[r], adst[r]); asrc[r] += 32; }
        #pragma unroll
        for (int r = 0; r < 4; ++r) { gll16(bsrc[r], bdst[r]); bsrc[r] += 32; }
        __syncthreads();

        bf16x8 ah[MFRAG], al[MFRAG], bh[4], bl[4];
        #pragma unroll
        for (int m = 0; m < MFRAG; ++m) {
            int row = wm * (BM / 2) + m * 16 + fr;
            ah[m] = *(const bf16x8*)&Ah[row][kb * 8];
            al[m] = *(const bf16x8*)&Al[row][kb * 8];
        }
        #pragma unroll
        for (int n = 0; n < 4; ++n) {
            int col = wn * 64 + n * 16 + fr;
            bh[n] = *(const bf16x8*)&Bh[col][kb * 8];
            bl[n] = *(const bf16x8*)&Bl[col][kb * 8];
        }
        #pragma unroll
        for (int m = 0; m < MFRAG; ++m)
            #pragma unroll
            for (int n = 0; n < 4; ++n) {
                acc[m][n] = MFMA16(ah[m], bh[n], acc[m][n], 0, 0, 0);
                acc[m][n] = MFMA16(ah[m], bl[n], acc[m][n], 0, 0, 0);
                acc[m][n] = MFMA16(al[m], bh[n], acc[m][n], 0, 0, 0);
            }
        __syncthreads();
    }

    #pragma unroll
    for (int m = 0; m < MFRAG; ++m)
        #pragma unroll
        for (int e = 0; e < 4; ++e) {
            const int row = m0 + wm * (BM / 2) + m * 16 + kb * 4 + e;
            #pragma unroll
            for (int n = 0; n < 4; ++n) {
                const int col = n0 + wn * 64 + n * 16 + fr;
                float v = acc[m][n][e] + bias[col];
                if (OUTMODE == 0) {
                    ((float*)C0)[(size_t)row * 256 + col] = v;
                } else if (OUTMODE == 1) {
                    ((unsigned short*)C0)[(size_t)row * 256 + col] = f2bf(v);
                } else {
                    unsigned short h = f2bf(v);
                    ((unsigned short*)C0)[(size_t)row * 256 + col] = h;
                    ((unsigned short*)C1)[(size_t)row * 256 + col] =
                        f2bf(v - bf2f(h));
                }
            }
        }
}

template<int KDIM, int OUTMODE, int BM>
__global__ __launch_bounds__(256, (BM == 64) ? 4 : 2) void mfma_gemm3_kernel(
    const unsigned short* __restrict__ Ah_, const unsigned short* __restrict__ Al_,
    const unsigned short* __restrict__ Bh_, const unsigned short* __restrict__ Bl_,
    const float* __restrict__ bias,
    void* __restrict__ C0, void* __restrict__ C1)
{
    __shared__ short Ah[BM][32], Al[BM][32], Bh[128][32], Bl[128][32];
    gemm3_body<KDIM, OUTMODE, BM>(Ah_, Al_, Bh_, Bl_, bias, C0, C1,
                                  blockIdx.y * BM, blockIdx.x * 128,
                                  Ah, Al, Bh, Bl);
}

// ---------------------------------------------------------------------------
// proj4: all four DIM x DIM projections in one launch (z selects weights).
// ---------------------------------------------------------------------------
struct Proj4Args {
    const unsigned short* Bh[4];
    const unsigned short* Bl[4];
    const float* bias[4];
    void* C[4];
};

__global__ __launch_bounds__(256, 2) void proj4_kernel(
    const unsigned short* __restrict__ Ah_, const unsigned short* __restrict__ Al_,
    Proj4Args p)
{
    __shared__ short Ah[128][32], Al[128][32], Bh[128][32], Bl[128][32];
    const int z = blockIdx.z;
    if (z < 3)
        gemm3_body<DIM, 0, 128>(Ah_, Al_, p.Bh[z], p.Bl[z], p.bias[z], p.C[z],
                                nullptr, blockIdx.y * 128, blockIdx.x * 128,
                                Ah, Al, Bh, Bl);
    else
        gemm3_body<DIM, 1, 128>(Ah_, Al_, p.Bh[z], p.Bl[z], p.bias[z], p.C[z],
                                nullptr, blockIdx.y * 128, blockIdx.x * 128,
                                Ah, Al, Bh, Bl);
}

// ---------------------------------------------------------------------------
// LayerNorm + hi/lo bf16 split for Q and K in one launch (blockIdx.y).
// ---------------------------------------------------------------------------
__global__ __launch_bounds__(256) void ln_split2_kernel(
    const float* __restrict__ Qf, const float* __restrict__ Kf,
    unsigned short* __restrict__ Qh, unsigned short* __restrict__ Ql,
    unsigned short* __restrict__ Kh, unsigned short* __restrict__ Kl)
{
    const int row = blockIdx.x;
    const int t = threadIdx.x;
    const float* X = blockIdx.y ? Kf : Qf;
    unsigned short* Hi = blockIdx.y ? Kh : Qh;
    unsigned short* Lo = blockIdx.y ? Kl : Ql;

    float x = X[(size_t)row * DIM + t];

    float s1 = x, s2 = x * x;
    #pragma unroll
    for (int o = 32; o; o >>= 1) {
        s1 += __shfl_xor(s1, o);
        s2 += __shfl_xor(s2, o);
    }
    __shared__ float r1[4], r2[4];
    const int wid = t >> 6;
    if ((t & 63) == 0) { r1[wid] = s1; r2[wid] = s2; }
    __syncthreads();
    const float sum = r1[0] + r1[1] + r1[2] + r1[3];
    const float ssq = r2[0] + r2[1] + r2[2] + r2[3];
    const float mean = sum * (1.0f / DIM);
    const float var  = ssq * (1.0f / DIM) - mean * mean;
    const float y = (x - mean) * rsqrtf(var + 1e-5f);

    const unsigned short h = f2bf(y);
    Hi[(size_t)row * DIM + t] = h;
    Lo[(size_t)row * DIM + t] = f2bf(y - bf2f(h));
}

// ---------------------------------------------------------------------------
// V [8192,256] fp32 -> VT [256,8192] bf16.
// ---------------------------------------------------------------------------
__global__ __launch_bounds__(256) void vtrans_kernel(
    const float* __restrict__ V, unsigned short* __restrict__ VT)
{
    __shared__ float tile[64][65];
    const int r0 = blockIdx.x * 64;
    const int c0 = blockIdx.y * 64;
    const int t = threadIdx.x;
    #pragma unroll
    for (int i = 0; i < 4; ++i) {
        int r = i * 16 + (t >> 4);
        int c = (t & 15) * 4;
        float4 v = *(const float4*)&V[(size_t)(r0 + r) * DIM + c0 + c];
        tile[r][c] = v.x; tile[r][c + 1] = v.y;
        tile[r][c + 2] = v.z; tile[r][c + 3] = v.w;
    }
    __syncthreads();
    #pragma unroll
    for (int i = 0; i < 4; ++i) {
        int c = i * 16 + (t >> 4);
        int r = (t & 15) * 4;
        ushort4 o;
        o.x = f2bf(tile[r][c]);     o.y = f2bf(tile[r + 1][c]);
        o.z = f2bf(tile[r + 2][c]); o.w = f2bf(tile[r + 3][c]);
        *(ushort4*)&VT[(size_t)(c0 + c) * N_NODES + r0 + r] = o;
    }
}

// ---------------------------------------------------------------------------
// scores = Q @ K^T (split-bf16). Sb = bf16 exp(s-m_blk) packed into the
// SECOND HALF of each k-slice's fp32 target range within the attn row slot:
// row byte offset = ks*8192 + 4096 + lb*256  (ks = nb>>4, lb = nb&15).
// ---------------------------------------------------------------------------
__global__ __launch_bounds__(256, 4) void qkt_kernel(
    const unsigned short* __restrict__ Qh, const unsigned short* __restrict__ Ql,
    const unsigned short* __restrict__ Kh, const unsigned short* __restrict__ Kl,
    unsigned short* __restrict__ Sb, float2* __restrict__ pstat)
{
    __shared__ short stage[4][128][32];   // Ah/Al/Bh/Bl; reused as bf16 out-tile
    __shared__ float2 ps[2][128];
    __shared__ float gmr[128];

    // 2D-chunked XCD swizzle: xcd owns mb in [x*8,x*8+8); nb grouped by 8.
    const int bid = blockIdx.x;
    const int x   = bid & 7;
    const int i   = bid >> 3;          // 0..511
    const int nbs = i >> 6;            // 0..7
    const int j   = i & 63;
    const int mb  = x * 8 + (j & 7);
    const int nb  = nbs * 8 + (j >> 3);
    const int m0 = mb * 128, n0 = nb * 128;
    const int sbbase = (nb >> 4) * 4096 + 2048 + (nb & 15) * 128;  // ushorts

    const int t = threadIdx.x, lane = t & 63, w = t >> 6;
    const int wm = w >> 1, wn = w & 1;
    const int fr = lane & 15, kb = lane >> 4;

    // hoisted staging pointers (2 chunks x 4 tensors per thread)
    const unsigned short* qsrc[2][2];
    const unsigned short* ksrc[2][2];
    char* qdst[2][2];
    char* kdst[2][2];
    #pragma unroll
    for (int r = 0; r < 2; ++r) {
        int c = r * 256 + t;
        int row = c >> 2, slot = c & 3;
        size_t ga = (size_t)(m0 + row) * DIM + slot * 8;
        size_t gb = (size_t)(n0 + row) * DIM + slot * 8;
        qsrc[r][0] = Qh + ga; qsrc[r][1] = Ql + ga;
        ksrc[r][0] = Kh + gb; ksrc[r][1] = Kl + gb;
        qdst[r][0] = (char*)&stage[0][0][0] + c * 16;
        qdst[r][1] = (char*)&stage[1][0][0] + c * 16;
        kdst[r][0] = (char*)&stage[2][0][0] + c * 16;
        kdst[r][1] = (char*)&stage[3][0][0] + c * 16;
    }

    f32x4 acc[4][4] = {};

    for (int k0 = 0; k0 < DIM; k0 += 32) {
        #pragma unroll
        for (int r = 0; r < 2; ++r) {
            gll16(qsrc[r][0], qdst[r][0]); qsrc[r][0] += 32;
            gll16(qsrc[r][1], qdst[r][1]); qsrc[r][1] += 32;
            gll16(ksrc[r][0], kdst[r][0]); ksrc[r][0] += 32;
            gll16(ksrc[r][1], kdst[r][1]); ksrc[r][1] += 32;
        }
        __syncthreads();

        bf16x8 ah[4], al[4], bh[4], bl[4];
        #pragma unroll
        for (int m = 0; m < 4; ++m) {
            int row = wm * 64 + m * 16 + fr;
            ah[m] = *(const bf16x8*)&stage[0][row][kb * 8];
            al[m] = *(const bf16x8*)&stage[1][row][kb * 8];
        }
        #pragma unroll
        for (int n = 0; n < 4; ++n) {
            int col = wn * 64 + n * 16 + fr;
            bh[n] = *(const bf16x8*)&stage[2][col][kb * 8];
            bl[n] = *(const bf16x8*)&stage[3][col][kb * 8];
        }
        #pragma unroll
        for (int m = 0; m < 4; ++m)
            #pragma unroll
            for (int n = 0; n < 4; ++n) {
                acc[m][n] = MFMA16(ah[m], bh[n], acc[m][n], 0, 0, 0);
                acc[m][n] = MFMA16(ah[m], bl[n], acc[m][n], 0, 0, 0);
                acc[m][n] = MFMA16(al[m], bh[n], acc[m][n], 0, 0, 0);
            }
        __syncthreads();
    }

    // ---- phase A: per-row max over this block's 128 cols
    #pragma unroll
    for (int m = 0; m < 4; ++m)
        #pragma unroll
        for (int e = 0; e < 4; ++e) {
            float mx = acc[m][0][e];
            #pragma unroll
            for (int n = 1; n < 4; ++n) mx = fmaxf(mx, acc[m][n][e]);
            #pragma unroll
            for (int o = 1; o < 16; o <<= 1) mx = fmaxf(mx, __shfl_xor(mx, o));
            if (fr == 0) ps[wn][wm * 64 + m * 16 + kb * 4 + e].x = mx;
        }
    __syncthreads();
    if (t < 128) gmr[t] = fmaxf(ps[0][t].x, ps[1][t].x);
    __syncthreads();

    // ---- phase B: single exp pass -> bf16 tile (XOR-swizzled) + sumexp
    unsigned short* tile = (unsigned short*)&stage[0][0][0];   // [128][128]
    #pragma unroll
    for (int m = 0; m < 4; ++m)
        #pragma unroll
        for (int e = 0; e < 4; ++e) {
            const int rl = wm * 64 + m * 16 + kb * 4 + e;
            const float g = gmr[rl];
            const int key = kb << 1;           // (rl>>2)&3 == kb
            float se = 0.f;
            #pragma unroll
            for (int n = 0; n < 4; ++n) {
                float ev = __expf(acc[m][n][e] - g);
                se += ev;
                const int col = wn * 64 + n * 16 + fr;
                tile[rl * 128 + (((col >> 3) ^ key) << 3) + (col & 7)] =
                    f2bf(ev);
            }
            #pragma unroll
            for (int o = 1; o < 16; o <<= 1) se += __shfl_xor(se, o);
            if (fr == 0) ps[wn][rl].y = se;
        }
    __syncthreads();
    if (t < 128)
        pstat[(size_t)(m0 + t) * 64 + nb] =
            make_float2(gmr[t], ps[0][t].y + ps[1][t].y);

    // ---- coalesced bf16 store into the packed slot
    #pragma unroll
    for (int p = 0; p < 8; ++p) {
        int c = p * 256 + t;            // 16B chunk id (2048 total)
        int r = c >> 4, sl = c & 15;
        int slx = sl ^ (((r >> 2) & 3) << 1);
        *(int4*)&Sb[(size_t)(m0 + r) * 16384 + sbbase + sl * 8] =
            *(const int4*)((const char*)tile + (r * 16 + slx) * 16);
    }
}

// ---------------------------------------------------------------------------
// factab[row][cb] = exp(m_cb - m_row) / Z_row. 4 rows/block, 64 lanes/row.
// ---------------------------------------------------------------------------
__global__ __launch_bounds__(256) void factor_kernel(
    const float2* __restrict__ pstat, float* __restrict__ factab)
{
    const int row = blockIdx.x * 4 + (threadIdx.x >> 6);
    const int lane = threadIdx.x & 63;
    float2 v = pstat[(size_t)row * 64 + lane];
    float gm = v.x;
    #pragma unroll
    for (int o = 1; o < 64; o <<= 1) gm = fmaxf(gm, __shfl_xor(gm, o));
    float s = v.y * __expf(v.x - gm);
    #pragma unroll
    for (int o = 1; o < 64; o <<= 1) s += __shfl_xor(s, o);
    factab[(size_t)row * 64 + lane] = __expf(v.x - gm) / s;
}

// ---------------------------------------------------------------------------
// av_mfma: ZA partials = (factor * Sb) @ VT^T via per-step scaled MFMA,
// PLUS in-place fp32 attn expansion from the staged LDS tile.
// ---------------------------------------------------------------------------
__global__ __launch_bounds__(256, 2) void av_mfma_kernel(
    const unsigned short* __restrict__ Sb, const float* __restrict__ factab,
    const unsigned short* __restrict__ VT, float* __restrict__ attn,
    float* __restrict__ P0, float* __restrict__ P1,
    float* __restrict__ P2, float* __restrict__ P3)
{
    __shared__ unsigned short As[2][64][128];   // linear dest, swizzled source
    __shared__ float facsT[16][64];             // [local cb][row]

    const int bid = blockIdx.x;
    const int x = bid & 7, i = bid >> 3;        // i in [0,64)
    const int ks = i >> 4;                      // slow per XCD
    const int rb = (i & 15) * 8 + x;            // 0..127
    const int r0 = rb * 64, kbase = ks * 2048, cb0 = ks * 16;
    const int t = threadIdx.x, lane = t & 63, w = t >> 6;
    const int fr = lane & 15, kb = lane >> 4;

    for (int ii = t; ii < 1024; ii += 256)
        facsT[ii >> 6][ii & 63] =
            factab[(size_t)(r0 + (ii & 63)) * 64 + cb0 + (ii >> 6)];

    const unsigned short* vb[4];
    #pragma unroll
    for (int n = 0; n < 4; ++n)
        vb[n] = VT + (size_t)(w * 64 + n * 16 + fr) * N_NODES + kbase + kb * 8;

    // hoisted STAGE pointers (packed Sb base: ks*4096 + 2048)
    const unsigned short* ssrc[4];
    char* sdst[4];
    #pragma unroll
    for (int p = 0; p < 4; ++p) {
        int c = p * 256 + t;
        int rr = c >> 4, sl = c & 15;
        int slp = sl ^ (rr & 7);
        ssrc[p] = Sb + (size_t)(r0 + rr) * 16384 + ks * 4096 + 2048 + slp * 8;
        sdst[p] = (char*)&As[0][0][0] + c * 16;
    }

    #define STAGE(BUF_) do {                                                  \
        _Pragma("unroll")                                                     \
        for (int p = 0; p < 4; ++p) {                                         \
            gll16(ssrc[p], sdst[p] + (BUF_) * 16384);                         \
            ssrc[p] += 128;                                                   \
        } } while (0)

    f32x4 acc[4][4] = {};
    const f32x4 z4 = {0.f, 0.f, 0.f, 0.f};

    STAGE(0);
    __syncthreads();

    for (int s = 0; s < 16; ++s) {
        const int b = s & 1;
        if (s + 1 < 16) STAGE(b ^ 1);

        bf16x8 bb[4][4];
        #pragma unroll
        for (int ksl = 0; ksl < 4; ++ksl)
            #pragma unroll
            for (int n = 0; n < 4; ++n)
                bb[ksl][n] = *(const bf16x8*)(vb[n] + s * 128 + ksl * 32);

        const char* abase = (const char*)&As[b][0][0];
        #pragma unroll
        for (int m = 0; m < 4; ++m) {
            f32x4 sacc[4];
            {
                bf16x8 a = *(const bf16x8*)(abase + (m * 16 + fr) * 256 +
                                            ((kb ^ (fr & 7)) * 16));
                #pragma unroll
                for (int n = 0; n < 4; ++n)
                    sacc[n] = MFMA16(a, bb[0][n], z4, 0, 0, 0);
            }
            #pragma unroll
            for (int ksl = 1; ksl < 4; ++ksl) {
                bf16x8 a = *(const bf16x8*)(abase + (m * 16 + fr) * 256 +
                                            (((ksl * 4 + kb) ^ (fr & 7)) * 16));
                #pragma unroll
                for (int n = 0; n < 4; ++n)
                    sacc[n] = MFMA16(a, bb[ksl][n], sacc[n], 0, 0, 0);
            }
            f32x4 fac = *(const f32x4*)&facsT[s][m * 16 + kb * 4];
            #pragma unroll
            for (int n = 0; n < 4; ++n)
                acc[m][n] += fac * sacc[n];
        }

        // ---- fused attn epilogue: expand this step's LDS tile to fp32
        #pragma unroll
        for (int p = 0; p < 4; ++p) {
            int ci = p * 256 + t;
            int rr = ci >> 4, g = ci & 15;
            const float fac = facsT[s][rr];
            int4 v = *(const int4*)(abase + (rr * 16 + (g ^ (rr & 7))) * 16);
            float* dst = attn + (size_t)(r0 + rr) * N_NODES +
                         kbase + s * 128 + g * 8;
            float4 o0, o1;
            o0.x = bf2f((unsigned short)(v.x & 0xffff)) * fac;
            o0.y = bf2f((unsigned short)((unsigned)v.x >> 16)) * fac;
            o0.z = bf2f((unsigned short)(v.y & 0xffff)) * fac;
            o0.w = bf2f((unsigned short)((unsigned)v.y >> 16)) * fac;
            o1.x = bf2f((unsigned short)(v.z & 0xffff)) * fac;
            o1.y = bf2f((unsigned short)((unsigned)v.z >> 16)) * fac;
            o1.z = bf2f((unsigned short)(v.w & 0xffff)) * fac;
            o1.w = bf2f((unsigned short)((unsigned)v.w >> 16)) * fac;
            *(float4*)dst       = o0;
            *(float4*)(dst + 4) = o1;
        }
        __syncthreads();
    }
    #undef STAGE

    float* P = (ks == 0) ? P0 : (ks == 1) ? P1 : (ks == 2) ? P2 : P3;
    #pragma unroll
    for (int m = 0; m < 4; ++m)
        #pragma unroll
        for (int e = 0; e < 4; ++e) {
            int row = r0 + m * 16 + kb * 4 + e;
            #pragma unroll
            for (int n = 0; n < 4; ++n)
                P[(size_t)row * DIM + w * 64 + n * 16 + fr] = acc[m][n][e];
        }
}

// ---------------------------------------------------------------------------
// SpMM: one 64-lane wave per node, lane holds 4 features (ushort4 loads).
// ---------------------------------------------------------------------------
__global__ __launch_bounds__(256) void spmm_kernel(
    const unsigned short* __restrict__ Hb, const int* __restrict__ erow,
    const int* __restrict__ ecol, const float* __restrict__ ew,
    float* __restrict__ out, int E)
{
    const int node = blockIdx.x * 4 + (threadIdx.x >> 6);
    const int lane = threadIdx.x & 63;

    int lo = 0, hi = E;
    while (lo < hi) { int mid = (lo + hi) >> 1; if (erow[mid] < node) lo = mid + 1; else hi = mid; }
    const int beg = lo;
    hi = E;
    while (lo < hi) { int mid = (lo + hi) >> 1; if (erow[mid] < node + 1) lo = mid + 1; else hi = mid; }
    const int end = lo;

    float4 acc = make_float4(0.f, 0.f, 0.f, 0.f);
    for (int e = beg; e < end; ++e) {
        const int col = ecol[e];
        const float wgt = ew[e];
        ushort4 h = *(const ushort4*)&Hb[(size_t)col * DIM + lane * 4];
        acc.x += wgt * bf2f(h.x);
        acc.y += wgt * bf2f(h.y);
        acc.z += wgt * bf2f(h.z);
        acc.w += wgt * bf2f(h.w);
    }
    *(float4*)&out[(size_t)node * DIM + lane * 4] = acc;
}

// ---------------------------------------------------------------------------
// Y = (0.5*(P0+P1+P2+P3) + 0.5*GNN) @ Wc + bc
// ---------------------------------------------------------------------------
__global__ __launch_bounds__(256) void blend_cls_kernel(
    const float* __restrict__ p0, const float* __restrict__ p1,
    const float* __restrict__ p2, const float* __restrict__ p3,
    const float* __restrict__ gnn,
    const float* __restrict__ Wc, const float* __restrict__ bc,
    float* __restrict__ Y)
{
    const int row = blockIdx.x;
    const int t = threadIdx.x;
    __shared__ float z[DIM];
    __shared__ float part[4][NCLS];

    const size_t i = (size_t)row * DIM + t;
    z[t] = 0.5f * (p0[i] + p1[i] + p2[i] + p3[i] + gnn[i]);
    __syncthreads();

    if (t < 160) {
        const int c = t % NCLS, q = t / NCLS;
        float acc = 0.0f;
        #pragma unroll 4
        for (int d = q * 64; d < q * 64 + 64; ++d)
            acc += z[d] * Wc[d * NCLS + c];
        part[q][c] = acc;
    }
    __syncthreads();
    if (t < NCLS)
        Y[(size_t)row * NCLS + t] =
            part[0][t] + part[1][t] + part[2][t] + part[3][t] + bc[t];
}

// ---------------------------------------------------------------------------
extern "C" void kernel_launch(void* const* d_in, const int* in_sizes, int n_in,
                              void* d_out, int out_size, void* d_ws, size_t ws_size,
                              hipStream_t stream)
{
    const float* X     = (const float*)d_in[0];
    const int*   erow  = (const int*)d_in[1];
    const int*   ecol  = (const int*)d_in[2];
    const float* ew    = (const float*)d_in[3];
    const float* W_emb = (const float*)d_in[4];
    const float* b_emb = (const float*)d_in[5];
    const float* W_q   = (const float*)d_in[6];
    const float* b_q   = (const float*)d_in[7];
    const float* W_k   = (const float*)d_in[8];
    const float* b_k   = (const float*)d_in[9];
    const float* W_v   = (const float*)d_in[10];
    const float* b_v   = (const float*)d_in[11];
    const float* W_g   = (const float*)d_in[12];
    const float* b_g   = (const float*)d_in[13];
    const float* W_c   = (const float*)d_in[14];
    const float* b_c   = (const float*)d_in[15];
    const int E = in_sizes[1];

    float* Y    = (float*)d_out;
    float* Sc   = Y + (size_t)N_NODES * NCLS;      // attn [N,N]; Sb packed inside
    unsigned short* Sb = (unsigned short*)Sc;      // row r at ushort offset r*16384

    const size_t ND = (size_t)N_NODES * DIM;       // 2M elements (8 MB fp32)
    float* R0 = (float*)d_ws;
    float* R1 = R0 + ND;
    float* R2 = R1 + ND;
    float* R3 = R2 + ND;
    float* R4 = R3 + ND;
    float* R5 = R4 + ND;
    float* R6 = R5 + ND;

    // phase-1 aliases
    unsigned short* Xh = (unsigned short*)R0;      // 8 MB
    unsigned short* Xl = (unsigned short*)R1;      // 8 MB
    unsigned short* Wt = (unsigned short*)R2;      // packed weight transposes
    unsigned short* WembTh = Wt;                   // 256x512
    unsigned short* WembTl = Wt + 256 * 512;
    unsigned short* WqTh = WembTl + 256 * 512;     // 256x256 each
    unsigned short* WqTl = WqTh + 256 * 256;
    unsigned short* WkTh = WqTl + 256 * 256;
    unsigned short* WkTl = WkTh + 256 * 256;
    unsigned short* WvTh = WkTl + 256 * 256;
    unsigned short* WvTl = WvTh + 256 * 256;
    unsigned short* WgTh = WvTl + 256 * 256;
    unsigned short* WgTl = WgTh + 256 * 256;
    unsigned short* Z0h = (unsigned short*)R3;     // 4 MB
    unsigned short* Z0l = Z0h + ND;                // 4 MB
    float* Qf = R4;
    float* Kf = R5;
    float* Vf = R6;
    unsigned short* Hb = (unsigned short*)R0;      // first 4 MB (X dead)
    // phase-2 aliases
    unsigned short* Qh = (unsigned short*)R1;      // Xl dead
    unsigned short* Ql = Qh + ND;
    unsigned short* Kh = (unsigned short*)R2;      // weights dead
    unsigned short* Kl = Kh + ND;
    unsigned short* VT = (unsigned short*)(R0 + ND / 2);  // second 4 MB of R0
    float2* pstat = (float2*)R4;                   // Qf dead after ln_split
    float*  factab = R5;                           // Kf dead after ln_split+qkt
    // ZA partials (each 8 MB)
    float* P0 = R6;   // Vf dead after vtrans
    float* P1 = R3;   // Z0 dead after projections
    float* P2 = R4;   // pstat dead after factor
    float* P3 = R1;   // Qh/Ql dead after qkt
    float* GNN = R2;  // Kh/Kl dead after qkt

    // 1. X -> hi/lo bf16
    split_kernel<<<(N_NODES * F_IN) / 1024, 256, 0, stream>>>(X, Xh, Xl);

    // 2. weight transposes: emb (512x256) + the four DIM x DIM batched
    wtrans_kernel<<<dim3(F_IN / 64, DIM / 64), 256, 0, stream>>>(
        W_emb, WembTh, WembTl, F_IN, DIM);
    Wt4Args wa;
    wa.W[0] = W_q; wa.Th[0] = WqTh; wa.Tl[0] = WqTl;
    wa.W[1] = W_k; wa.Th[1] = WkTh; wa.Tl[1] = WkTl;
    wa.W[2] = W_v; wa.Th[2] = WvTh; wa.Tl[2] = WvTl;
    wa.W[3] = W_g; wa.Th[3] = WgTh; wa.Tl[3] = WgTl;
    wtrans4_kernel<<<dim3(DIM / 64, DIM / 64, 4), 256, 0, stream>>>(wa);

    // 3. Z0 = X @ W_emb + b (BM=64 -> 256 blocks = 1/CU)
    mfma_gemm3_kernel<F_IN, 2, 64><<<dim3(2, N_NODES / 64), 256, 0, stream>>>(
        Xh, Xl, WembTh, WembTl, b_emb, Z0h, Z0l);

    // 4. all four projections in one launch
    Proj4Args pa;
    pa.Bh[0] = WqTh; pa.Bl[0] = WqTl; pa.bias[0] = b_q; pa.C[0] = Qf;
    pa.Bh[1] = WkTh; pa.Bl[1] = WkTl; pa.bias[1] = b_k; pa.C[1] = Kf;
    pa.Bh[2] = WvTh; pa.Bl[2] = WvTl; pa.bias[2] = b_v; pa.C[2] = Vf;
    pa.Bh[3] = WgTh; pa.Bl[3] = WgTl; pa.bias[3] = b_g; pa.C[3] = Hb;
    proj4_kernel<<<dim3(2, N_NODES / 128, 4), 256, 0, stream>>>(Z0h, Z0l, pa);

    // 5. LN + hi/lo split (Q and K in one launch)
    ln_split2_kernel<<<dim3(N_NODES, 2), 256, 0, stream>>>(
        Qf, Kf, Qh, Ql, Kh, Kl);

    // 6. V -> VT bf16
    vtrans_kernel<<<dim3(N_NODES / 64, DIM / 64), 256, 0, stream>>>(Vf, VT);

    // 7. Sb = bf16 exp(QK^T - m_block) (packed) + pstat
    qkt_kernel<<<4096, 256, 0, stream>>>(Qh, Ql, Kh, Kl, Sb, pstat);

    // 8. factor table
    factor_kernel<<<N_NODES / 4, 256, 0, stream>>>(pstat, factab);

    // 9. ZA partials + fused in-place attn fp32 expansion
    av_mfma_kernel<<<512, 256, 0, stream>>>(
        Sb, factab, VT, Sc, P0, P1, P2, P3);

    // 10. GNN branch (bf16 H)
    spmm_kernel<<<N_NODES / 4, 256, 0, stream>>>(Hb, erow, ecol, ew, GNN, E);

    // 11. blend (partials summed inline) + classifier
    blend_cls_kernel<<<N_NODES, 256, 0, stream>>>(
        P0, P1, P2, P3, GNN, W_c, b_c, Y);
}